// Round 1
// baseline (2412.794 us; speedup 1.0000x reference)
//
#include <hip/hip_runtime.h>
#include <math.h>

// Problem constants: B=4, C=64, H=256, W=256, L=2, M1=M2=32, HM=128, P=256, O=1
#define NB 4
#define NC 64
#define NH 256
#define NW 256
#define NKX 32
#define NKY 64   // 2*M1
#define NHM 128
#define NP 256

// workspace layout (in floats)
#define OFF_XA   0                      // 16777216 floats
#define OFF_XB   16777216               // 16777216
#define OFF_Z1   33554432               // 4194304 (float2[2097152]) : X1 / Z reuse
#define OFF_XF   37748736               // 1048576 (float2[524288])
#define OFF_OF   38797312               // 1048576
#define OFF_TWW  39845888               // float2[8192]  [w][kx]  (c,s) of 2*pi*(kx*w mod 256)/256
#define OFF_TWWT 39862272               // float2[8192]  [kx][w]
#define OFF_TH   39878656               // float2[16384] [j][h]   ky_j = j<32? j : 192+j
// total = 39911424 floats = 159645696 bytes (~152.3 MiB)

__device__ __forceinline__ float gelu_f(float v) {
    return 0.5f * v * (1.0f + erff(v * 0.70710678118654752440f));
}

__global__ __launch_bounds__(256) void init_tw(float* ws) {
    int idx = blockIdx.x * 256 + threadIdx.x;
    float2* tww  = (float2*)(ws + OFF_TWW);
    float2* twwt = (float2*)(ws + OFF_TWWT);
    float2* th   = (float2*)(ws + OFF_TH);
    if (idx < 8192) {
        int w = idx >> 5, kx = idx & 31;
        int m = (kx * w) & 255;
        double a = (double)m * (3.14159265358979323846 / 128.0);
        float c = (float)cos(a), s = (float)sin(a);
        tww[w * 32 + kx]  = make_float2(c, s);
        twwt[kx * 256 + w] = make_float2(c, s);
    }
    int idx2 = idx - 8192;
    if (idx2 >= 0 && idx2 < 16384) {
        int j = idx2 >> 8, h = idx2 & 255;
        int ky = (j < 32) ? j : (192 + j);
        int m = (ky * h) & 255;
        double a = (double)m * (3.14159265358979323846 / 128.0);
        th[j * 256 + h] = make_float2((float)cos(a), (float)sin(a));
    }
}

// ---- forward DFT over W: x[row(b,c,h)][w] -> X1[row][kx] (complex, exp(-i th))
// 16 rows per block, 256 threads: thread = (kx, rr), handles rows rr and rr+8
__global__ __launch_bounds__(256) void k_fwd_w(const float* __restrict__ x,
                                               float2* __restrict__ X1,
                                               const float2* __restrict__ tww) {
    __shared__ float xs[16 * 256];     // 16 KB
    __shared__ float2 tcs[8192];       // 64 KB
    int tid = threadIdx.x;
    int row0 = blockIdx.x * 16;
    for (int i = tid; i < 8192; i += 256) tcs[i] = tww[i];
    for (int i = tid; i < 4096; i += 256) xs[i] = x[row0 * 256 + i];
    __syncthreads();
    int kx = tid & 31, rr = tid >> 5;
    float ar0 = 0.f, ai0 = 0.f, ar1 = 0.f, ai1 = 0.f;
    const float* xr0 = &xs[rr * 256];
    const float* xr1 = &xs[(rr + 8) * 256];
    for (int w = 0; w < 256; ++w) {
        float2 cs = tcs[w * 32 + kx];
        float x0 = xr0[w], x1 = xr1[w];
        ar0 = fmaf(x0, cs.x, ar0);  ai0 = fmaf(x0, -cs.y, ai0);
        ar1 = fmaf(x1, cs.x, ar1);  ai1 = fmaf(x1, -cs.y, ai1);
    }
    X1[(row0 + rr) * 32 + kx]     = make_float2(ar0, ai0);
    X1[(row0 + rr + 8) * 32 + kx] = make_float2(ar1, ai1);
}

// ---- forward DFT over H: X1[(b,c)][h][kx] -> XF[(b,c)][j][kx], exp(-i th)
__global__ __launch_bounds__(256) void k_fwd_h(const float2* __restrict__ X1,
                                               float2* __restrict__ XF,
                                               const float2* __restrict__ th) {
    __shared__ float2 xs[8192];        // 64 KB  [h][kx]
    int tid = threadIdx.x, plane = blockIdx.x;
    for (int i = tid; i < 8192; i += 256) xs[i] = X1[plane * 8192 + i];
    __syncthreads();
    int kx = tid & 31, j0 = tid >> 5;
    for (int q = 0; q < 8; ++q) {
        int j = j0 + 8 * q;
        const float2* tr = &th[j * 256];
        float ar = 0.f, ai = 0.f;
        for (int hh = 0; hh < 256; ++hh) {
            float2 xv = xs[hh * 32 + kx];
            float2 cs = tr[hh];
            ar = fmaf(xv.x, cs.x, fmaf(xv.y, cs.y, ar));
            ai = fmaf(xv.y, cs.x, fmaf(-xv.x, cs.y, ai));
        }
        XF[(plane * 64 + j) * 32 + kx] = make_float2(ar, ai);
    }
}

// ---- per-mode complex matmul: OF[b,o,j,kx] = sum_i XF[b,i,j,kx]*W[i,o,j,kx]
// grid (o=64, j=64), 128 threads = (kx, b)
__global__ __launch_bounds__(128) void k_modemul(const float2* __restrict__ XF,
                                                 const float2* __restrict__ sw1,
                                                 const float2* __restrict__ sw2,
                                                 float2* __restrict__ OF, int l) {
    int o = blockIdx.x, j = blockIdx.y;
    int tid = threadIdx.x;
    int kx = tid & 31, b = tid >> 5;
    int jj = (j < 32) ? j : (j - 32);
    const float2* Wb = ((j < 32) ? sw1 : sw2) + (l * 4194304 + o * 1024 + jj * 32 + kx);
    const float2* Xb = XF + (b * 64 * 64 * 32 + j * 32 + kx);
    float ar = 0.f, ai = 0.f;
    for (int i = 0; i < 64; ++i) {
        float2 xv = Xb[i * 2048];
        float2 wv = Wb[i * 65536];
        ar += xv.x * wv.x - xv.y * wv.y;
        ai += xv.x * wv.y + xv.y * wv.x;
    }
    OF[((b * 64 + o) * 64 + j) * 32 + kx] = make_float2(ar, ai);
}

// ---- inverse DFT over H: Z[(b,c)][h][kx] = sum_j OF[(b,c)][j][kx] * exp(+i th)
__global__ __launch_bounds__(256) void k_inv_h(const float2* __restrict__ OF,
                                               float2* __restrict__ Z,
                                               const float2* __restrict__ th) {
    __shared__ float2 ofs[2048];       // 16 KB [j][kx]
    int tid = threadIdx.x, plane = blockIdx.x;
    for (int i = tid; i < 2048; i += 256) ofs[i] = OF[plane * 2048 + i];
    __syncthreads();
    int kx = tid & 31, h0 = tid >> 5;
    for (int q = 0; q < 32; ++q) {
        int hh = h0 + 8 * q;
        float zr = 0.f, zi = 0.f;
        for (int j = 0; j < 64; ++j) {
            float2 ov = ofs[j * 32 + kx];
            float2 cs = th[j * 256 + hh];
            zr += ov.x * cs.x - ov.y * cs.y;
            zi += ov.y * cs.x + ov.x * cs.y;
        }
        Z[(plane * 256 + hh) * 32 + kx] = make_float2(zr, zi);
    }
}

// ---- fused inverse DFT over W (real output) + channel skip conv + bias + GELU
// grid (4 wtiles, 256 h, 4 b), 256 threads = (wl 64, g 4); o = g + 4q
__global__ __launch_bounds__(256) void k_invw_skip(const float2* __restrict__ Z,
                                                   const float* __restrict__ xin,
                                                   const float* __restrict__ skip_w,
                                                   const float* __restrict__ skip_b,
                                                   const float2* __restrict__ twwt,
                                                   float* __restrict__ xout, int l) {
    __shared__ float2 zs[2048];        // [o][kx]     16 KB
    __shared__ float xsk[4096];        // [i][w]      16 KB
    __shared__ float swl[4096];        // [o][i]      16 KB
    __shared__ float2 twl[2048];       // [kx][64w]   16 KB
    int tid = threadIdx.x;
    int b = blockIdx.z, hh = blockIdx.y, w0 = blockIdx.x * 64;
    for (int i = tid; i < 2048; i += 256) {
        int o = i >> 5, kx = i & 31;
        zs[i] = Z[(b * 64 + o) * 8192 + hh * 32 + kx];
    }
    for (int i = tid; i < 4096; i += 256) {
        int ch = i >> 6, wl = i & 63;
        xsk[i] = xin[((b * 64 + ch) * 256 + hh) * 256 + w0 + wl];
        swl[i] = skip_w[l * 4096 + i];
    }
    for (int i = tid; i < 2048; i += 256) {
        int kx = i >> 6, wl = i & 63;
        twl[i] = twwt[kx * 256 + w0 + wl];
    }
    __syncthreads();
    int wl = tid & 63, g = tid >> 6;
    float sp[16];
#pragma unroll
    for (int q = 0; q < 16; ++q) sp[q] = 0.f;
    for (int kx = 1; kx < 32; ++kx) {
        float2 cs = twl[kx * 64 + wl];
#pragma unroll
        for (int q = 0; q < 16; ++q) {
            float2 zv = zs[(g + 4 * q) * 32 + kx];
            sp[q] += zv.x * cs.x - zv.y * cs.y;
        }
    }
#pragma unroll
    for (int q = 0; q < 16; ++q) {
        int o = g + 4 * q;
        sp[q] = (zs[o * 32].x + 2.f * sp[q]) * (1.f / 65536.f) + skip_b[l * 64 + o];
    }
    for (int i2 = 0; i2 < 64; ++i2) {
        float xv = xsk[i2 * 64 + wl];
#pragma unroll
        for (int q = 0; q < 16; ++q)
            sp[q] = fmaf(swl[(g + 4 * q) * 64 + i2], xv, sp[q]);
    }
#pragma unroll
    for (int q = 0; q < 16; ++q) {
        int o = g + 4 * q;
        xout[((b * 64 + o) * 256 + hh) * 256 + w0 + wl] = gelu_f(sp[q]);
    }
}

// ---- fused channel MLP: x2 = gelu(W2*gelu(W1*x1+b1)+b2 + Wsk*x1+bsk)
// two hm-phases of 64 so hidden never touches HBM. grid (4,256,4), 256 thr
__global__ __launch_bounds__(256) void k_mlp(const float* __restrict__ xin,
                                             const float* __restrict__ w1,
                                             const float* __restrict__ b1,
                                             const float* __restrict__ w2,
                                             const float* __restrict__ b2,
                                             const float* __restrict__ wsk,
                                             const float* __restrict__ bsk,
                                             float* __restrict__ xout, int l) {
    __shared__ float xs[4096];         // [i][w]
    __shared__ float wskl[4096];       // [o][i]
    __shared__ float hbuf[4096];       // [hm][w]
    __shared__ float wbuf[4096];       // w1 half then w2 half
    int tid = threadIdx.x;
    int b = blockIdx.z, hh = blockIdx.y, w0 = blockIdx.x * 64;
    for (int i = tid; i < 4096; i += 256) {
        int ch = i >> 6, wl = i & 63;
        xs[i] = xin[((b * 64 + ch) * 256 + hh) * 256 + w0 + wl];
        wskl[i] = wsk[l * 4096 + i];
    }
    int wl = tid & 63, g = tid >> 6;
    float acc[16];
#pragma unroll
    for (int q = 0; q < 16; ++q) acc[q] = b2[l * 64 + g + 4 * q] + bsk[l * 64 + g + 4 * q];
    for (int ph = 0; ph < 2; ++ph) {
        __syncthreads();
        for (int i = tid; i < 4096; i += 256)
            wbuf[i] = w1[(l * 128 + ph * 64) * 64 + i];
        __syncthreads();
        float hacc[16];
#pragma unroll
        for (int q = 0; q < 16; ++q) hacc[q] = b1[l * 128 + ph * 64 + g + 4 * q];
        for (int i2 = 0; i2 < 64; ++i2) {
            float xv = xs[i2 * 64 + wl];
#pragma unroll
            for (int q = 0; q < 16; ++q)
                hacc[q] = fmaf(wbuf[(g + 4 * q) * 64 + i2], xv, hacc[q]);
        }
        __syncthreads();
#pragma unroll
        for (int q = 0; q < 16; ++q) hbuf[(g + 4 * q) * 64 + wl] = gelu_f(hacc[q]);
        __syncthreads();
        for (int i = tid; i < 4096; i += 256) {
            int o = i >> 6, hm = i & 63;
            wbuf[i] = w2[(l * 64 + o) * 128 + ph * 64 + hm];
        }
        __syncthreads();
        for (int hm = 0; hm < 64; ++hm) {
            float hv = hbuf[hm * 64 + wl];
#pragma unroll
            for (int q = 0; q < 16; ++q)
                acc[q] = fmaf(wbuf[(g + 4 * q) * 64 + hm], hv, acc[q]);
        }
    }
    for (int i2 = 0; i2 < 64; ++i2) {
        float xv = xs[i2 * 64 + wl];
#pragma unroll
        for (int q = 0; q < 16; ++q)
            acc[q] = fmaf(wskl[(g + 4 * q) * 64 + i2], xv, acc[q]);
    }
#pragma unroll
    for (int q = 0; q < 16; ++q)
        xout[((b * 64 + g + 4 * q) * 256 + hh) * 256 + w0 + wl] = gelu_f(acc[q]);
}

// ---- fused projection: out = W2 * gelu(W1*x + b1) + b2   (P=256 in 2 phases)
__global__ __launch_bounds__(256) void k_proj(const float* __restrict__ xin,
                                              const float* __restrict__ pw1,
                                              const float* __restrict__ pb1,
                                              const float* __restrict__ pw2,
                                              const float* __restrict__ pb2,
                                              float* __restrict__ out) {
    __shared__ float xs[4096];         // [i][w]
    __shared__ float wbuf[8192];       // 128 p rows x 64
    __shared__ float red[256];
    int tid = threadIdx.x;
    int b = blockIdx.z, hh = blockIdx.y, w0 = blockIdx.x * 64;
    for (int i = tid; i < 4096; i += 256) {
        int ch = i >> 6, wl = i & 63;
        xs[i] = xin[((b * 64 + ch) * 256 + hh) * 256 + w0 + wl];
    }
    int wl = tid & 63, g = tid >> 6;
    float psum = 0.f;
    for (int ph = 0; ph < 2; ++ph) {
        __syncthreads();
        for (int i = tid; i < 8192; i += 256) wbuf[i] = pw1[ph * 8192 + i];
        __syncthreads();
        float pacc[32];
#pragma unroll
        for (int q = 0; q < 32; ++q) pacc[q] = pb1[ph * 128 + g + 4 * q];
        for (int i2 = 0; i2 < 64; ++i2) {
            float xv = xs[i2 * 64 + wl];
#pragma unroll
            for (int q = 0; q < 32; ++q)
                pacc[q] = fmaf(wbuf[(g + 4 * q) * 64 + i2], xv, pacc[q]);
        }
#pragma unroll
        for (int q = 0; q < 32; ++q)
            psum = fmaf(pw2[ph * 128 + g + 4 * q], gelu_f(pacc[q]), psum);
    }
    __syncthreads();
    red[g * 64 + wl] = psum;
    __syncthreads();
    if (g == 0) {
        float v = red[wl] + red[64 + wl] + red[128 + wl] + red[192 + wl] + pb2[0];
        out[(b * 256 + hh) * 256 + w0 + wl] = v;
    }
}

extern "C" void kernel_launch(void* const* d_in, const int* in_sizes, int n_in,
                              void* d_out, int out_size, void* d_ws, size_t ws_size,
                              hipStream_t stream) {
    const float* x          = (const float*)d_in[0];
    const float2* sw1       = (const float2*)d_in[1];
    const float2* sw2       = (const float2*)d_in[2];
    const float* skip_w     = (const float*)d_in[3];
    const float* skip_b     = (const float*)d_in[4];
    const float* mlp_w1     = (const float*)d_in[5];
    const float* mlp_b1     = (const float*)d_in[6];
    const float* mlp_w2     = (const float*)d_in[7];
    const float* mlp_b2     = (const float*)d_in[8];
    const float* mlp_skip_w = (const float*)d_in[9];
    const float* mlp_skip_b = (const float*)d_in[10];
    const float* proj_w1    = (const float*)d_in[11];
    const float* proj_b1    = (const float*)d_in[12];
    const float* proj_w2    = (const float*)d_in[13];
    const float* proj_b2    = (const float*)d_in[14];

    float* ws = (float*)d_ws;
    float* XA = ws + OFF_XA;
    float* XB = ws + OFF_XB;
    float2* Z1 = (float2*)(ws + OFF_Z1);
    float2* XF = (float2*)(ws + OFF_XF);
    float2* OF = (float2*)(ws + OFF_OF);
    const float2* TWW  = (const float2*)(ws + OFF_TWW);
    const float2* TWWT = (const float2*)(ws + OFF_TWWT);
    const float2* TH   = (const float2*)(ws + OFF_TH);

    init_tw<<<96, 256, 0, stream>>>(ws);

    const float* cur = x;
    for (int l = 0; l < 2; ++l) {
        k_fwd_w<<<4096, 256, 0, stream>>>(cur, Z1, TWW);
        k_fwd_h<<<256, 256, 0, stream>>>(Z1, XF, TH);
        k_modemul<<<dim3(64, 64), 128, 0, stream>>>(XF, sw1, sw2, OF, l);
        k_inv_h<<<256, 256, 0, stream>>>(OF, Z1, TH);
        k_invw_skip<<<dim3(4, 256, 4), 256, 0, stream>>>(Z1, cur, skip_w, skip_b, TWWT, XA, l);
        k_mlp<<<dim3(4, 256, 4), 256, 0, stream>>>(XA, mlp_w1, mlp_b1, mlp_w2, mlp_b2,
                                                   mlp_skip_w, mlp_skip_b, XB, l);
        cur = XB;
    }
    k_proj<<<dim3(4, 256, 4), 256, 0, stream>>>(XB, proj_w1, proj_b1, proj_w2, proj_b2,
                                                (float*)d_out);
}

// Round 2
// 1463.897 us; speedup vs baseline: 1.6482x; 1.6482x over previous
//
#include <hip/hip_runtime.h>
#include <math.h>

// Problem constants: B=4, C=64, H=256, W=256, L=2, M1=M2=32, HM=128, P=256, O=1

// workspace layout (in floats)
#define OFF_XA   0                      // 16777216 floats
#define OFF_XB   16777216               // 16777216
#define OFF_Z1   33554432               // 4194304 (float2[2097152]) : X1 / Z reuse
#define OFF_XF   37748736               // 1048576 (float2[524288])
#define OFF_OF   38797312               // 1048576
#define OFF_TWW  39845888               // float2[8192]  [w][kx]
#define OFF_TWWT 39862272               // float2[8192]  [kx][w]
#define OFF_TH   39878656               // float2[16384] [j][h]   ky_j = j<32? j : 192+j
#define OFF_WBF  39911424               // ushort[57344] bf16 weights (28672 floats)
// total = 39940096 floats ≈ 152.4 MiB

typedef __attribute__((ext_vector_type(8))) short short8b;   // 8 bf16 (4 VGPRs)
typedef __attribute__((ext_vector_type(4))) float f32x4;     // MFMA acc

__device__ __forceinline__ float gelu_f(float v) {
    // sigmoid form of tanh-GELU: x * sigmoid(1.59577x + 0.07135x^3); max dev ~1.5e-4
    float u = v * fmaf(v * v, 0.0713548162f, 1.5957691216f);
    return v * __builtin_amdgcn_rcpf(1.0f + __expf(-u));
}

__device__ __forceinline__ unsigned short f2bf(float f) {
    unsigned int u = __float_as_uint(f);
    u += 0x7FFFu + ((u >> 16) & 1u);   // RNE
    return (unsigned short)(u >> 16);
}

__global__ __launch_bounds__(256) void init_tw(float* ws) {
    int idx = blockIdx.x * 256 + threadIdx.x;
    float2* tww  = (float2*)(ws + OFF_TWW);
    float2* twwt = (float2*)(ws + OFF_TWWT);
    float2* th   = (float2*)(ws + OFF_TH);
    if (idx < 8192) {
        int w = idx >> 5, kx = idx & 31;
        int m = (kx * w) & 255;
        double a = (double)m * (3.14159265358979323846 / 128.0);
        float c = (float)cos(a), s = (float)sin(a);
        tww[w * 32 + kx]  = make_float2(c, s);
        twwt[kx * 256 + w] = make_float2(c, s);
    }
    int idx2 = idx - 8192;
    if (idx2 >= 0 && idx2 < 16384) {
        int j = idx2 >> 8, h = idx2 & 255;
        int ky = (j < 32) ? j : (192 + j);
        int m = (ky * h) & 255;
        double a = (double)m * (3.14159265358979323846 / 128.0);
        th[j * 256 + h] = make_float2((float)cos(a), (float)sin(a));
    }
}

// convert MLP/proj weights to bf16 once: [W1 2x128x64][W2 2x64x128][Wsk 2x64x64][PW1 256x64]
__global__ __launch_bounds__(256) void k_cvt(const float* __restrict__ w1,
                                             const float* __restrict__ w2,
                                             const float* __restrict__ wsk,
                                             const float* __restrict__ pw1,
                                             unsigned short* __restrict__ wb) {
    int idx = blockIdx.x * 256 + threadIdx.x;
    if (idx < 16384)       wb[idx] = f2bf(w1[idx]);
    else if (idx < 32768)  wb[idx] = f2bf(w2[idx - 16384]);
    else if (idx < 40960)  wb[idx] = f2bf(wsk[idx - 32768]);
    else if (idx < 57344)  wb[idx] = f2bf(pw1[idx - 40960]);
}

// ---- forward DFT over W
__global__ __launch_bounds__(256) void k_fwd_w(const float* __restrict__ x,
                                               float2* __restrict__ X1,
                                               const float2* __restrict__ tww) {
    __shared__ float xs[16 * 256];
    __shared__ float2 tcs[8192];
    int tid = threadIdx.x;
    int row0 = blockIdx.x * 16;
    for (int i = tid; i < 8192; i += 256) tcs[i] = tww[i];
    for (int i = tid; i < 4096; i += 256) xs[i] = x[row0 * 256 + i];
    __syncthreads();
    int kx = tid & 31, rr = tid >> 5;
    float ar0 = 0.f, ai0 = 0.f, ar1 = 0.f, ai1 = 0.f;
    const float* xr0 = &xs[rr * 256];
    const float* xr1 = &xs[(rr + 8) * 256];
    for (int w = 0; w < 256; ++w) {
        float2 cs = tcs[w * 32 + kx];
        float x0 = xr0[w], x1 = xr1[w];
        ar0 = fmaf(x0, cs.x, ar0);  ai0 = fmaf(x0, -cs.y, ai0);
        ar1 = fmaf(x1, cs.x, ar1);  ai1 = fmaf(x1, -cs.y, ai1);
    }
    X1[(row0 + rr) * 32 + kx]     = make_float2(ar0, ai0);
    X1[(row0 + rr + 8) * 32 + kx] = make_float2(ar1, ai1);
}

// ---- forward DFT over H
__global__ __launch_bounds__(256) void k_fwd_h(const float2* __restrict__ X1,
                                               float2* __restrict__ XF,
                                               const float2* __restrict__ th) {
    __shared__ float2 xs[8192];
    int tid = threadIdx.x, plane = blockIdx.x;
    for (int i = tid; i < 8192; i += 256) xs[i] = X1[plane * 8192 + i];
    __syncthreads();
    int kx = tid & 31, j0 = tid >> 5;
    for (int q = 0; q < 8; ++q) {
        int j = j0 + 8 * q;
        const float2* tr = &th[j * 256];
        float ar = 0.f, ai = 0.f;
        for (int hh = 0; hh < 256; ++hh) {
            float2 xv = xs[hh * 32 + kx];
            float2 cs = tr[hh];
            ar = fmaf(xv.x, cs.x, fmaf(xv.y, cs.y, ar));
            ai = fmaf(xv.y, cs.x, fmaf(-xv.x, cs.y, ai));
        }
        XF[(plane * 64 + j) * 32 + kx] = make_float2(ar, ai);
    }
}

// ---- per-mode complex matmul
__global__ __launch_bounds__(128) void k_modemul(const float2* __restrict__ XF,
                                                 const float2* __restrict__ sw1,
                                                 const float2* __restrict__ sw2,
                                                 float2* __restrict__ OF, int l) {
    int o = blockIdx.x, j = blockIdx.y;
    int tid = threadIdx.x;
    int kx = tid & 31, b = tid >> 5;
    int jj = (j < 32) ? j : (j - 32);
    const float2* Wb = ((j < 32) ? sw1 : sw2) + (l * 4194304 + o * 1024 + jj * 32 + kx);
    const float2* Xb = XF + (b * 64 * 64 * 32 + j * 32 + kx);
    float ar = 0.f, ai = 0.f;
    for (int i = 0; i < 64; ++i) {
        float2 xv = Xb[i * 2048];
        float2 wv = Wb[i * 65536];
        ar += xv.x * wv.x - xv.y * wv.y;
        ai += xv.x * wv.y + xv.y * wv.x;
    }
    OF[((b * 64 + o) * 64 + j) * 32 + kx] = make_float2(ar, ai);
}

// ---- inverse DFT over H
__global__ __launch_bounds__(256) void k_inv_h(const float2* __restrict__ OF,
                                               float2* __restrict__ Z,
                                               const float2* __restrict__ th) {
    __shared__ float2 ofs[2048];
    int tid = threadIdx.x, plane = blockIdx.x;
    for (int i = tid; i < 2048; i += 256) ofs[i] = OF[plane * 2048 + i];
    __syncthreads();
    int kx = tid & 31, h0 = tid >> 5;
    for (int q = 0; q < 32; ++q) {
        int hh = h0 + 8 * q;
        float zr = 0.f, zi = 0.f;
        for (int j = 0; j < 64; ++j) {
            float2 ov = ofs[j * 32 + kx];
            float2 cs = th[j * 256 + hh];
            zr += ov.x * cs.x - ov.y * cs.y;
            zi += ov.y * cs.x + ov.x * cs.y;
        }
        Z[(plane * 256 + hh) * 32 + kx] = make_float2(zr, zi);
    }
}

// ---- fused inverse DFT over W (real) + channel skip conv + bias + GELU
__global__ __launch_bounds__(256) void k_invw_skip(const float2* __restrict__ Z,
                                                   const float* __restrict__ xin,
                                                   const float* __restrict__ skip_w,
                                                   const float* __restrict__ skip_b,
                                                   const float2* __restrict__ twwt,
                                                   float* __restrict__ xout, int l) {
    __shared__ float2 zs[2048];
    __shared__ float xsk[4096];
    __shared__ float swl[4096];
    __shared__ float2 twl[2048];
    int tid = threadIdx.x;
    int b = blockIdx.z, hh = blockIdx.y, w0 = blockIdx.x * 64;
    for (int i = tid; i < 2048; i += 256) {
        int o = i >> 5, kx = i & 31;
        zs[i] = Z[(b * 64 + o) * 8192 + hh * 32 + kx];
    }
    for (int i = tid; i < 4096; i += 256) {
        int ch = i >> 6, wl = i & 63;
        xsk[i] = xin[((b * 64 + ch) * 256 + hh) * 256 + w0 + wl];
        swl[i] = skip_w[l * 4096 + i];
    }
    for (int i = tid; i < 2048; i += 256) {
        int kx = i >> 6, wl = i & 63;
        twl[i] = twwt[kx * 256 + w0 + wl];
    }
    __syncthreads();
    int wl = tid & 63, g = tid >> 6;
    float sp[16];
#pragma unroll
    for (int q = 0; q < 16; ++q) sp[q] = 0.f;
    for (int kx = 1; kx < 32; ++kx) {
        float2 cs = twl[kx * 64 + wl];
#pragma unroll
        for (int q = 0; q < 16; ++q) {
            float2 zv = zs[(g + 4 * q) * 32 + kx];
            sp[q] += zv.x * cs.x - zv.y * cs.y;
        }
    }
#pragma unroll
    for (int q = 0; q < 16; ++q) {
        int o = g + 4 * q;
        sp[q] = (zs[o * 32].x + 2.f * sp[q]) * (1.f / 65536.f) + skip_b[l * 64 + o];
    }
    for (int i2 = 0; i2 < 64; ++i2) {
        float xv = xsk[i2 * 64 + wl];
#pragma unroll
        for (int q = 0; q < 16; ++q)
            sp[q] = fmaf(swl[(g + 4 * q) * 64 + i2], xv, sp[q]);
    }
#pragma unroll
    for (int q = 0; q < 16; ++q) {
        int o = g + 4 * q;
        xout[((b * 64 + o) * 256 + hh) * 256 + w0 + wl] = gelu_f(sp[q]);
    }
}

// ---- MFMA channel MLP: x2 = gelu(W2@gelu(W1@x+b1)+b2 + Wsk@x+bsk)
// block: 128 px, 4 waves; wave owns 32 px (2 tiles of 16). bf16 MFMA 16x16x32.
__global__ __launch_bounds__(256) void k_mlp(const float* __restrict__ xin,
                                             const unsigned short* __restrict__ wb,
                                             const float* __restrict__ b1,
                                             const float* __restrict__ b2,
                                             const float* __restrict__ bsk,
                                             float* __restrict__ xout, int l) {
    __shared__ __align__(16) unsigned short smemX[128 * 64];   // [px][ch] xor-swizzled octets
    __shared__ __align__(16) unsigned short smemH[128 * 128];  // [px][hm] xor-swizzled octets
    int t = threadIdx.x;
    int b = blockIdx.y;
    int p0 = blockIdx.x * 128;

    // stage X (fp32 global -> bf16 LDS), 16B writes
    {
        int pxs = t & 127;
        int cb = (t >> 7) * 8;
        const float* xb = xin + (size_t)(b * 64) * 65536 + p0 + pxs;
#pragma unroll
        for (int pass = 0; pass < 4; ++pass) {
            int ch0 = pass * 16 + cb;
            float v[8];
#pragma unroll
            for (int i = 0; i < 8; ++i) v[i] = xb[(size_t)(ch0 + i) * 65536];
            uint4 pk;
            pk.x = (unsigned)f2bf(v[0]) | ((unsigned)f2bf(v[1]) << 16);
            pk.y = (unsigned)f2bf(v[2]) | ((unsigned)f2bf(v[3]) << 16);
            pk.z = (unsigned)f2bf(v[4]) | ((unsigned)f2bf(v[5]) << 16);
            pk.w = (unsigned)f2bf(v[6]) | ((unsigned)f2bf(v[7]) << 16);
            int blk = (ch0 >> 3) ^ (pxs & 7);
            *(uint4*)&smemX[pxs * 64 + blk * 8] = pk;
        }
    }
    __syncthreads();

    int lane = t & 63, wv = t >> 6;
    int col = lane & 15, grp = lane >> 4;

    // B-frags for X (per wave-private px tiles)
    short8b bx[2][2];
#pragma unroll
    for (int pxt = 0; pxt < 2; ++pxt)
#pragma unroll
        for (int kb = 0; kb < 2; ++kb) {
            int px = wv * 32 + pxt * 16 + col;
            int blk = (kb * 4 + grp) ^ (px & 7);
            bx[pxt][kb] = *(const short8b*)&smemX[px * 64 + blk * 8];
        }

    // fc1: h = gelu(W1@x + b1) -> smemH (wave-private px rows, no barrier needed)
    const unsigned short* W1p = wb + l * 8192;
#pragma unroll
    for (int ot = 0; ot < 8; ++ot) {
        short8b a0 = *(const short8b*)&W1p[(ot * 16 + col) * 64 + grp * 8];
        short8b a1 = *(const short8b*)&W1p[(ot * 16 + col) * 64 + 32 + grp * 8];
        int hm0 = ot * 16 + grp * 4;
        f32x4 bb = *(const f32x4*)&b1[l * 128 + hm0];
#pragma unroll
        for (int pxt = 0; pxt < 2; ++pxt) {
            f32x4 acc = bb;
            acc = __builtin_amdgcn_mfma_f32_16x16x32_bf16(a0, bx[pxt][0], acc, 0, 0, 0);
            acc = __builtin_amdgcn_mfma_f32_16x16x32_bf16(a1, bx[pxt][1], acc, 0, 0, 0);
            ushort4 hp;
            hp.x = f2bf(gelu_f(acc[0]));
            hp.y = f2bf(gelu_f(acc[1]));
            hp.z = f2bf(gelu_f(acc[2]));
            hp.w = f2bf(gelu_f(acc[3]));
            int px = wv * 32 + pxt * 16 + col;
            int blk = (hm0 >> 3) ^ (px & 7);
            *(ushort4*)&smemH[px * 128 + blk * 8 + (hm0 & 7)] = hp;
        }
    }

    // B-frags for h
    short8b bh[2][4];
#pragma unroll
    for (int pxt = 0; pxt < 2; ++pxt)
#pragma unroll
        for (int kb = 0; kb < 4; ++kb) {
            int px = wv * 32 + pxt * 16 + col;
            int blk = (kb * 4 + grp) ^ (px & 7);
            bh[pxt][kb] = *(const short8b*)&smemH[px * 128 + blk * 8];
        }

    // fc2 + skip: out = gelu(W2@h + Wsk@x + b2 + bsk)
    const unsigned short* W2p = wb + 16384 + l * 8192;
    const unsigned short* WSp = wb + 32768 + l * 4096;
#pragma unroll
    for (int ot = 0; ot < 4; ++ot) {
        int o0 = ot * 16 + grp * 4;
        f32x4 b2v = *(const f32x4*)&b2[l * 64 + o0];
        f32x4 bsv = *(const f32x4*)&bsk[l * 64 + o0];
        short8b a2[4], as[2];
#pragma unroll
        for (int kb = 0; kb < 4; ++kb)
            a2[kb] = *(const short8b*)&W2p[(ot * 16 + col) * 128 + kb * 32 + grp * 8];
#pragma unroll
        for (int kb = 0; kb < 2; ++kb)
            as[kb] = *(const short8b*)&WSp[(ot * 16 + col) * 64 + kb * 32 + grp * 8];
#pragma unroll
        for (int pxt = 0; pxt < 2; ++pxt) {
            f32x4 acc = b2v + bsv;
#pragma unroll
            for (int kb = 0; kb < 4; ++kb)
                acc = __builtin_amdgcn_mfma_f32_16x16x32_bf16(a2[kb], bh[pxt][kb], acc, 0, 0, 0);
#pragma unroll
            for (int kb = 0; kb < 2; ++kb)
                acc = __builtin_amdgcn_mfma_f32_16x16x32_bf16(as[kb], bx[pxt][kb], acc, 0, 0, 0);
            int px = wv * 32 + pxt * 16 + col;
            float* op = xout + (size_t)(b * 64 + o0) * 65536 + p0 + px;
            op[0]          = gelu_f(acc[0]);
            op[65536]      = gelu_f(acc[1]);
            op[2 * 65536]  = gelu_f(acc[2]);
            op[3 * 65536]  = gelu_f(acc[3]);
        }
    }
}

// ---- MFMA projection: out = PW2 @ gelu(PW1@x + pb1) + pb2  (O=1)
__global__ __launch_bounds__(256) void k_proj(const float* __restrict__ xin,
                                              const unsigned short* __restrict__ wb,
                                              const float* __restrict__ pb1,
                                              const float* __restrict__ pw2,
                                              const float* __restrict__ pb2,
                                              float* __restrict__ out) {
    __shared__ __align__(16) unsigned short smemX[128 * 64];
    int t = threadIdx.x;
    int b = blockIdx.y;
    int p0 = blockIdx.x * 128;
    {
        int pxs = t & 127;
        int cb = (t >> 7) * 8;
        const float* xb = xin + (size_t)(b * 64) * 65536 + p0 + pxs;
#pragma unroll
        for (int pass = 0; pass < 4; ++pass) {
            int ch0 = pass * 16 + cb;
            float v[8];
#pragma unroll
            for (int i = 0; i < 8; ++i) v[i] = xb[(size_t)(ch0 + i) * 65536];
            uint4 pk;
            pk.x = (unsigned)f2bf(v[0]) | ((unsigned)f2bf(v[1]) << 16);
            pk.y = (unsigned)f2bf(v[2]) | ((unsigned)f2bf(v[3]) << 16);
            pk.z = (unsigned)f2bf(v[4]) | ((unsigned)f2bf(v[5]) << 16);
            pk.w = (unsigned)f2bf(v[6]) | ((unsigned)f2bf(v[7]) << 16);
            int blk = (ch0 >> 3) ^ (pxs & 7);
            *(uint4*)&smemX[pxs * 64 + blk * 8] = pk;
        }
    }
    __syncthreads();

    int lane = t & 63, wv = t >> 6;
    int col = lane & 15, grp = lane >> 4;

    short8b bx[2][2];
#pragma unroll
    for (int pxt = 0; pxt < 2; ++pxt)
#pragma unroll
        for (int kb = 0; kb < 2; ++kb) {
            int px = wv * 32 + pxt * 16 + col;
            int blk = (kb * 4 + grp) ^ (px & 7);
            bx[pxt][kb] = *(const short8b*)&smemX[px * 64 + blk * 8];
        }

    const unsigned short* P1p = wb + 40960;
    float psum0 = 0.f, psum1 = 0.f;
#pragma unroll
    for (int ot = 0; ot < 16; ++ot) {
        short8b a0 = *(const short8b*)&P1p[(ot * 16 + col) * 64 + grp * 8];
        short8b a1 = *(const short8b*)&P1p[(ot * 16 + col) * 64 + 32 + grp * 8];
        int o0 = ot * 16 + grp * 4;
        f32x4 b1v = *(const f32x4*)&pb1[o0];
        f32x4 w2v = *(const f32x4*)&pw2[o0];
        {
            f32x4 acc = b1v;
            acc = __builtin_amdgcn_mfma_f32_16x16x32_bf16(a0, bx[0][0], acc, 0, 0, 0);
            acc = __builtin_amdgcn_mfma_f32_16x16x32_bf16(a1, bx[0][1], acc, 0, 0, 0);
            psum0 += w2v[0] * gelu_f(acc[0]) + w2v[1] * gelu_f(acc[1])
                   + w2v[2] * gelu_f(acc[2]) + w2v[3] * gelu_f(acc[3]);
        }
        {
            f32x4 acc = b1v;
            acc = __builtin_amdgcn_mfma_f32_16x16x32_bf16(a0, bx[1][0], acc, 0, 0, 0);
            acc = __builtin_amdgcn_mfma_f32_16x16x32_bf16(a1, bx[1][1], acc, 0, 0, 0);
            psum1 += w2v[0] * gelu_f(acc[0]) + w2v[1] * gelu_f(acc[1])
                   + w2v[2] * gelu_f(acc[2]) + w2v[3] * gelu_f(acc[3]);
        }
    }
    psum0 += __shfl_xor(psum0, 16);
    psum0 += __shfl_xor(psum0, 32);
    psum1 += __shfl_xor(psum1, 16);
    psum1 += __shfl_xor(psum1, 32);
    if (grp == 0) {
        float bias = pb2[0];
        out[(size_t)b * 65536 + p0 + wv * 32 + col] = psum0 + bias;
        out[(size_t)b * 65536 + p0 + wv * 32 + 16 + col] = psum1 + bias;
    }
}

extern "C" void kernel_launch(void* const* d_in, const int* in_sizes, int n_in,
                              void* d_out, int out_size, void* d_ws, size_t ws_size,
                              hipStream_t stream) {
    const float* x          = (const float*)d_in[0];
    const float2* sw1       = (const float2*)d_in[1];
    const float2* sw2       = (const float2*)d_in[2];
    const float* skip_w     = (const float*)d_in[3];
    const float* skip_b     = (const float*)d_in[4];
    const float* mlp_w1     = (const float*)d_in[5];
    const float* mlp_b1     = (const float*)d_in[6];
    const float* mlp_w2     = (const float*)d_in[7];
    const float* mlp_b2     = (const float*)d_in[8];
    const float* mlp_skip_w = (const float*)d_in[9];
    const float* mlp_skip_b = (const float*)d_in[10];
    const float* proj_w1    = (const float*)d_in[11];
    const float* proj_b1    = (const float*)d_in[12];
    const float* proj_w2    = (const float*)d_in[13];
    const float* proj_b2    = (const float*)d_in[14];

    float* ws = (float*)d_ws;
    float* XA = ws + OFF_XA;
    float* XB = ws + OFF_XB;
    float2* Z1 = (float2*)(ws + OFF_Z1);
    float2* XF = (float2*)(ws + OFF_XF);
    float2* OF = (float2*)(ws + OFF_OF);
    const float2* TWW  = (const float2*)(ws + OFF_TWW);
    const float2* TWWT = (const float2*)(ws + OFF_TWWT);
    const float2* TH   = (const float2*)(ws + OFF_TH);
    unsigned short* WB = (unsigned short*)(ws + OFF_WBF);

    init_tw<<<96, 256, 0, stream>>>(ws);
    k_cvt<<<224, 256, 0, stream>>>(mlp_w1, mlp_w2, mlp_skip_w, proj_w1, WB);

    const float* cur = x;
    for (int l = 0; l < 2; ++l) {
        k_fwd_w<<<4096, 256, 0, stream>>>(cur, Z1, TWW);
        k_fwd_h<<<256, 256, 0, stream>>>(Z1, XF, TH);
        k_modemul<<<dim3(64, 64), 128, 0, stream>>>(XF, sw1, sw2, OF, l);
        k_inv_h<<<256, 256, 0, stream>>>(OF, Z1, TH);
        k_invw_skip<<<dim3(4, 256, 4), 256, 0, stream>>>(Z1, cur, skip_w, skip_b, TWWT, XA, l);
        k_mlp<<<dim3(512, 4), 256, 0, stream>>>(XA, WB, mlp_b1, mlp_b2, mlp_skip_b, XB, l);
        cur = XB;
    }
    k_proj<<<dim3(512, 4), 256, 0, stream>>>(XB, WB, proj_b1, proj_w2, proj_b2, (float*)d_out);
}

// Round 3
// 889.861 us; speedup vs baseline: 2.7114x; 1.6451x over previous
//
#include <hip/hip_runtime.h>
#include <math.h>

// Problem constants: B=4, C=64, H=256, W=256, L=2, M1=M2=32, HM=128, P=256, O=1

// workspace layout (in floats)
#define OFF_XA   0                      // 16777216 floats
#define OFF_XB   16777216               // 16777216
#define OFF_Z1   33554432               // 4194304 (float2[2097152]) : X1 / Z reuse
#define OFF_XF   37748736               // 1048576 (float2[524288])
#define OFF_OF   38797312               // 1048576
#define OFF_TWW  39845888               // float2[8192]  [w][kx]
#define OFF_TWWT 39862272               // float2[8192]  [kx][w]
#define OFF_TH   39878656               // float2[16384] [j][h]   ky_j = j<32? j : 192+j
#define OFF_WBF  39911424               // ushort[57344] bf16 weights (28672 floats)
#define OFF_ROOT 39940096               // float2[256] 256th roots of unity (512 floats)
// total = 39940608 floats ≈ 152.4 MiB

typedef __attribute__((ext_vector_type(8))) short short8b;   // 8 bf16 (4 VGPRs)
typedef __attribute__((ext_vector_type(4))) float f32x4;     // MFMA acc

__device__ __forceinline__ float gelu_f(float v) {
    // sigmoid form of tanh-GELU: x * sigmoid(1.59577x + 0.07135x^3); max dev ~1.5e-4
    float u = v * fmaf(v * v, 0.0713548162f, 1.5957691216f);
    return v * __builtin_amdgcn_rcpf(1.0f + __expf(-u));
}

__device__ __forceinline__ unsigned short f2bf(float f) {
    unsigned int u = __float_as_uint(f);
    u += 0x7FFFu + ((u >> 16) & 1u);   // RNE
    return (unsigned short)(u >> 16);
}

__global__ __launch_bounds__(256) void init_tw(float* ws) {
    int idx = blockIdx.x * 256 + threadIdx.x;
    float2* tww  = (float2*)(ws + OFF_TWW);
    float2* twwt = (float2*)(ws + OFF_TWWT);
    float2* th   = (float2*)(ws + OFF_TH);
    float2* root = (float2*)(ws + OFF_ROOT);
    if (idx < 256) {
        double a = (double)idx * (3.14159265358979323846 / 128.0);
        root[idx] = make_float2((float)cos(a), (float)sin(a));
    }
    if (idx < 8192) {
        int w = idx >> 5, kx = idx & 31;
        int m = (kx * w) & 255;
        double a = (double)m * (3.14159265358979323846 / 128.0);
        float c = (float)cos(a), s = (float)sin(a);
        tww[w * 32 + kx]  = make_float2(c, s);
        twwt[kx * 256 + w] = make_float2(c, s);
    }
    int idx2 = idx - 8192;
    if (idx2 >= 0 && idx2 < 16384) {
        int j = idx2 >> 8, h = idx2 & 255;
        int ky = (j < 32) ? j : (192 + j);
        int m = (ky * h) & 255;
        double a = (double)m * (3.14159265358979323846 / 128.0);
        th[j * 256 + h] = make_float2((float)cos(a), (float)sin(a));
    }
}

// convert MLP/proj weights to bf16 once: [W1 2x128x64][W2 2x64x128][Wsk 2x64x64][PW1 256x64]
__global__ __launch_bounds__(256) void k_cvt(const float* __restrict__ w1,
                                             const float* __restrict__ w2,
                                             const float* __restrict__ wsk,
                                             const float* __restrict__ pw1,
                                             unsigned short* __restrict__ wb) {
    int idx = blockIdx.x * 256 + threadIdx.x;
    if (idx < 16384)       wb[idx] = f2bf(w1[idx]);
    else if (idx < 32768)  wb[idx] = f2bf(w2[idx - 16384]);
    else if (idx < 40960)  wb[idx] = f2bf(wsk[idx - 32768]);
    else if (idx < 57344)  wb[idx] = f2bf(pw1[idx - 40960]);
}

// ---- forward DFT over W: x[row][w] -> X1[row][kx] complex (exp(-i th))
// 32 rows/block, 2048 blocks. Twiddles from 256-entry root table (2 KB LDS):
// factor(w,kx) = conj(root[(kx*w)&255]). Even w from table, odd w by one rotation.
__global__ __launch_bounds__(256) void k_fwd_w(const float* __restrict__ x,
                                               float2* __restrict__ X1,
                                               const float2* __restrict__ root) {
    __shared__ float xs[32 * 256];     // 32 KB
    __shared__ float2 rl[256];         // 2 KB
    int tid = threadIdx.x;
    int row0 = blockIdx.x * 32;
    const float4* xg = (const float4*)x;
    for (int i = tid; i < 2048; i += 256) *(float4*)&xs[i * 4] = xg[(size_t)row0 * 64 + i];
    rl[tid & 255] = root[tid & 255];
    __syncthreads();
    int kx = tid & 31, rr = tid >> 5;   // rows rr + 8q
    float2 rk = rl[kx];
    float ar[4] = {0.f, 0.f, 0.f, 0.f}, ai[4] = {0.f, 0.f, 0.f, 0.f};
    int m = 0;                          // (kx * w) & 255 for even w
    for (int w2 = 0; w2 < 128; ++w2) {
        float2 c0 = rl[m];                       // w = 2*w2
        float c1x = c0.x * rk.x - c0.y * rk.y;   // w = 2*w2+1
        float c1y = c0.x * rk.y + c0.y * rk.x;
#pragma unroll
        for (int q = 0; q < 4; ++q) {
            float2 xv = *(const float2*)&xs[(rr + 8 * q) * 256 + 2 * w2];
            ar[q] += xv.x * c0.x + xv.y * c1x;
            ai[q] -= xv.x * c0.y + xv.y * c1y;
        }
        m = (m + 2 * kx) & 255;
    }
#pragma unroll
    for (int q = 0; q < 4; ++q)
        X1[(size_t)(row0 + rr + 8 * q) * 32 + kx] = make_float2(ar[q], ai[q]);
}

// ---- forward DFT over H: X1[plane][h][kx] -> XF[plane][j][kx], exp(-i th)
// grid (256 planes, 8 j-octs); X1 read from L2 (broadcast-folded), th slice in LDS
__global__ __launch_bounds__(256) void k_fwd_h(const float2* __restrict__ X1,
                                               float2* __restrict__ XF,
                                               const float2* __restrict__ th) {
    __shared__ float2 thl[8 * 256];    // 16 KB
    int tid = threadIdx.x;
    int plane = blockIdx.x, joct = blockIdx.y;
    for (int i = tid; i < 2048; i += 256) thl[i] = th[joct * 2048 + i];
    __syncthreads();
    int kx = tid & 31, g = tid >> 5;   // j = joct*8 + g
    const float2* Xp = X1 + (size_t)plane * 8192 + kx;
    const float2* tr = &thl[g * 256];
    float ar = 0.f, ai = 0.f;
#pragma unroll 16
    for (int hh = 0; hh < 256; ++hh) {
        float2 xv = Xp[hh * 32];
        float2 cs = tr[hh];
        ar = fmaf(xv.x, cs.x, fmaf(xv.y, cs.y, ar));
        ai = fmaf(xv.y, cs.x, fmaf(-xv.x, cs.y, ai));
    }
    XF[(size_t)plane * 2048 + (joct * 8 + g) * 32 + kx] = make_float2(ar, ai);
}

// ---- per-mode complex matmul
__global__ __launch_bounds__(128) void k_modemul(const float2* __restrict__ XF,
                                                 const float2* __restrict__ sw1,
                                                 const float2* __restrict__ sw2,
                                                 float2* __restrict__ OF, int l) {
    int o = blockIdx.x, j = blockIdx.y;
    int tid = threadIdx.x;
    int kx = tid & 31, b = tid >> 5;
    int jj = (j < 32) ? j : (j - 32);
    const float2* Wb = ((j < 32) ? sw1 : sw2) + (l * 4194304 + o * 1024 + jj * 32 + kx);
    const float2* Xb = XF + (b * 64 * 64 * 32 + j * 32 + kx);
    float ar = 0.f, ai = 0.f;
    for (int i = 0; i < 64; ++i) {
        float2 xv = Xb[i * 2048];
        float2 wv = Wb[i * 65536];
        ar += xv.x * wv.x - xv.y * wv.y;
        ai += xv.x * wv.y + xv.y * wv.x;
    }
    OF[((b * 64 + o) * 64 + j) * 32 + kx] = make_float2(ar, ai);
}

// ---- inverse DFT over H: Z[plane][h][kx] = sum_j OF[plane][j][kx] * exp(+i th)
// grid (256 planes, 8 h-octs); OF from L2 (broadcast-folded), th slice in LDS
__global__ __launch_bounds__(256) void k_inv_h(const float2* __restrict__ OF,
                                               float2* __restrict__ Z,
                                               const float2* __restrict__ th) {
    __shared__ float2 thl[64 * 32];    // [j][hl] 16 KB
    int tid = threadIdx.x;
    int plane = blockIdx.x, h0 = blockIdx.y * 32;
    for (int i = tid; i < 2048; i += 256) {
        int j = i >> 5, hl = i & 31;
        thl[i] = th[j * 256 + h0 + hl];
    }
    __syncthreads();
    int kx = tid & 31, g = tid >> 5;   // h = h0 + g + 8q
    const float2* Op = OF + (size_t)plane * 2048 + kx;
    float zr[4] = {0.f, 0.f, 0.f, 0.f}, zi[4] = {0.f, 0.f, 0.f, 0.f};
#pragma unroll 8
    for (int j = 0; j < 64; ++j) {
        float2 ov = Op[j * 32];
#pragma unroll
        for (int q = 0; q < 4; ++q) {
            float2 cs = thl[j * 32 + g + 8 * q];
            zr[q] += ov.x * cs.x - ov.y * cs.y;
            zi[q] += ov.y * cs.x + ov.x * cs.y;
        }
    }
#pragma unroll
    for (int q = 0; q < 4; ++q)
        Z[(size_t)plane * 8192 + (h0 + g + 8 * q) * 32 + kx] = make_float2(zr[q], zi[q]);
}

// ---- fused inverse DFT over W (real) + channel skip conv + bias + GELU
__global__ __launch_bounds__(256) void k_invw_skip(const float2* __restrict__ Z,
                                                   const float* __restrict__ xin,
                                                   const float* __restrict__ skip_w,
                                                   const float* __restrict__ skip_b,
                                                   const float2* __restrict__ twwt,
                                                   float* __restrict__ xout, int l) {
    __shared__ float2 zs[2048];
    __shared__ float xsk[4096];
    __shared__ float swl[4096];
    __shared__ float2 twl[2048];
    int tid = threadIdx.x;
    int b = blockIdx.z, hh = blockIdx.y, w0 = blockIdx.x * 64;
    for (int i = tid; i < 2048; i += 256) {
        int o = i >> 5, kx = i & 31;
        zs[i] = Z[(b * 64 + o) * 8192 + hh * 32 + kx];
    }
    for (int i = tid; i < 4096; i += 256) {
        int ch = i >> 6, wl = i & 63;
        xsk[i] = xin[((b * 64 + ch) * 256 + hh) * 256 + w0 + wl];
        swl[i] = skip_w[l * 4096 + i];
    }
    for (int i = tid; i < 2048; i += 256) {
        int kx = i >> 6, wl = i & 63;
        twl[i] = twwt[kx * 256 + w0 + wl];
    }
    __syncthreads();
    int wl = tid & 63, g = tid >> 6;
    float sp[16];
#pragma unroll
    for (int q = 0; q < 16; ++q) sp[q] = 0.f;
    for (int kx = 1; kx < 32; ++kx) {
        float2 cs = twl[kx * 64 + wl];
#pragma unroll
        for (int q = 0; q < 16; ++q) {
            float2 zv = zs[(g + 4 * q) * 32 + kx];
            sp[q] += zv.x * cs.x - zv.y * cs.y;
        }
    }
#pragma unroll
    for (int q = 0; q < 16; ++q) {
        int o = g + 4 * q;
        sp[q] = (zs[o * 32].x + 2.f * sp[q]) * (1.f / 65536.f) + skip_b[l * 64 + o];
    }
    for (int i2 = 0; i2 < 64; ++i2) {
        float xv = xsk[i2 * 64 + wl];
#pragma unroll
        for (int q = 0; q < 16; ++q)
            sp[q] = fmaf(swl[(g + 4 * q) * 64 + i2], xv, sp[q]);
    }
#pragma unroll
    for (int q = 0; q < 16; ++q) {
        int o = g + 4 * q;
        xout[((b * 64 + o) * 256 + hh) * 256 + w0 + wl] = gelu_f(sp[q]);
    }
}

// ---- MFMA channel MLP: x2 = gelu(W2@gelu(W1@x+b1)+b2 + Wsk@x+bsk)
__global__ __launch_bounds__(256) void k_mlp(const float* __restrict__ xin,
                                             const unsigned short* __restrict__ wb,
                                             const float* __restrict__ b1,
                                             const float* __restrict__ b2,
                                             const float* __restrict__ bsk,
                                             float* __restrict__ xout, int l) {
    __shared__ __align__(16) unsigned short smemX[128 * 64];   // [px][ch] xor-swizzled octets
    __shared__ __align__(16) unsigned short smemH[128 * 128];  // [px][hm] xor-swizzled octets
    int t = threadIdx.x;
    int b = blockIdx.y;
    int p0 = blockIdx.x * 128;

    {
        int pxs = t & 127;
        int cb = (t >> 7) * 8;
        const float* xb = xin + (size_t)(b * 64) * 65536 + p0 + pxs;
#pragma unroll
        for (int pass = 0; pass < 4; ++pass) {
            int ch0 = pass * 16 + cb;
            float v[8];
#pragma unroll
            for (int i = 0; i < 8; ++i) v[i] = xb[(size_t)(ch0 + i) * 65536];
            uint4 pk;
            pk.x = (unsigned)f2bf(v[0]) | ((unsigned)f2bf(v[1]) << 16);
            pk.y = (unsigned)f2bf(v[2]) | ((unsigned)f2bf(v[3]) << 16);
            pk.z = (unsigned)f2bf(v[4]) | ((unsigned)f2bf(v[5]) << 16);
            pk.w = (unsigned)f2bf(v[6]) | ((unsigned)f2bf(v[7]) << 16);
            int blk = (ch0 >> 3) ^ (pxs & 7);
            *(uint4*)&smemX[pxs * 64 + blk * 8] = pk;
        }
    }
    __syncthreads();

    int lane = t & 63, wv = t >> 6;
    int col = lane & 15, grp = lane >> 4;

    short8b bx[2][2];
#pragma unroll
    for (int pxt = 0; pxt < 2; ++pxt)
#pragma unroll
        for (int kb = 0; kb < 2; ++kb) {
            int px = wv * 32 + pxt * 16 + col;
            int blk = (kb * 4 + grp) ^ (px & 7);
            bx[pxt][kb] = *(const short8b*)&smemX[px * 64 + blk * 8];
        }

    const unsigned short* W1p = wb + l * 8192;
#pragma unroll
    for (int ot = 0; ot < 8; ++ot) {
        short8b a0 = *(const short8b*)&W1p[(ot * 16 + col) * 64 + grp * 8];
        short8b a1 = *(const short8b*)&W1p[(ot * 16 + col) * 64 + 32 + grp * 8];
        int hm0 = ot * 16 + grp * 4;
        f32x4 bb = *(const f32x4*)&b1[l * 128 + hm0];
#pragma unroll
        for (int pxt = 0; pxt < 2; ++pxt) {
            f32x4 acc = bb;
            acc = __builtin_amdgcn_mfma_f32_16x16x32_bf16(a0, bx[pxt][0], acc, 0, 0, 0);
            acc = __builtin_amdgcn_mfma_f32_16x16x32_bf16(a1, bx[pxt][1], acc, 0, 0, 0);
            ushort4 hp;
            hp.x = f2bf(gelu_f(acc[0]));
            hp.y = f2bf(gelu_f(acc[1]));
            hp.z = f2bf(gelu_f(acc[2]));
            hp.w = f2bf(gelu_f(acc[3]));
            int px = wv * 32 + pxt * 16 + col;
            int blk = (hm0 >> 3) ^ (px & 7);
            *(ushort4*)&smemH[px * 128 + blk * 8 + (hm0 & 7)] = hp;
        }
    }

    short8b bh[2][4];
#pragma unroll
    for (int pxt = 0; pxt < 2; ++pxt)
#pragma unroll
        for (int kb = 0; kb < 4; ++kb) {
            int px = wv * 32 + pxt * 16 + col;
            int blk = (kb * 4 + grp) ^ (px & 7);
            bh[pxt][kb] = *(const short8b*)&smemH[px * 128 + blk * 8];
        }

    const unsigned short* W2p = wb + 16384 + l * 8192;
    const unsigned short* WSp = wb + 32768 + l * 4096;
#pragma unroll
    for (int ot = 0; ot < 4; ++ot) {
        int o0 = ot * 16 + grp * 4;
        f32x4 b2v = *(const f32x4*)&b2[l * 64 + o0];
        f32x4 bsv = *(const f32x4*)&bsk[l * 64 + o0];
        short8b a2[4], as[2];
#pragma unroll
        for (int kb = 0; kb < 4; ++kb)
            a2[kb] = *(const short8b*)&W2p[(ot * 16 + col) * 128 + kb * 32 + grp * 8];
#pragma unroll
        for (int kb = 0; kb < 2; ++kb)
            as[kb] = *(const short8b*)&WSp[(ot * 16 + col) * 64 + kb * 32 + grp * 8];
#pragma unroll
        for (int pxt = 0; pxt < 2; ++pxt) {
            f32x4 acc = b2v + bsv;
#pragma unroll
            for (int kb = 0; kb < 4; ++kb)
                acc = __builtin_amdgcn_mfma_f32_16x16x32_bf16(a2[kb], bh[pxt][kb], acc, 0, 0, 0);
#pragma unroll
            for (int kb = 0; kb < 2; ++kb)
                acc = __builtin_amdgcn_mfma_f32_16x16x32_bf16(as[kb], bx[pxt][kb], acc, 0, 0, 0);
            int px = wv * 32 + pxt * 16 + col;
            float* op = xout + (size_t)(b * 64 + o0) * 65536 + p0 + px;
            op[0]          = gelu_f(acc[0]);
            op[65536]      = gelu_f(acc[1]);
            op[2 * 65536]  = gelu_f(acc[2]);
            op[3 * 65536]  = gelu_f(acc[3]);
        }
    }
}

// ---- MFMA projection: out = PW2 @ gelu(PW1@x + pb1) + pb2  (O=1)
__global__ __launch_bounds__(256) void k_proj(const float* __restrict__ xin,
                                              const unsigned short* __restrict__ wb,
                                              const float* __restrict__ pb1,
                                              const float* __restrict__ pw2,
                                              const float* __restrict__ pb2,
                                              float* __restrict__ out) {
    __shared__ __align__(16) unsigned short smemX[128 * 64];
    int t = threadIdx.x;
    int b = blockIdx.y;
    int p0 = blockIdx.x * 128;
    {
        int pxs = t & 127;
        int cb = (t >> 7) * 8;
        const float* xb = xin + (size_t)(b * 64) * 65536 + p0 + pxs;
#pragma unroll
        for (int pass = 0; pass < 4; ++pass) {
            int ch0 = pass * 16 + cb;
            float v[8];
#pragma unroll
            for (int i = 0; i < 8; ++i) v[i] = xb[(size_t)(ch0 + i) * 65536];
            uint4 pk;
            pk.x = (unsigned)f2bf(v[0]) | ((unsigned)f2bf(v[1]) << 16);
            pk.y = (unsigned)f2bf(v[2]) | ((unsigned)f2bf(v[3]) << 16);
            pk.z = (unsigned)f2bf(v[4]) | ((unsigned)f2bf(v[5]) << 16);
            pk.w = (unsigned)f2bf(v[6]) | ((unsigned)f2bf(v[7]) << 16);
            int blk = (ch0 >> 3) ^ (pxs & 7);
            *(uint4*)&smemX[pxs * 64 + blk * 8] = pk;
        }
    }
    __syncthreads();

    int lane = t & 63, wv = t >> 6;
    int col = lane & 15, grp = lane >> 4;

    short8b bx[2][2];
#pragma unroll
    for (int pxt = 0; pxt < 2; ++pxt)
#pragma unroll
        for (int kb = 0; kb < 2; ++kb) {
            int px = wv * 32 + pxt * 16 + col;
            int blk = (kb * 4 + grp) ^ (px & 7);
            bx[pxt][kb] = *(const short8b*)&smemX[px * 64 + blk * 8];
        }

    const unsigned short* P1p = wb + 40960;
    float psum0 = 0.f, psum1 = 0.f;
#pragma unroll
    for (int ot = 0; ot < 16; ++ot) {
        short8b a0 = *(const short8b*)&P1p[(ot * 16 + col) * 64 + grp * 8];
        short8b a1 = *(const short8b*)&P1p[(ot * 16 + col) * 64 + 32 + grp * 8];
        int o0 = ot * 16 + grp * 4;
        f32x4 b1v = *(const f32x4*)&pb1[o0];
        f32x4 w2v = *(const f32x4*)&pw2[o0];
        {
            f32x4 acc = b1v;
            acc = __builtin_amdgcn_mfma_f32_16x16x32_bf16(a0, bx[0][0], acc, 0, 0, 0);
            acc = __builtin_amdgcn_mfma_f32_16x16x32_bf16(a1, bx[0][1], acc, 0, 0, 0);
            psum0 += w2v[0] * gelu_f(acc[0]) + w2v[1] * gelu_f(acc[1])
                   + w2v[2] * gelu_f(acc[2]) + w2v[3] * gelu_f(acc[3]);
        }
        {
            f32x4 acc = b1v;
            acc = __builtin_amdgcn_mfma_f32_16x16x32_bf16(a0, bx[1][0], acc, 0, 0, 0);
            acc = __builtin_amdgcn_mfma_f32_16x16x32_bf16(a1, bx[1][1], acc, 0, 0, 0);
            psum1 += w2v[0] * gelu_f(acc[0]) + w2v[1] * gelu_f(acc[1])
                   + w2v[2] * gelu_f(acc[2]) + w2v[3] * gelu_f(acc[3]);
        }
    }
    psum0 += __shfl_xor(psum0, 16);
    psum0 += __shfl_xor(psum0, 32);
    psum1 += __shfl_xor(psum1, 16);
    psum1 += __shfl_xor(psum1, 32);
    if (grp == 0) {
        float bias = pb2[0];
        out[(size_t)b * 65536 + p0 + wv * 32 + col] = psum0 + bias;
        out[(size_t)b * 65536 + p0 + wv * 32 + 16 + col] = psum1 + bias;
    }
}

extern "C" void kernel_launch(void* const* d_in, const int* in_sizes, int n_in,
                              void* d_out, int out_size, void* d_ws, size_t ws_size,
                              hipStream_t stream) {
    const float* x          = (const float*)d_in[0];
    const float2* sw1       = (const float2*)d_in[1];
    const float2* sw2       = (const float2*)d_in[2];
    const float* skip_w     = (const float*)d_in[3];
    const float* skip_b     = (const float*)d_in[4];
    const float* mlp_w1     = (const float*)d_in[5];
    const float* mlp_b1     = (const float*)d_in[6];
    const float* mlp_w2     = (const float*)d_in[7];
    const float* mlp_b2     = (const float*)d_in[8];
    const float* mlp_skip_w = (const float*)d_in[9];
    const float* mlp_skip_b = (const float*)d_in[10];
    const float* proj_w1    = (const float*)d_in[11];
    const float* proj_b1    = (const float*)d_in[12];
    const float* proj_w2    = (const float*)d_in[13];
    const float* proj_b2    = (const float*)d_in[14];

    float* ws = (float*)d_ws;
    float* XA = ws + OFF_XA;
    float* XB = ws + OFF_XB;
    float2* Z1 = (float2*)(ws + OFF_Z1);
    float2* XF = (float2*)(ws + OFF_XF);
    float2* OF = (float2*)(ws + OFF_OF);
    const float2* TWWT = (const float2*)(ws + OFF_TWWT);
    const float2* TH   = (const float2*)(ws + OFF_TH);
    const float2* ROOT = (const float2*)(ws + OFF_ROOT);
    unsigned short* WB = (unsigned short*)(ws + OFF_WBF);

    init_tw<<<96, 256, 0, stream>>>(ws);
    k_cvt<<<224, 256, 0, stream>>>(mlp_w1, mlp_w2, mlp_skip_w, proj_w1, WB);

    const float* cur = x;
    for (int l = 0; l < 2; ++l) {
        k_fwd_w<<<2048, 256, 0, stream>>>(cur, Z1, ROOT);
        k_fwd_h<<<dim3(256, 8), 256, 0, stream>>>(Z1, XF, TH);
        k_modemul<<<dim3(64, 64), 128, 0, stream>>>(XF, sw1, sw2, OF, l);
        k_inv_h<<<dim3(256, 8), 256, 0, stream>>>(OF, Z1, TH);
        k_invw_skip<<<dim3(4, 256, 4), 256, 0, stream>>>(Z1, cur, skip_w, skip_b, TWWT, XA, l);
        k_mlp<<<dim3(512, 4), 256, 0, stream>>>(XA, WB, mlp_b1, mlp_b2, mlp_skip_b, XB, l);
        cur = XB;
    }
    k_proj<<<dim3(512, 4), 256, 0, stream>>>(XB, WB, proj_b1, proj_w2, proj_b2, (float*)d_out);
}

// Round 4
// 599.738 us; speedup vs baseline: 4.0231x; 1.4837x over previous
//
#include <hip/hip_runtime.h>
#include <math.h>

// Problem constants: B=4, C=64, H=256, W=256, L=2, M1=M2=32, HM=128, P=256, O=1

// workspace layout (in floats)
#define OFF_XA   0                      // 16777216 floats
#define OFF_XB   16777216               // 16777216
#define OFF_Z1   33554432               // 4194304 (float2[2097152]) : X1 / Z reuse
#define OFF_XF   37748736               // 1048576 (float2[524288])
#define OFF_OF   38797312               // 1048576
#define OFF_TH   39878656               // float2[16384] [j][h]   ky_j = j<32? j : 192+j
#define OFF_WBF  39911424               // ushort[65536] bf16 weights (32768 floats)
#define OFF_ROOT 39944192               // float2[256] (512 floats)
#define OFF_TBF  39944704               // ushort[16384] bf16 invW twiddle Tt[w][k] (8192 floats)
// total = 39952896 floats ≈ 152.4 MiB

// WB (ushort) layout: [0:16384) mlp_w1 | [16384:32768) mlp_w2 | [32768:40960) mlp_skip_w
//                     [40960:57344) proj_w1 | [57344:65536) spectral skip_w (2x64x64)

typedef __attribute__((ext_vector_type(8))) short short8b;   // 8 bf16 (4 VGPRs)
typedef __attribute__((ext_vector_type(4))) float f32x4;     // MFMA acc

__device__ __forceinline__ float gelu_f(float v) {
    // sigmoid form of tanh-GELU: x * sigmoid(1.59577x + 0.07135x^3); max dev ~1.5e-4
    float u = v * fmaf(v * v, 0.0713548162f, 1.5957691216f);
    return v * __builtin_amdgcn_rcpf(1.0f + __expf(-u));
}

__device__ __forceinline__ unsigned f2bf(float f) {
    unsigned int u = __float_as_uint(f);
    u += 0x7FFFu + ((u >> 16) & 1u);   // RNE
    return u >> 16;
}

__global__ __launch_bounds__(256) void init_tw(float* ws) {
    int idx = blockIdx.x * 256 + threadIdx.x;
    float2* th   = (float2*)(ws + OFF_TH);
    float2* root = (float2*)(ws + OFF_ROOT);
    unsigned short* tbf = (unsigned short*)(ws + OFF_TBF);
    if (idx < 256) {
        double a = (double)idx * (3.14159265358979323846 / 128.0);
        root[idx] = make_float2((float)cos(a), (float)sin(a));
    }
    if (idx < 16384) {
        // Tt[w][k]: k=2kx -> cos*sc, k=2kx+1 -> -sin*sc ; sc=(kx==0?1:2)/65536
        int w = idx >> 6, k = idx & 63;
        int kx = k >> 1;
        int m = (kx * w) & 255;
        double a = (double)m * (3.14159265358979323846 / 128.0);
        float sc = (kx == 0) ? (1.0f / 65536.0f) : (2.0f / 65536.0f);
        float v = (k & 1) ? (float)(-sin(a)) * sc : (float)cos(a) * sc;
        tbf[idx] = (unsigned short)f2bf(v);
    }
    int idx2 = idx - 8192;
    if (idx2 >= 0 && idx2 < 16384) {
        int j = idx2 >> 8, h = idx2 & 255;
        int ky = (j < 32) ? j : (192 + j);
        int m = (ky * h) & 255;
        double a = (double)m * (3.14159265358979323846 / 128.0);
        th[j * 256 + h] = make_float2((float)cos(a), (float)sin(a));
    }
}

// convert all GEMM weights to bf16 once
__global__ __launch_bounds__(256) void k_cvt(const float* __restrict__ w1,
                                             const float* __restrict__ w2,
                                             const float* __restrict__ wsk,
                                             const float* __restrict__ pw1,
                                             const float* __restrict__ ssk,
                                             unsigned short* __restrict__ wb) {
    int idx = blockIdx.x * 256 + threadIdx.x;
    if (idx < 16384)       wb[idx] = (unsigned short)f2bf(w1[idx]);
    else if (idx < 32768)  wb[idx] = (unsigned short)f2bf(w2[idx - 16384]);
    else if (idx < 40960)  wb[idx] = (unsigned short)f2bf(wsk[idx - 32768]);
    else if (idx < 57344)  wb[idx] = (unsigned short)f2bf(pw1[idx - 40960]);
    else if (idx < 65536)  wb[idx] = (unsigned short)f2bf(ssk[idx - 57344]);
}

// ---- forward DFT over W: x[row][w] -> X1[row][kx] complex (exp(-i th))
__global__ __launch_bounds__(256) void k_fwd_w(const float* __restrict__ x,
                                               float2* __restrict__ X1,
                                               const float2* __restrict__ root) {
    __shared__ float xs[32 * 256];     // 32 KB
    __shared__ float2 rl[256];         // 2 KB
    int tid = threadIdx.x;
    int row0 = blockIdx.x * 32;
    const float4* xg = (const float4*)x;
    for (int i = tid; i < 2048; i += 256) *(float4*)&xs[i * 4] = xg[(size_t)row0 * 64 + i];
    rl[tid & 255] = root[tid & 255];
    __syncthreads();
    int kx = tid & 31, rr = tid >> 5;   // rows rr + 8q
    float2 rk = rl[kx];
    float ar[4] = {0.f, 0.f, 0.f, 0.f}, ai[4] = {0.f, 0.f, 0.f, 0.f};
    int m = 0;                          // (kx * w) & 255 for even w
    for (int w2 = 0; w2 < 128; ++w2) {
        float2 c0 = rl[m];                       // w = 2*w2
        float c1x = c0.x * rk.x - c0.y * rk.y;   // w = 2*w2+1
        float c1y = c0.x * rk.y + c0.y * rk.x;
#pragma unroll
        for (int q = 0; q < 4; ++q) {
            float2 xv = *(const float2*)&xs[(rr + 8 * q) * 256 + 2 * w2];
            ar[q] += xv.x * c0.x + xv.y * c1x;
            ai[q] -= xv.x * c0.y + xv.y * c1y;
        }
        m = (m + 2 * kx) & 255;
    }
#pragma unroll
    for (int q = 0; q < 4; ++q)
        X1[(size_t)(row0 + rr + 8 * q) * 32 + kx] = make_float2(ar[q], ai[q]);
}

// ---- forward DFT over H: X1[plane][h][kx] -> XF[plane][j][kx], exp(-i th)
__global__ __launch_bounds__(256) void k_fwd_h(const float2* __restrict__ X1,
                                               float2* __restrict__ XF,
                                               const float2* __restrict__ th) {
    __shared__ float2 thl[8 * 256];    // 16 KB
    int tid = threadIdx.x;
    int plane = blockIdx.x, joct = blockIdx.y;
    for (int i = tid; i < 2048; i += 256) thl[i] = th[joct * 2048 + i];
    __syncthreads();
    int kx = tid & 31, g = tid >> 5;   // j = joct*8 + g
    const float2* Xp = X1 + (size_t)plane * 8192 + kx;
    const float2* tr = &thl[g * 256];
    float ar = 0.f, ai = 0.f;
#pragma unroll 16
    for (int hh = 0; hh < 256; ++hh) {
        float2 xv = Xp[hh * 32];
        float2 cs = tr[hh];
        ar = fmaf(xv.x, cs.x, fmaf(xv.y, cs.y, ar));
        ai = fmaf(xv.y, cs.x, fmaf(-xv.x, cs.y, ai));
    }
    XF[(size_t)plane * 2048 + (joct * 8 + g) * 32 + kx] = make_float2(ar, ai);
}

// ---- per-mode complex matmul
__global__ __launch_bounds__(128) void k_modemul(const float2* __restrict__ XF,
                                                 const float2* __restrict__ sw1,
                                                 const float2* __restrict__ sw2,
                                                 float2* __restrict__ OF, int l) {
    int o = blockIdx.x, j = blockIdx.y;
    int tid = threadIdx.x;
    int kx = tid & 31, b = tid >> 5;
    int jj = (j < 32) ? j : (j - 32);
    const float2* Wb = ((j < 32) ? sw1 : sw2) + (l * 4194304 + o * 1024 + jj * 32 + kx);
    const float2* Xb = XF + (b * 64 * 64 * 32 + j * 32 + kx);
    float ar = 0.f, ai = 0.f;
    for (int i = 0; i < 64; ++i) {
        float2 xv = Xb[i * 2048];
        float2 wv = Wb[i * 65536];
        ar += xv.x * wv.x - xv.y * wv.y;
        ai += xv.x * wv.y + xv.y * wv.x;
    }
    OF[((b * 64 + o) * 64 + j) * 32 + kx] = make_float2(ar, ai);
}

// ---- inverse DFT over H: Z[plane][h][kx] = sum_j OF[plane][j][kx] * exp(+i th)
__global__ __launch_bounds__(256) void k_inv_h(const float2* __restrict__ OF,
                                               float2* __restrict__ Z,
                                               const float2* __restrict__ th) {
    __shared__ float2 thl[64 * 32];    // [j][hl] 16 KB
    int tid = threadIdx.x;
    int plane = blockIdx.x, h0 = blockIdx.y * 32;
    for (int i = tid; i < 2048; i += 256) {
        int j = i >> 5, hl = i & 31;
        thl[i] = th[j * 256 + h0 + hl];
    }
    __syncthreads();
    int kx = tid & 31, g = tid >> 5;   // h = h0 + g + 8q
    const float2* Op = OF + (size_t)plane * 2048 + kx;
    float zr[4] = {0.f, 0.f, 0.f, 0.f}, zi[4] = {0.f, 0.f, 0.f, 0.f};
#pragma unroll 8
    for (int j = 0; j < 64; ++j) {
        float2 ov = Op[j * 32];
#pragma unroll
        for (int q = 0; q < 4; ++q) {
            float2 cs = thl[j * 32 + g + 8 * q];
            zr[q] += ov.x * cs.x - ov.y * cs.y;
            zi[q] += ov.y * cs.x + ov.x * cs.y;
        }
    }
#pragma unroll
    for (int q = 0; q < 4; ++q)
        Z[(size_t)plane * 8192 + (h0 + g + 8 * q) * 32 + kx] = make_float2(zr[q], zi[q]);
}

// ---- MFMA fused inverse-W DFT + channel skip + bias + GELU
// out[o,w] = gelu( sum_k Z2[o,k]*Tt[w,k] + sum_i skip_w[o,i]*x[i,w] + skip_b[o] )
// block = (hh, b); 4 waves, each owns a 64-w quadrant x all 64 o.
__global__ __launch_bounds__(256) void k_invw_skip(const float* __restrict__ Zf,
                                                   const float* __restrict__ xin,
                                                   const unsigned short* __restrict__ tbf,
                                                   const unsigned short* __restrict__ wsk,
                                                   const float* __restrict__ skip_b,
                                                   float* __restrict__ xout, int l) {
    __shared__ __align__(16) unsigned short smZ[64 * 64];    // [o][k] swizzled octets, 8 KB
    __shared__ __align__(16) unsigned short smX[256 * 64];   // [w][i] swizzled octets, 32 KB
    int t = threadIdx.x;
    int hh = blockIdx.x, b = blockIdx.y;

    // stage Z2 (float view of Z: [o] rows of 64 consecutive floats = interleaved re/im)
    {
        int o = t >> 2, seg = t & 3;
        const float* zp = Zf + ((size_t)(b * 64 + o) * 8192 + hh * 32) * 2 + seg * 16;
        float4 v0 = *(const float4*)(zp + 0);
        float4 v1 = *(const float4*)(zp + 4);
        float4 v2 = *(const float4*)(zp + 8);
        float4 v3 = *(const float4*)(zp + 12);
        uint4 pk0, pk1;
        pk0.x = f2bf(v0.x) | (f2bf(v0.y) << 16);
        pk0.y = f2bf(v0.z) | (f2bf(v0.w) << 16);
        pk0.z = f2bf(v1.x) | (f2bf(v1.y) << 16);
        pk0.w = f2bf(v1.z) | (f2bf(v1.w) << 16);
        pk1.x = f2bf(v2.x) | (f2bf(v2.y) << 16);
        pk1.y = f2bf(v2.z) | (f2bf(v2.w) << 16);
        pk1.z = f2bf(v3.x) | (f2bf(v3.y) << 16);
        pk1.w = f2bf(v3.z) | (f2bf(v3.w) << 16);
        int blk0 = (seg * 2) ^ (o & 7);
        int blk1 = (seg * 2 + 1) ^ (o & 7);
        *(uint4*)&smZ[o * 64 + blk0 * 8] = pk0;
        *(uint4*)&smZ[o * 64 + blk1 * 8] = pk1;
    }
    // stage X: thread owns w = t, converts all 64 channels
    {
        const float* xb = xin + (size_t)(b * 64) * 65536 + hh * 256 + t;
#pragma unroll
        for (int i0 = 0; i0 < 64; i0 += 8) {
            float v[8];
#pragma unroll
            for (int i = 0; i < 8; ++i) v[i] = xb[(size_t)(i0 + i) * 65536];
            uint4 pk;
            pk.x = f2bf(v[0]) | (f2bf(v[1]) << 16);
            pk.y = f2bf(v[2]) | (f2bf(v[3]) << 16);
            pk.z = f2bf(v[4]) | (f2bf(v[5]) << 16);
            pk.w = f2bf(v[6]) | (f2bf(v[7]) << 16);
            int blk = (i0 >> 3) ^ (t & 7);
            *(uint4*)&smX[t * 64 + blk * 8] = pk;
        }
    }
    __syncthreads();

    int lane = t & 63, wv = t >> 6;
    int col = lane & 15, grp = lane >> 4;
    int w0 = wv * 64;

    // B-frags: twiddle (L2-resident global) and x (LDS)
    short8b tf[4][2], bxf[4][2];
#pragma unroll
    for (int wt = 0; wt < 4; ++wt) {
        int w = w0 + wt * 16 + col;
#pragma unroll
        for (int kb = 0; kb < 2; ++kb) {
            tf[wt][kb] = *(const short8b*)&tbf[w * 64 + kb * 32 + grp * 8];
            int blk = (kb * 4 + grp) ^ (w & 7);
            bxf[wt][kb] = *(const short8b*)&smX[w * 64 + blk * 8];
        }
    }

    const unsigned short* WSp = wsk + l * 4096;
#pragma unroll
    for (int ot = 0; ot < 4; ++ot) {
        int o = ot * 16 + col;
        short8b az[2], ask[2];
#pragma unroll
        for (int kb = 0; kb < 2; ++kb) {
            int blk = (kb * 4 + grp) ^ (o & 7);
            az[kb] = *(const short8b*)&smZ[o * 64 + blk * 8];
            ask[kb] = *(const short8b*)&WSp[o * 64 + kb * 32 + grp * 8];
        }
        f32x4 bias = *(const f32x4*)&skip_b[l * 64 + ot * 16 + grp * 4];
#pragma unroll
        for (int wt = 0; wt < 4; ++wt) {
            f32x4 acc = bias;
            acc = __builtin_amdgcn_mfma_f32_16x16x32_bf16(az[0], tf[wt][0], acc, 0, 0, 0);
            acc = __builtin_amdgcn_mfma_f32_16x16x32_bf16(az[1], tf[wt][1], acc, 0, 0, 0);
            acc = __builtin_amdgcn_mfma_f32_16x16x32_bf16(ask[0], bxf[wt][0], acc, 0, 0, 0);
            acc = __builtin_amdgcn_mfma_f32_16x16x32_bf16(ask[1], bxf[wt][1], acc, 0, 0, 0);
            float* op = xout + (size_t)(b * 64 + ot * 16 + grp * 4) * 65536
                      + hh * 256 + w0 + wt * 16 + col;
            op[0]          = gelu_f(acc[0]);
            op[65536]      = gelu_f(acc[1]);
            op[2 * 65536]  = gelu_f(acc[2]);
            op[3 * 65536]  = gelu_f(acc[3]);
        }
    }
}

// ---- MFMA channel MLP: x2 = gelu(W2@gelu(W1@x+b1)+b2 + Wsk@x+bsk)
__global__ __launch_bounds__(256) void k_mlp(const float* __restrict__ xin,
                                             const unsigned short* __restrict__ wb,
                                             const float* __restrict__ b1,
                                             const float* __restrict__ b2,
                                             const float* __restrict__ bsk,
                                             float* __restrict__ xout, int l) {
    __shared__ __align__(16) unsigned short smemX[128 * 64];   // [px][ch] xor-swizzled octets
    __shared__ __align__(16) unsigned short smemH[128 * 128];  // [px][hm] xor-swizzled octets
    int t = threadIdx.x;
    int b = blockIdx.y;
    int p0 = blockIdx.x * 128;

    {
        int pxs = t & 127;
        int cb = (t >> 7) * 8;
        const float* xb = xin + (size_t)(b * 64) * 65536 + p0 + pxs;
#pragma unroll
        for (int pass = 0; pass < 4; ++pass) {
            int ch0 = pass * 16 + cb;
            float v[8];
#pragma unroll
            for (int i = 0; i < 8; ++i) v[i] = xb[(size_t)(ch0 + i) * 65536];
            uint4 pk;
            pk.x = f2bf(v[0]) | (f2bf(v[1]) << 16);
            pk.y = f2bf(v[2]) | (f2bf(v[3]) << 16);
            pk.z = f2bf(v[4]) | (f2bf(v[5]) << 16);
            pk.w = f2bf(v[6]) | (f2bf(v[7]) << 16);
            int blk = (ch0 >> 3) ^ (pxs & 7);
            *(uint4*)&smemX[pxs * 64 + blk * 8] = pk;
        }
    }
    __syncthreads();

    int lane = t & 63, wv = t >> 6;
    int col = lane & 15, grp = lane >> 4;

    short8b bx[2][2];
#pragma unroll
    for (int pxt = 0; pxt < 2; ++pxt)
#pragma unroll
        for (int kb = 0; kb < 2; ++kb) {
            int px = wv * 32 + pxt * 16 + col;
            int blk = (kb * 4 + grp) ^ (px & 7);
            bx[pxt][kb] = *(const short8b*)&smemX[px * 64 + blk * 8];
        }

    const unsigned short* W1p = wb + l * 8192;
#pragma unroll
    for (int ot = 0; ot < 8; ++ot) {
        short8b a0 = *(const short8b*)&W1p[(ot * 16 + col) * 64 + grp * 8];
        short8b a1 = *(const short8b*)&W1p[(ot * 16 + col) * 64 + 32 + grp * 8];
        int hm0 = ot * 16 + grp * 4;
        f32x4 bb = *(const f32x4*)&b1[l * 128 + hm0];
#pragma unroll
        for (int pxt = 0; pxt < 2; ++pxt) {
            f32x4 acc = bb;
            acc = __builtin_amdgcn_mfma_f32_16x16x32_bf16(a0, bx[pxt][0], acc, 0, 0, 0);
            acc = __builtin_amdgcn_mfma_f32_16x16x32_bf16(a1, bx[pxt][1], acc, 0, 0, 0);
            ushort4 hp;
            hp.x = (unsigned short)f2bf(gelu_f(acc[0]));
            hp.y = (unsigned short)f2bf(gelu_f(acc[1]));
            hp.z = (unsigned short)f2bf(gelu_f(acc[2]));
            hp.w = (unsigned short)f2bf(gelu_f(acc[3]));
            int px = wv * 32 + pxt * 16 + col;
            int blk = (hm0 >> 3) ^ (px & 7);
            *(ushort4*)&smemH[px * 128 + blk * 8 + (hm0 & 7)] = hp;
        }
    }

    short8b bh[2][4];
#pragma unroll
    for (int pxt = 0; pxt < 2; ++pxt)
#pragma unroll
        for (int kb = 0; kb < 4; ++kb) {
            int px = wv * 32 + pxt * 16 + col;
            int blk = (kb * 4 + grp) ^ (px & 7);
            bh[pxt][kb] = *(const short8b*)&smemH[px * 128 + blk * 8];
        }

    const unsigned short* W2p = wb + 16384 + l * 8192;
    const unsigned short* WSp = wb + 32768 + l * 4096;
#pragma unroll
    for (int ot = 0; ot < 4; ++ot) {
        int o0 = ot * 16 + grp * 4;
        f32x4 b2v = *(const f32x4*)&b2[l * 64 + o0];
        f32x4 bsv = *(const f32x4*)&bsk[l * 64 + o0];
        short8b a2[4], as[2];
#pragma unroll
        for (int kb = 0; kb < 4; ++kb)
            a2[kb] = *(const short8b*)&W2p[(ot * 16 + col) * 128 + kb * 32 + grp * 8];
#pragma unroll
        for (int kb = 0; kb < 2; ++kb)
            as[kb] = *(const short8b*)&WSp[(ot * 16 + col) * 64 + kb * 32 + grp * 8];
#pragma unroll
        for (int pxt = 0; pxt < 2; ++pxt) {
            f32x4 acc = b2v + bsv;
#pragma unroll
            for (int kb = 0; kb < 4; ++kb)
                acc = __builtin_amdgcn_mfma_f32_16x16x32_bf16(a2[kb], bh[pxt][kb], acc, 0, 0, 0);
#pragma unroll
            for (int kb = 0; kb < 2; ++kb)
                acc = __builtin_amdgcn_mfma_f32_16x16x32_bf16(as[kb], bx[pxt][kb], acc, 0, 0, 0);
            int px = wv * 32 + pxt * 16 + col;
            float* op = xout + (size_t)(b * 64 + o0) * 65536 + p0 + px;
            op[0]          = gelu_f(acc[0]);
            op[65536]      = gelu_f(acc[1]);
            op[2 * 65536]  = gelu_f(acc[2]);
            op[3 * 65536]  = gelu_f(acc[3]);
        }
    }
}

// ---- MFMA projection: out = PW2 @ gelu(PW1@x + pb1) + pb2  (O=1)
__global__ __launch_bounds__(256) void k_proj(const float* __restrict__ xin,
                                              const unsigned short* __restrict__ wb,
                                              const float* __restrict__ pb1,
                                              const float* __restrict__ pw2,
                                              const float* __restrict__ pb2,
                                              float* __restrict__ out) {
    __shared__ __align__(16) unsigned short smemX[128 * 64];
    int t = threadIdx.x;
    int b = blockIdx.y;
    int p0 = blockIdx.x * 128;
    {
        int pxs = t & 127;
        int cb = (t >> 7) * 8;
        const float* xb = xin + (size_t)(b * 64) * 65536 + p0 + pxs;
#pragma unroll
        for (int pass = 0; pass < 4; ++pass) {
            int ch0 = pass * 16 + cb;
            float v[8];
#pragma unroll
            for (int i = 0; i < 8; ++i) v[i] = xb[(size_t)(ch0 + i) * 65536];
            uint4 pk;
            pk.x = f2bf(v[0]) | (f2bf(v[1]) << 16);
            pk.y = f2bf(v[2]) | (f2bf(v[3]) << 16);
            pk.z = f2bf(v[4]) | (f2bf(v[5]) << 16);
            pk.w = f2bf(v[6]) | (f2bf(v[7]) << 16);
            int blk = (ch0 >> 3) ^ (pxs & 7);
            *(uint4*)&smemX[pxs * 64 + blk * 8] = pk;
        }
    }
    __syncthreads();

    int lane = t & 63, wv = t >> 6;
    int col = lane & 15, grp = lane >> 4;

    short8b bx[2][2];
#pragma unroll
    for (int pxt = 0; pxt < 2; ++pxt)
#pragma unroll
        for (int kb = 0; kb < 2; ++kb) {
            int px = wv * 32 + pxt * 16 + col;
            int blk = (kb * 4 + grp) ^ (px & 7);
            bx[pxt][kb] = *(const short8b*)&smemX[px * 64 + blk * 8];
        }

    const unsigned short* P1p = wb + 40960;
    float psum0 = 0.f, psum1 = 0.f;
#pragma unroll
    for (int ot = 0; ot < 16; ++ot) {
        short8b a0 = *(const short8b*)&P1p[(ot * 16 + col) * 64 + grp * 8];
        short8b a1 = *(const short8b*)&P1p[(ot * 16 + col) * 64 + 32 + grp * 8];
        int o0 = ot * 16 + grp * 4;
        f32x4 b1v = *(const f32x4*)&pb1[o0];
        f32x4 w2v = *(const f32x4*)&pw2[o0];
        {
            f32x4 acc = b1v;
            acc = __builtin_amdgcn_mfma_f32_16x16x32_bf16(a0, bx[0][0], acc, 0, 0, 0);
            acc = __builtin_amdgcn_mfma_f32_16x16x32_bf16(a1, bx[0][1], acc, 0, 0, 0);
            psum0 += w2v[0] * gelu_f(acc[0]) + w2v[1] * gelu_f(acc[1])
                   + w2v[2] * gelu_f(acc[2]) + w2v[3] * gelu_f(acc[3]);
        }
        {
            f32x4 acc = b1v;
            acc = __builtin_amdgcn_mfma_f32_16x16x32_bf16(a0, bx[1][0], acc, 0, 0, 0);
            acc = __builtin_amdgcn_mfma_f32_16x16x32_bf16(a1, bx[1][1], acc, 0, 0, 0);
            psum1 += w2v[0] * gelu_f(acc[0]) + w2v[1] * gelu_f(acc[1])
                   + w2v[2] * gelu_f(acc[2]) + w2v[3] * gelu_f(acc[3]);
        }
    }
    psum0 += __shfl_xor(psum0, 16);
    psum0 += __shfl_xor(psum0, 32);
    psum1 += __shfl_xor(psum1, 16);
    psum1 += __shfl_xor(psum1, 32);
    if (grp == 0) {
        float bias = pb2[0];
        out[(size_t)b * 65536 + p0 + wv * 32 + col] = psum0 + bias;
        out[(size_t)b * 65536 + p0 + wv * 32 + 16 + col] = psum1 + bias;
    }
}

extern "C" void kernel_launch(void* const* d_in, const int* in_sizes, int n_in,
                              void* d_out, int out_size, void* d_ws, size_t ws_size,
                              hipStream_t stream) {
    const float* x          = (const float*)d_in[0];
    const float2* sw1       = (const float2*)d_in[1];
    const float2* sw2       = (const float2*)d_in[2];
    const float* skip_w     = (const float*)d_in[3];
    const float* skip_b     = (const float*)d_in[4];
    const float* mlp_w1     = (const float*)d_in[5];
    const float* mlp_b1     = (const float*)d_in[6];
    const float* mlp_w2     = (const float*)d_in[7];
    const float* mlp_b2     = (const float*)d_in[8];
    const float* mlp_skip_w = (const float*)d_in[9];
    const float* mlp_skip_b = (const float*)d_in[10];
    const float* proj_w1    = (const float*)d_in[11];
    const float* proj_b1    = (const float*)d_in[12];
    const float* proj_w2    = (const float*)d_in[13];
    const float* proj_b2    = (const float*)d_in[14];

    float* ws = (float*)d_ws;
    float* XA = ws + OFF_XA;
    float* XB = ws + OFF_XB;
    float2* Z1 = (float2*)(ws + OFF_Z1);
    float2* XF = (float2*)(ws + OFF_XF);
    float2* OF = (float2*)(ws + OFF_OF);
    const float2* TH   = (const float2*)(ws + OFF_TH);
    const float2* ROOT = (const float2*)(ws + OFF_ROOT);
    const unsigned short* TBF = (const unsigned short*)(ws + OFF_TBF);
    unsigned short* WB = (unsigned short*)(ws + OFF_WBF);

    init_tw<<<96, 256, 0, stream>>>(ws);
    k_cvt<<<256, 256, 0, stream>>>(mlp_w1, mlp_w2, mlp_skip_w, proj_w1, skip_w, WB);

    const float* cur = x;
    for (int l = 0; l < 2; ++l) {
        k_fwd_w<<<2048, 256, 0, stream>>>(cur, Z1, ROOT);
        k_fwd_h<<<dim3(256, 8), 256, 0, stream>>>(Z1, XF, TH);
        k_modemul<<<dim3(64, 64), 128, 0, stream>>>(XF, sw1, sw2, OF, l);
        k_inv_h<<<dim3(256, 8), 256, 0, stream>>>(OF, Z1, TH);
        k_invw_skip<<<dim3(256, 4), 256, 0, stream>>>((const float*)Z1, cur, TBF,
                                                      WB + 57344, skip_b, XA, l);
        k_mlp<<<dim3(512, 4), 256, 0, stream>>>(XA, WB, mlp_b1, mlp_b2, mlp_skip_b, XB, l);
        cur = XB;
    }
    k_proj<<<dim3(512, 4), 256, 0, stream>>>(XB, WB, proj_b1, proj_w2, proj_b2, (float*)d_out);
}

// Round 5
// 555.979 us; speedup vs baseline: 4.3397x; 1.0787x over previous
//
#include <hip/hip_runtime.h>
#include <math.h>

// Problem constants: B=4, C=64, H=256, W=256, L=2, M1=M2=32, HM=128, P=256, O=1

// workspace layout (in floats)
#define OFF_XA   0                      // bf16 now: ushort[33554432] region (16777216 floats reserved)
#define OFF_XB   16777216               // 16777216 floats (fp32)
#define OFF_Z1   33554432               // 4194304 (float2[2097152]) : X1 / Z reuse
#define OFF_XF   37748736               // 1048576 (float2[524288])
#define OFF_OF   38797312               // 1048576
#define OFF_TH   39878656               // float2[16384] [j][h]   ky_j = j<32? j : 192+j
#define OFF_WBF  39911424               // ushort[65536] bf16 weights (32768 floats)
#define OFF_ROOT 39944192               // (reserved, unused)
#define OFF_TBF  39944704               // ushort[16384] bf16 invW twiddle Tt[w][k] (8192 floats)
#define OFF_EH   39952896               // ushort[16384] fwdW DFT E_hi[n][w] (8192 floats)
#define OFF_EL   39961088               // ushort[16384] fwdW DFT E_lo[n][w] (8192 floats)
// total = 39969280 floats ≈ 152.5 MiB

// WB (ushort) layout: [0:16384) mlp_w1 | [16384:32768) mlp_w2 | [32768:40960) mlp_skip_w
//                     [40960:57344) proj_w1 | [57344:65536) spectral skip_w (2x64x64)

typedef __attribute__((ext_vector_type(8))) short short8b;   // 8 bf16 (4 VGPRs)
typedef __attribute__((ext_vector_type(4))) float f32x4;     // MFMA acc

__device__ __forceinline__ float gelu_f(float v) {
    // sigmoid form of tanh-GELU: x * sigmoid(1.59577x + 0.07135x^3); max dev ~1.5e-4
    float u = v * fmaf(v * v, 0.0713548162f, 1.5957691216f);
    return v * __builtin_amdgcn_rcpf(1.0f + __expf(-u));
}

__device__ __forceinline__ unsigned f2bf(float f) {
    unsigned int u = __float_as_uint(f);
    u += 0x7FFFu + ((u >> 16) & 1u);   // RNE
    return u >> 16;
}

__global__ __launch_bounds__(256) void init_tw(float* ws) {
    int idx = blockIdx.x * 256 + threadIdx.x;
    float2* th   = (float2*)(ws + OFF_TH);
    unsigned short* tbf = (unsigned short*)(ws + OFF_TBF);
    unsigned short* eh  = (unsigned short*)(ws + OFF_EH);
    unsigned short* el  = (unsigned short*)(ws + OFF_EL);
    if (idx < 16384) {
        // Tt[w][k]: k=2kx -> cos*sc, k=2kx+1 -> -sin*sc ; sc=(kx==0?1:2)/65536
        int w = idx >> 6, k = idx & 63;
        int kx = k >> 1;
        int m = (kx * w) & 255;
        double a = (double)m * (3.14159265358979323846 / 128.0);
        float sc = (kx == 0) ? (1.0f / 65536.0f) : (2.0f / 65536.0f);
        float v = (k & 1) ? (float)(-sin(a)) * sc : (float)cos(a) * sc;
        tbf[idx] = (unsigned short)f2bf(v);
    }
    int idx2 = idx - 8192;
    if (idx2 >= 0 && idx2 < 16384) {
        int j = idx2 >> 8, h = idx2 & 255;
        int ky = (j < 32) ? j : (192 + j);
        int m = (ky * h) & 255;
        double a = (double)m * (3.14159265358979323846 / 128.0);
        th[j * 256 + h] = make_float2((float)cos(a), (float)sin(a));
    }
    int idx3 = idx - 24576;
    if (idx3 >= 0 && idx3 < 16384) {
        // E[n][w]: n=2kx -> cos(2pi kx w/256), n=2kx+1 -> -sin(...)  (fwd exp(-i))
        int n = idx3 >> 8, w = idx3 & 255;
        int kx = n >> 1;
        int m = (kx * w) & 255;
        double a = (double)m * (3.14159265358979323846 / 128.0);
        float v = (n & 1) ? (float)(-sin(a)) : (float)cos(a);
        unsigned h = f2bf(v);
        float hf = __uint_as_float(h << 16);
        eh[idx3] = (unsigned short)h;
        el[idx3] = (unsigned short)f2bf(v - hf);
    }
}

// convert all GEMM weights to bf16 once
__global__ __launch_bounds__(256) void k_cvt(const float* __restrict__ w1,
                                             const float* __restrict__ w2,
                                             const float* __restrict__ wsk,
                                             const float* __restrict__ pw1,
                                             const float* __restrict__ ssk,
                                             unsigned short* __restrict__ wb) {
    int idx = blockIdx.x * 256 + threadIdx.x;
    if (idx < 16384)       wb[idx] = (unsigned short)f2bf(w1[idx]);
    else if (idx < 32768)  wb[idx] = (unsigned short)f2bf(w2[idx - 16384]);
    else if (idx < 40960)  wb[idx] = (unsigned short)f2bf(wsk[idx - 32768]);
    else if (idx < 57344)  wb[idx] = (unsigned short)f2bf(pw1[idx - 40960]);
    else if (idx < 65536)  wb[idx] = (unsigned short)f2bf(ssk[idx - 57344]);
}

// ---- MFMA forward DFT over W: X1[row][n] = sum_w x[row][w] * E[n][w]
// Split-bf16 3-pass (x=xh+xl, E=Eh+El): error ~2^-17, fp32-grade.
// Block: 64 rows, 4 waves; wave wv owns rows wv*16..+15, all 64 n outputs.
__global__ __launch_bounds__(256) void k_fwd_w(const float* __restrict__ x,
                                               float* __restrict__ X1f,
                                               const unsigned short* __restrict__ EH,
                                               const unsigned short* __restrict__ EL) {
    __shared__ __align__(16) unsigned short smH[64 * 256];   // 32 KB  [row][w] swizzled
    __shared__ __align__(16) unsigned short smL[64 * 256];   // 32 KB
    int t = threadIdx.x;
    size_t row0 = (size_t)blockIdx.x * 64;

    // stage: thread t -> row t>>2, w-range (t&3)*64..+63 (fully coalesced reads)
    {
        int row = t >> 2, seg = t & 3;
        const float* xp = x + (row0 + row) * 256 + seg * 64;
#pragma unroll
        for (int bq = 0; bq < 8; ++bq) {
            float4 v0 = *(const float4*)(xp + bq * 8);
            float4 v1 = *(const float4*)(xp + bq * 8 + 4);
            float vv[8] = {v0.x, v0.y, v0.z, v0.w, v1.x, v1.y, v1.z, v1.w};
            unsigned h[8], lo[8];
#pragma unroll
            for (int i = 0; i < 8; ++i) {
                h[i] = f2bf(vv[i]);
                float hf = __uint_as_float(h[i] << 16);
                lo[i] = f2bf(vv[i] - hf);
            }
            uint4 ph, pl;
            ph.x = h[0] | (h[1] << 16);  ph.y = h[2] | (h[3] << 16);
            ph.z = h[4] | (h[5] << 16);  ph.w = h[6] | (h[7] << 16);
            pl.x = lo[0] | (lo[1] << 16); pl.y = lo[2] | (lo[3] << 16);
            pl.z = lo[4] | (lo[5] << 16); pl.w = lo[6] | (lo[7] << 16);
            int blk = (seg * 8 + bq) ^ (row & 7);
            *(uint4*)&smH[row * 256 + blk * 8] = ph;
            *(uint4*)&smL[row * 256 + blk * 8] = pl;
        }
    }
    __syncthreads();

    int lane = t & 63, wv = t >> 6;
    int col = lane & 15, grp = lane >> 4;
    int row = wv * 16 + col;

    short8b bH[8], bL[8];
#pragma unroll
    for (int kb = 0; kb < 8; ++kb) {
        int blk = (kb * 4 + grp) ^ (row & 7);
        bH[kb] = *(const short8b*)&smH[row * 256 + blk * 8];
        bL[kb] = *(const short8b*)&smL[row * 256 + blk * 8];
    }

#pragma unroll
    for (int ot = 0; ot < 4; ++ot) {
        f32x4 acc = {0.f, 0.f, 0.f, 0.f};
#pragma unroll
        for (int kb = 0; kb < 8; ++kb) {
            const short8b aH = *(const short8b*)&EH[(ot * 16 + col) * 256 + kb * 32 + grp * 8];
            const short8b aL = *(const short8b*)&EL[(ot * 16 + col) * 256 + kb * 32 + grp * 8];
            acc = __builtin_amdgcn_mfma_f32_16x16x32_bf16(aH, bH[kb], acc, 0, 0, 0);
            acc = __builtin_amdgcn_mfma_f32_16x16x32_bf16(aH, bL[kb], acc, 0, 0, 0);
            acc = __builtin_amdgcn_mfma_f32_16x16x32_bf16(aL, bH[kb], acc, 0, 0, 0);
        }
        *(float4*)&X1f[(row0 + row) * 64 + ot * 16 + grp * 4] =
            *(float4*)&acc;
    }
}

// ---- forward DFT over H: X1[plane][h][kx] -> XF[plane][j][kx], exp(-i th)
__global__ __launch_bounds__(256) void k_fwd_h(const float2* __restrict__ X1,
                                               float2* __restrict__ XF,
                                               const float2* __restrict__ th) {
    __shared__ float2 thl[8 * 256];    // 16 KB
    int tid = threadIdx.x;
    int plane = blockIdx.x, joct = blockIdx.y;
    for (int i = tid; i < 2048; i += 256) thl[i] = th[joct * 2048 + i];
    __syncthreads();
    int kx = tid & 31, g = tid >> 5;   // j = joct*8 + g
    const float2* Xp = X1 + (size_t)plane * 8192 + kx;
    const float2* tr = &thl[g * 256];
    float ar = 0.f, ai = 0.f;
#pragma unroll 16
    for (int hh = 0; hh < 256; ++hh) {
        float2 xv = Xp[hh * 32];
        float2 cs = tr[hh];
        ar = fmaf(xv.x, cs.x, fmaf(xv.y, cs.y, ar));
        ai = fmaf(xv.y, cs.x, fmaf(-xv.x, cs.y, ai));
    }
    XF[(size_t)plane * 2048 + (joct * 8 + g) * 32 + kx] = make_float2(ar, ai);
}

// ---- per-mode complex matmul
__global__ __launch_bounds__(128) void k_modemul(const float2* __restrict__ XF,
                                                 const float2* __restrict__ sw1,
                                                 const float2* __restrict__ sw2,
                                                 float2* __restrict__ OF, int l) {
    int o = blockIdx.x, j = blockIdx.y;
    int tid = threadIdx.x;
    int kx = tid & 31, b = tid >> 5;
    int jj = (j < 32) ? j : (j - 32);
    const float2* Wb = ((j < 32) ? sw1 : sw2) + (l * 4194304 + o * 1024 + jj * 32 + kx);
    const float2* Xb = XF + (b * 64 * 64 * 32 + j * 32 + kx);
    float ar = 0.f, ai = 0.f;
    for (int i = 0; i < 64; ++i) {
        float2 xv = Xb[i * 2048];
        float2 wv = Wb[i * 65536];
        ar += xv.x * wv.x - xv.y * wv.y;
        ai += xv.x * wv.y + xv.y * wv.x;
    }
    OF[((b * 64 + o) * 64 + j) * 32 + kx] = make_float2(ar, ai);
}

// ---- inverse DFT over H: Z[plane][h][kx] = sum_j OF[plane][j][kx] * exp(+i th)
__global__ __launch_bounds__(256) void k_inv_h(const float2* __restrict__ OF,
                                               float2* __restrict__ Z,
                                               const float2* __restrict__ th) {
    __shared__ float2 thl[64 * 32];    // [j][hl] 16 KB
    int tid = threadIdx.x;
    int plane = blockIdx.x, h0 = blockIdx.y * 32;
    for (int i = tid; i < 2048; i += 256) {
        int j = i >> 5, hl = i & 31;
        thl[i] = th[j * 256 + h0 + hl];
    }
    __syncthreads();
    int kx = tid & 31, g = tid >> 5;   // h = h0 + g + 8q
    const float2* Op = OF + (size_t)plane * 2048 + kx;
    float zr[4] = {0.f, 0.f, 0.f, 0.f}, zi[4] = {0.f, 0.f, 0.f, 0.f};
#pragma unroll 8
    for (int j = 0; j < 64; ++j) {
        float2 ov = Op[j * 32];
#pragma unroll
        for (int q = 0; q < 4; ++q) {
            float2 cs = thl[j * 32 + g + 8 * q];
            zr[q] += ov.x * cs.x - ov.y * cs.y;
            zi[q] += ov.y * cs.x + ov.x * cs.y;
        }
    }
#pragma unroll
    for (int q = 0; q < 4; ++q)
        Z[(size_t)plane * 8192 + (h0 + g + 8 * q) * 32 + kx] = make_float2(zr[q], zi[q]);
}

// ---- MFMA fused inverse-W DFT + channel skip + bias + GELU -> bf16 XA
__global__ __launch_bounds__(256) void k_invw_skip(const float* __restrict__ Zf,
                                                   const float* __restrict__ xin,
                                                   const unsigned short* __restrict__ tbf,
                                                   const unsigned short* __restrict__ wsk,
                                                   const float* __restrict__ skip_b,
                                                   unsigned short* __restrict__ xout, int l) {
    __shared__ __align__(16) unsigned short smZ[64 * 64];    // [o][k] swizzled octets, 8 KB
    __shared__ __align__(16) unsigned short smX[256 * 64];   // [w][i] swizzled octets, 32 KB
    int t = threadIdx.x;
    int hh = blockIdx.x, b = blockIdx.y;

    // stage Z2 (float view of Z: [o] rows of 64 consecutive floats = interleaved re/im)
    {
        int o = t >> 2, seg = t & 3;
        const float* zp = Zf + ((size_t)(b * 64 + o) * 8192 + hh * 32) * 2 + seg * 16;
        float4 v0 = *(const float4*)(zp + 0);
        float4 v1 = *(const float4*)(zp + 4);
        float4 v2 = *(const float4*)(zp + 8);
        float4 v3 = *(const float4*)(zp + 12);
        uint4 pk0, pk1;
        pk0.x = f2bf(v0.x) | (f2bf(v0.y) << 16);
        pk0.y = f2bf(v0.z) | (f2bf(v0.w) << 16);
        pk0.z = f2bf(v1.x) | (f2bf(v1.y) << 16);
        pk0.w = f2bf(v1.z) | (f2bf(v1.w) << 16);
        pk1.x = f2bf(v2.x) | (f2bf(v2.y) << 16);
        pk1.y = f2bf(v2.z) | (f2bf(v2.w) << 16);
        pk1.z = f2bf(v3.x) | (f2bf(v3.y) << 16);
        pk1.w = f2bf(v3.z) | (f2bf(v3.w) << 16);
        int blk0 = (seg * 2) ^ (o & 7);
        int blk1 = (seg * 2 + 1) ^ (o & 7);
        *(uint4*)&smZ[o * 64 + blk0 * 8] = pk0;
        *(uint4*)&smZ[o * 64 + blk1 * 8] = pk1;
    }
    // stage X: thread owns w = t, converts all 64 channels
    {
        const float* xb = xin + (size_t)(b * 64) * 65536 + hh * 256 + t;
#pragma unroll
        for (int i0 = 0; i0 < 64; i0 += 8) {
            float v[8];
#pragma unroll
            for (int i = 0; i < 8; ++i) v[i] = xb[(size_t)(i0 + i) * 65536];
            uint4 pk;
            pk.x = f2bf(v[0]) | (f2bf(v[1]) << 16);
            pk.y = f2bf(v[2]) | (f2bf(v[3]) << 16);
            pk.z = f2bf(v[4]) | (f2bf(v[5]) << 16);
            pk.w = f2bf(v[6]) | (f2bf(v[7]) << 16);
            int blk = (i0 >> 3) ^ (t & 7);
            *(uint4*)&smX[t * 64 + blk * 8] = pk;
        }
    }
    __syncthreads();

    int lane = t & 63, wv = t >> 6;
    int col = lane & 15, grp = lane >> 4;
    int w0 = wv * 64;

    short8b tf[4][2], bxf[4][2];
#pragma unroll
    for (int wt = 0; wt < 4; ++wt) {
        int w = w0 + wt * 16 + col;
#pragma unroll
        for (int kb = 0; kb < 2; ++kb) {
            tf[wt][kb] = *(const short8b*)&tbf[w * 64 + kb * 32 + grp * 8];
            int blk = (kb * 4 + grp) ^ (w & 7);
            bxf[wt][kb] = *(const short8b*)&smX[w * 64 + blk * 8];
        }
    }

    const unsigned short* WSp = wsk + l * 4096;
#pragma unroll
    for (int ot = 0; ot < 4; ++ot) {
        int o = ot * 16 + col;
        short8b az[2], ask[2];
#pragma unroll
        for (int kb = 0; kb < 2; ++kb) {
            int blk = (kb * 4 + grp) ^ (o & 7);
            az[kb] = *(const short8b*)&smZ[o * 64 + blk * 8];
            ask[kb] = *(const short8b*)&WSp[o * 64 + kb * 32 + grp * 8];
        }
        f32x4 bias = *(const f32x4*)&skip_b[l * 64 + ot * 16 + grp * 4];
#pragma unroll
        for (int wt = 0; wt < 4; ++wt) {
            f32x4 acc = bias;
            acc = __builtin_amdgcn_mfma_f32_16x16x32_bf16(az[0], tf[wt][0], acc, 0, 0, 0);
            acc = __builtin_amdgcn_mfma_f32_16x16x32_bf16(az[1], tf[wt][1], acc, 0, 0, 0);
            acc = __builtin_amdgcn_mfma_f32_16x16x32_bf16(ask[0], bxf[wt][0], acc, 0, 0, 0);
            acc = __builtin_amdgcn_mfma_f32_16x16x32_bf16(ask[1], bxf[wt][1], acc, 0, 0, 0);
            unsigned short* op = xout + (size_t)(b * 64 + ot * 16 + grp * 4) * 65536
                               + hh * 256 + w0 + wt * 16 + col;
            op[0]          = (unsigned short)f2bf(gelu_f(acc[0]));
            op[65536]      = (unsigned short)f2bf(gelu_f(acc[1]));
            op[2 * 65536]  = (unsigned short)f2bf(gelu_f(acc[2]));
            op[3 * 65536]  = (unsigned short)f2bf(gelu_f(acc[3]));
        }
    }
}

// ---- MFMA channel MLP: x2 = gelu(W2@gelu(W1@x+b1)+b2 + Wsk@x+bsk); input bf16 XA
__global__ __launch_bounds__(256) void k_mlp(const unsigned short* __restrict__ xin,
                                             const unsigned short* __restrict__ wb,
                                             const float* __restrict__ b1,
                                             const float* __restrict__ b2,
                                             const float* __restrict__ bsk,
                                             float* __restrict__ xout, int l) {
    __shared__ __align__(16) unsigned short smemX[128 * 64];   // [px][ch] xor-swizzled octets
    __shared__ __align__(16) unsigned short smemH[128 * 128];  // [px][hm] xor-swizzled octets
    int t = threadIdx.x;
    int b = blockIdx.y;
    int p0 = blockIdx.x * 128;

    {
        int pxs = t & 127;
        int cb = (t >> 7) * 8;
        const unsigned short* xb = xin + (size_t)(b * 64) * 65536 + p0 + pxs;
#pragma unroll
        for (int pass = 0; pass < 4; ++pass) {
            int ch0 = pass * 16 + cb;
            unsigned u[8];
#pragma unroll
            for (int i = 0; i < 8; ++i) u[i] = xb[(size_t)(ch0 + i) * 65536];
            uint4 pk;
            pk.x = u[0] | (u[1] << 16);
            pk.y = u[2] | (u[3] << 16);
            pk.z = u[4] | (u[5] << 16);
            pk.w = u[6] | (u[7] << 16);
            int blk = (ch0 >> 3) ^ (pxs & 7);
            *(uint4*)&smemX[pxs * 64 + blk * 8] = pk;
        }
    }
    __syncthreads();

    int lane = t & 63, wv = t >> 6;
    int col = lane & 15, grp = lane >> 4;

    short8b bx[2][2];
#pragma unroll
    for (int pxt = 0; pxt < 2; ++pxt)
#pragma unroll
        for (int kb = 0; kb < 2; ++kb) {
            int px = wv * 32 + pxt * 16 + col;
            int blk = (kb * 4 + grp) ^ (px & 7);
            bx[pxt][kb] = *(const short8b*)&smemX[px * 64 + blk * 8];
        }

    const unsigned short* W1p = wb + l * 8192;
#pragma unroll
    for (int ot = 0; ot < 8; ++ot) {
        short8b a0 = *(const short8b*)&W1p[(ot * 16 + col) * 64 + grp * 8];
        short8b a1 = *(const short8b*)&W1p[(ot * 16 + col) * 64 + 32 + grp * 8];
        int hm0 = ot * 16 + grp * 4;
        f32x4 bb = *(const f32x4*)&b1[l * 128 + hm0];
#pragma unroll
        for (int pxt = 0; pxt < 2; ++pxt) {
            f32x4 acc = bb;
            acc = __builtin_amdgcn_mfma_f32_16x16x32_bf16(a0, bx[pxt][0], acc, 0, 0, 0);
            acc = __builtin_amdgcn_mfma_f32_16x16x32_bf16(a1, bx[pxt][1], acc, 0, 0, 0);
            ushort4 hp;
            hp.x = (unsigned short)f2bf(gelu_f(acc[0]));
            hp.y = (unsigned short)f2bf(gelu_f(acc[1]));
            hp.z = (unsigned short)f2bf(gelu_f(acc[2]));
            hp.w = (unsigned short)f2bf(gelu_f(acc[3]));
            int px = wv * 32 + pxt * 16 + col;
            int blk = (hm0 >> 3) ^ (px & 7);
            *(ushort4*)&smemH[px * 128 + blk * 8 + (hm0 & 7)] = hp;
        }
    }

    short8b bh[2][4];
#pragma unroll
    for (int pxt = 0; pxt < 2; ++pxt)
#pragma unroll
        for (int kb = 0; kb < 4; ++kb) {
            int px = wv * 32 + pxt * 16 + col;
            int blk = (kb * 4 + grp) ^ (px & 7);
            bh[pxt][kb] = *(const short8b*)&smemH[px * 128 + blk * 8];
        }

    const unsigned short* W2p = wb + 16384 + l * 8192;
    const unsigned short* WSp = wb + 32768 + l * 4096;
#pragma unroll
    for (int ot = 0; ot < 4; ++ot) {
        int o0 = ot * 16 + grp * 4;
        f32x4 b2v = *(const f32x4*)&b2[l * 64 + o0];
        f32x4 bsv = *(const f32x4*)&bsk[l * 64 + o0];
        short8b a2[4], as[2];
#pragma unroll
        for (int kb = 0; kb < 4; ++kb)
            a2[kb] = *(const short8b*)&W2p[(ot * 16 + col) * 128 + kb * 32 + grp * 8];
#pragma unroll
        for (int kb = 0; kb < 2; ++kb)
            as[kb] = *(const short8b*)&WSp[(ot * 16 + col) * 64 + kb * 32 + grp * 8];
#pragma unroll
        for (int pxt = 0; pxt < 2; ++pxt) {
            f32x4 acc = b2v + bsv;
#pragma unroll
            for (int kb = 0; kb < 4; ++kb)
                acc = __builtin_amdgcn_mfma_f32_16x16x32_bf16(a2[kb], bh[pxt][kb], acc, 0, 0, 0);
#pragma unroll
            for (int kb = 0; kb < 2; ++kb)
                acc = __builtin_amdgcn_mfma_f32_16x16x32_bf16(as[kb], bx[pxt][kb], acc, 0, 0, 0);
            int px = wv * 32 + pxt * 16 + col;
            float* op = xout + (size_t)(b * 64 + o0) * 65536 + p0 + px;
            op[0]          = gelu_f(acc[0]);
            op[65536]      = gelu_f(acc[1]);
            op[2 * 65536]  = gelu_f(acc[2]);
            op[3 * 65536]  = gelu_f(acc[3]);
        }
    }
}

// ---- MFMA projection: out = PW2 @ gelu(PW1@x + pb1) + pb2  (O=1)
__global__ __launch_bounds__(256) void k_proj(const float* __restrict__ xin,
                                              const unsigned short* __restrict__ wb,
                                              const float* __restrict__ pb1,
                                              const float* __restrict__ pw2,
                                              const float* __restrict__ pb2,
                                              float* __restrict__ out) {
    __shared__ __align__(16) unsigned short smemX[128 * 64];
    int t = threadIdx.x;
    int b = blockIdx.y;
    int p0 = blockIdx.x * 128;
    {
        int pxs = t & 127;
        int cb = (t >> 7) * 8;
        const float* xb = xin + (size_t)(b * 64) * 65536 + p0 + pxs;
#pragma unroll
        for (int pass = 0; pass < 4; ++pass) {
            int ch0 = pass * 16 + cb;
            float v[8];
#pragma unroll
            for (int i = 0; i < 8; ++i) v[i] = xb[(size_t)(ch0 + i) * 65536];
            uint4 pk;
            pk.x = f2bf(v[0]) | (f2bf(v[1]) << 16);
            pk.y = f2bf(v[2]) | (f2bf(v[3]) << 16);
            pk.z = f2bf(v[4]) | (f2bf(v[5]) << 16);
            pk.w = f2bf(v[6]) | (f2bf(v[7]) << 16);
            int blk = (ch0 >> 3) ^ (pxs & 7);
            *(uint4*)&smemX[pxs * 64 + blk * 8] = pk;
        }
    }
    __syncthreads();

    int lane = t & 63, wv = t >> 6;
    int col = lane & 15, grp = lane >> 4;

    short8b bx[2][2];
#pragma unroll
    for (int pxt = 0; pxt < 2; ++pxt)
#pragma unroll
        for (int kb = 0; kb < 2; ++kb) {
            int px = wv * 32 + pxt * 16 + col;
            int blk = (kb * 4 + grp) ^ (px & 7);
            bx[pxt][kb] = *(const short8b*)&smemX[px * 64 + blk * 8];
        }

    const unsigned short* P1p = wb + 40960;
    float psum0 = 0.f, psum1 = 0.f;
#pragma unroll
    for (int ot = 0; ot < 16; ++ot) {
        short8b a0 = *(const short8b*)&P1p[(ot * 16 + col) * 64 + grp * 8];
        short8b a1 = *(const short8b*)&P1p[(ot * 16 + col) * 64 + 32 + grp * 8];
        int o0 = ot * 16 + grp * 4;
        f32x4 b1v = *(const f32x4*)&pb1[o0];
        f32x4 w2v = *(const f32x4*)&pw2[o0];
        {
            f32x4 acc = b1v;
            acc = __builtin_amdgcn_mfma_f32_16x16x32_bf16(a0, bx[0][0], acc, 0, 0, 0);
            acc = __builtin_amdgcn_mfma_f32_16x16x32_bf16(a1, bx[0][1], acc, 0, 0, 0);
            psum0 += w2v[0] * gelu_f(acc[0]) + w2v[1] * gelu_f(acc[1])
                   + w2v[2] * gelu_f(acc[2]) + w2v[3] * gelu_f(acc[3]);
        }
        {
            f32x4 acc = b1v;
            acc = __builtin_amdgcn_mfma_f32_16x16x32_bf16(a0, bx[1][0], acc, 0, 0, 0);
            acc = __builtin_amdgcn_mfma_f32_16x16x32_bf16(a1, bx[1][1], acc, 0, 0, 0);
            psum1 += w2v[0] * gelu_f(acc[0]) + w2v[1] * gelu_f(acc[1])
                   + w2v[2] * gelu_f(acc[2]) + w2v[3] * gelu_f(acc[3]);
        }
    }
    psum0 += __shfl_xor(psum0, 16);
    psum0 += __shfl_xor(psum0, 32);
    psum1 += __shfl_xor(psum1, 16);
    psum1 += __shfl_xor(psum1, 32);
    if (grp == 0) {
        float bias = pb2[0];
        out[(size_t)b * 65536 + p0 + wv * 32 + col] = psum0 + bias;
        out[(size_t)b * 65536 + p0 + wv * 32 + 16 + col] = psum1 + bias;
    }
}

extern "C" void kernel_launch(void* const* d_in, const int* in_sizes, int n_in,
                              void* d_out, int out_size, void* d_ws, size_t ws_size,
                              hipStream_t stream) {
    const float* x          = (const float*)d_in[0];
    const float2* sw1       = (const float2*)d_in[1];
    const float2* sw2       = (const float2*)d_in[2];
    const float* skip_w     = (const float*)d_in[3];
    const float* skip_b     = (const float*)d_in[4];
    const float* mlp_w1     = (const float*)d_in[5];
    const float* mlp_b1     = (const float*)d_in[6];
    const float* mlp_w2     = (const float*)d_in[7];
    const float* mlp_b2     = (const float*)d_in[8];
    const float* mlp_skip_w = (const float*)d_in[9];
    const float* mlp_skip_b = (const float*)d_in[10];
    const float* proj_w1    = (const float*)d_in[11];
    const float* proj_b1    = (const float*)d_in[12];
    const float* proj_w2    = (const float*)d_in[13];
    const float* proj_b2    = (const float*)d_in[14];

    float* ws = (float*)d_ws;
    unsigned short* XAb = (unsigned short*)(ws + OFF_XA);
    float* XB = ws + OFF_XB;
    float2* Z1 = (float2*)(ws + OFF_Z1);
    float2* XF = (float2*)(ws + OFF_XF);
    float2* OF = (float2*)(ws + OFF_OF);
    const float2* TH   = (const float2*)(ws + OFF_TH);
    const unsigned short* TBF = (const unsigned short*)(ws + OFF_TBF);
    const unsigned short* EH  = (const unsigned short*)(ws + OFF_EH);
    const unsigned short* EL  = (const unsigned short*)(ws + OFF_EL);
    unsigned short* WB = (unsigned short*)(ws + OFF_WBF);

    init_tw<<<160, 256, 0, stream>>>(ws);
    k_cvt<<<256, 256, 0, stream>>>(mlp_w1, mlp_w2, mlp_skip_w, proj_w1, skip_w, WB);

    const float* cur = x;
    for (int l = 0; l < 2; ++l) {
        k_fwd_w<<<1024, 256, 0, stream>>>(cur, (float*)Z1, EH, EL);
        k_fwd_h<<<dim3(256, 8), 256, 0, stream>>>(Z1, XF, TH);
        k_modemul<<<dim3(64, 64), 128, 0, stream>>>(XF, sw1, sw2, OF, l);
        k_inv_h<<<dim3(256, 8), 256, 0, stream>>>(OF, Z1, TH);
        k_invw_skip<<<dim3(256, 4), 256, 0, stream>>>((const float*)Z1, cur, TBF,
                                                      WB + 57344, skip_b, XAb, l);
        k_mlp<<<dim3(512, 4), 256, 0, stream>>>(XAb, WB, mlp_b1, mlp_b2, mlp_skip_b, XB, l);
        cur = XB;
    }
    k_proj<<<dim3(512, 4), 256, 0, stream>>>(XB, WB, proj_b1, proj_w2, proj_b2, (float*)d_out);
}

// Round 6
// 429.749 us; speedup vs baseline: 5.6144x; 1.2937x over previous
//
#include <hip/hip_runtime.h>
#include <math.h>

// Problem constants: B=4, C=64, H=256, W=256, L=2, M1=M2=32, HM=128, P=256, O=1

// workspace layout (in floats)
#define OFF_XA   0                      // bf16 XA: ushort[16777216] (8388608 floats used)
#define OFF_XB   16777216               // 16777216 floats (fp32)
#define OFF_Z1   33554432               // 4194304 floats: X1 (4M) OR Zre(2M)+Zim(2M)
#define OFF_XF   37748736               // XFre 524288 + XFim 524288
#define OFF_OF   38797312               // OFT 1048576  [plane][kx][2j+d]
#define OFF_TBF  39845888               // ushort[16384] invW twiddle Tt[w][k]
#define OFF_EH   39854080               // ushort[16384] fwdW E_hi[n][w]
#define OFF_EL   39862272               // ushort[16384] fwdW E_lo[n][w]
#define OFF_AFH  39870464               // ushort[65536] fwdH A_hi[n=128][k=512]
#define OFF_AFL  39903232               // ushort[65536] fwdH A_lo
#define OFF_AIH  39936000               // ushort[65536] invH A_hi[c=2][h=256][k=128]
#define OFF_AIL  39968768               // ushort[65536] invH A_lo
#define OFF_WBF  40001536               // ushort[65536] bf16 weights
// total = 40034304 floats ≈ 152.7 MiB

// WB (ushort) layout: [0:16384) mlp_w1 | [16384:32768) mlp_w2 | [32768:40960) mlp_skip_w
//                     [40960:57344) proj_w1 | [57344:65536) spectral skip_w (2x64x64)

typedef __attribute__((ext_vector_type(8))) short short8b;   // 8 bf16 (4 VGPRs)
typedef __attribute__((ext_vector_type(4))) float f32x4;     // MFMA acc

__device__ __forceinline__ float gelu_f(float v) {
    float u = v * fmaf(v * v, 0.0713548162f, 1.5957691216f);
    return v * __builtin_amdgcn_rcpf(1.0f + __expf(-u));
}

__device__ __forceinline__ unsigned f2bf(float f) {
    unsigned int u = __float_as_uint(f);
    u += 0x7FFFu + ((u >> 16) & 1u);   // RNE
    return u >> 16;
}

__global__ __launch_bounds__(256) void init_tw(float* ws) {
    int idx = blockIdx.x * 256 + threadIdx.x;
    unsigned short* tbf = (unsigned short*)(ws + OFF_TBF);
    unsigned short* eh  = (unsigned short*)(ws + OFF_EH);
    unsigned short* el  = (unsigned short*)(ws + OFF_EL);
    unsigned short* afh = (unsigned short*)(ws + OFF_AFH);
    unsigned short* afl = (unsigned short*)(ws + OFF_AFL);
    unsigned short* aih = (unsigned short*)(ws + OFF_AIH);
    unsigned short* ail = (unsigned short*)(ws + OFF_AIL);
    const double PI128 = 3.14159265358979323846 / 128.0;
    if (idx < 16384) {
        // Tt[w][k]: k=2kx -> cos*sc, k=2kx+1 -> -sin*sc ; sc=(kx==0?1:2)/65536
        int w = idx >> 6, k = idx & 63;
        int kx = k >> 1;
        int m = (kx * w) & 255;
        double a = (double)m * PI128;
        float sc = (kx == 0) ? (1.0f / 65536.0f) : (2.0f / 65536.0f);
        float v = (k & 1) ? (float)(-sin(a)) * sc : (float)cos(a) * sc;
        tbf[idx] = (unsigned short)f2bf(v);
    }
    int i2 = idx - 16384;
    if (i2 >= 0 && i2 < 16384) {
        // fwdW E[n][w]: n=2kx -> cos, n=2kx+1 -> -sin (exp(-i))
        int n = i2 >> 8, w = i2 & 255;
        int kx = n >> 1;
        int m = (kx * w) & 255;
        double a = (double)m * PI128;
        float v = (n & 1) ? (float)(-sin(a)) : (float)cos(a);
        unsigned h = f2bf(v);
        eh[i2] = (unsigned short)h;
        el[i2] = (unsigned short)f2bf(v - __uint_as_float(h << 16));
    }
    int i3 = idx - 32768;
    if (i3 >= 0 && i3 < 65536) {
        // fwdH A[n][k]: n=j+64c, k=2h+d. c=0(re): d0 cos, d1 sin; c=1(im): d0 -sin, d1 cos
        int n = i3 >> 9, k = i3 & 511;
        int j = n & 63, c = n >> 6;
        int h = k >> 1, d = k & 1;
        int ky = (j < 32) ? j : (192 + j);
        int m = (ky * h) & 255;
        double a = (double)m * PI128;
        float cv = (float)cos(a), sv = (float)sin(a);
        float v = (c == 0) ? (d ? sv : cv) : (d ? cv : -sv);
        unsigned hh = f2bf(v);
        afh[i3] = (unsigned short)hh;
        afl[i3] = (unsigned short)f2bf(v - __uint_as_float(hh << 16));
    }
    int i4 = idx - 98304;
    if (i4 >= 0 && i4 < 65536) {
        // invH A[c][h][k]: k=2j+d. c=0(Zre): d0 cos, d1 -sin; c=1(Zim): d0 sin, d1 cos
        int c = i4 >> 15, rem = i4 & 32767;
        int h = rem >> 7, k = rem & 127;
        int j = k >> 1, d = k & 1;
        int ky = (j < 32) ? j : (192 + j);
        int m = (ky * h) & 255;
        double a = (double)m * PI128;
        float cv = (float)cos(a), sv = (float)sin(a);
        float v = (c == 0) ? (d ? -sv : cv) : (d ? cv : sv);
        unsigned hh = f2bf(v);
        aih[i4] = (unsigned short)hh;
        ail[i4] = (unsigned short)f2bf(v - __uint_as_float(hh << 16));
    }
}

// convert all GEMM weights to bf16 once
__global__ __launch_bounds__(256) void k_cvt(const float* __restrict__ w1,
                                             const float* __restrict__ w2,
                                             const float* __restrict__ wsk,
                                             const float* __restrict__ pw1,
                                             const float* __restrict__ ssk,
                                             unsigned short* __restrict__ wb) {
    int idx = blockIdx.x * 256 + threadIdx.x;
    if (idx < 16384)       wb[idx] = (unsigned short)f2bf(w1[idx]);
    else if (idx < 32768)  wb[idx] = (unsigned short)f2bf(w2[idx - 16384]);
    else if (idx < 40960)  wb[idx] = (unsigned short)f2bf(wsk[idx - 32768]);
    else if (idx < 57344)  wb[idx] = (unsigned short)f2bf(pw1[idx - 40960]);
    else if (idx < 65536)  wb[idx] = (unsigned short)f2bf(ssk[idx - 57344]);
}

// ---- MFMA forward DFT over W (split-bf16 3-pass): X1[row][n] = sum_w x[row][w]*E[n][w]
__global__ __launch_bounds__(256) void k_fwd_w(const float* __restrict__ x,
                                               float* __restrict__ X1f,
                                               const unsigned short* __restrict__ EH,
                                               const unsigned short* __restrict__ EL) {
    __shared__ __align__(16) unsigned short smH[64 * 256];   // [row][w] swizzled
    __shared__ __align__(16) unsigned short smL[64 * 256];
    int t = threadIdx.x;
    size_t row0 = (size_t)blockIdx.x * 64;
    {
        int row = t >> 2, seg = t & 3;
        const float* xp = x + (row0 + row) * 256 + seg * 64;
#pragma unroll
        for (int bq = 0; bq < 8; ++bq) {
            float4 v0 = *(const float4*)(xp + bq * 8);
            float4 v1 = *(const float4*)(xp + bq * 8 + 4);
            float vv[8] = {v0.x, v0.y, v0.z, v0.w, v1.x, v1.y, v1.z, v1.w};
            unsigned h[8], lo[8];
#pragma unroll
            for (int i = 0; i < 8; ++i) {
                h[i] = f2bf(vv[i]);
                lo[i] = f2bf(vv[i] - __uint_as_float(h[i] << 16));
            }
            uint4 ph, pl;
            ph.x = h[0] | (h[1] << 16);  ph.y = h[2] | (h[3] << 16);
            ph.z = h[4] | (h[5] << 16);  ph.w = h[6] | (h[7] << 16);
            pl.x = lo[0] | (lo[1] << 16); pl.y = lo[2] | (lo[3] << 16);
            pl.z = lo[4] | (lo[5] << 16); pl.w = lo[6] | (lo[7] << 16);
            int blk = (seg * 8 + bq) ^ (row & 7);
            *(uint4*)&smH[row * 256 + blk * 8] = ph;
            *(uint4*)&smL[row * 256 + blk * 8] = pl;
        }
    }
    __syncthreads();
    int lane = t & 63, wv = t >> 6;
    int col = lane & 15, grp = lane >> 4;
    int row = wv * 16 + col;

    short8b bH[8], bL[8];
#pragma unroll
    for (int kb = 0; kb < 8; ++kb) {
        int blk = (kb * 4 + grp) ^ (row & 7);
        bH[kb] = *(const short8b*)&smH[row * 256 + blk * 8];
        bL[kb] = *(const short8b*)&smL[row * 256 + blk * 8];
    }
#pragma unroll
    for (int ot = 0; ot < 4; ++ot) {
        f32x4 acc = {0.f, 0.f, 0.f, 0.f};
#pragma unroll
        for (int kb = 0; kb < 8; ++kb) {
            const short8b aH = *(const short8b*)&EH[(ot * 16 + col) * 256 + kb * 32 + grp * 8];
            const short8b aL = *(const short8b*)&EL[(ot * 16 + col) * 256 + kb * 32 + grp * 8];
            acc = __builtin_amdgcn_mfma_f32_16x16x32_bf16(aH, bH[kb], acc, 0, 0, 0);
            acc = __builtin_amdgcn_mfma_f32_16x16x32_bf16(aH, bL[kb], acc, 0, 0, 0);
            acc = __builtin_amdgcn_mfma_f32_16x16x32_bf16(aL, bH[kb], acc, 0, 0, 0);
        }
        *(float4*)&X1f[(row0 + row) * 64 + ot * 16 + grp * 4] = *(float4*)&acc;
    }
}

// ---- MFMA forward DFT over H (split-bf16): XF[n][kx] = sum_k AF[n][k]*X1[plane][kx][k]
// X1 layout per plane: [h][2kx+d] (16384 floats); k = 2h+d. Output planar XFre/XFim.
__global__ __launch_bounds__(256) void k_fwd_h(const float* __restrict__ X1f,
                                               float* __restrict__ XFre,
                                               float* __restrict__ XFim,
                                               const unsigned short* __restrict__ AFH,
                                               const unsigned short* __restrict__ AFL) {
    __shared__ __align__(16) unsigned short smH[32 * 512];   // [kx][k] swizzled, 32 KB
    __shared__ __align__(16) unsigned short smL[32 * 512];
    int t = threadIdx.x;
    int plane = blockIdx.x;
    const float* xp = X1f + (size_t)plane * 16384;
#pragma unroll
    for (int pass = 0; pass < 16; ++pass) {
        int idx = pass * 256 + t;
        int h = idx >> 4, seg = idx & 15;
        float4 v = *(const float4*)(xp + h * 64 + seg * 4);
        int kx0 = seg * 2, kx1 = seg * 2 + 1;
        int k0 = 2 * h;
        unsigned hx = f2bf(v.x), hy = f2bf(v.y), hz = f2bf(v.z), hw = f2bf(v.w);
        unsigned lx = f2bf(v.x - __uint_as_float(hx << 16));
        unsigned ly = f2bf(v.y - __uint_as_float(hy << 16));
        unsigned lz = f2bf(v.z - __uint_as_float(hz << 16));
        unsigned lw = f2bf(v.w - __uint_as_float(hw << 16));
        int oct = k0 >> 3, e = k0 & 7;
        int b0 = oct ^ (kx0 & 7), b1 = oct ^ (kx1 & 7);
        *(unsigned*)&smH[kx0 * 512 + b0 * 8 + e] = hx | (hy << 16);
        *(unsigned*)&smH[kx1 * 512 + b1 * 8 + e] = hz | (hw << 16);
        *(unsigned*)&smL[kx0 * 512 + b0 * 8 + e] = lx | (ly << 16);
        *(unsigned*)&smL[kx1 * 512 + b1 * 8 + e] = lz | (lw << 16);
    }
    __syncthreads();
    int lane = t & 63, wv = t >> 6;
    int col = lane & 15, grp = lane >> 4;
#pragma unroll
    for (int mi = 0; mi < 2; ++mi) {
        int mt = wv * 2 + mi;                    // 8 M-tiles; n = mt*16 + grp*4 + r
        const unsigned short* Ah = AFH + (mt * 16 + col) * 512;
        const unsigned short* Al = AFL + (mt * 16 + col) * 512;
        f32x4 acc0 = {0.f, 0.f, 0.f, 0.f}, acc1 = {0.f, 0.f, 0.f, 0.f};
#pragma unroll
        for (int kb = 0; kb < 16; ++kb) {
            short8b aH = *(const short8b*)&Ah[kb * 32 + grp * 8];
            short8b aL = *(const short8b*)&Al[kb * 32 + grp * 8];
#pragma unroll
            for (int nt = 0; nt < 2; ++nt) {
                int kx = nt * 16 + col;
                int blk = (kb * 4 + grp) ^ (kx & 7);
                short8b bH = *(const short8b*)&smH[kx * 512 + blk * 8];
                short8b bL = *(const short8b*)&smL[kx * 512 + blk * 8];
                f32x4 a = (nt == 0) ? acc0 : acc1;
                a = __builtin_amdgcn_mfma_f32_16x16x32_bf16(aH, bH, a, 0, 0, 0);
                a = __builtin_amdgcn_mfma_f32_16x16x32_bf16(aH, bL, a, 0, 0, 0);
                a = __builtin_amdgcn_mfma_f32_16x16x32_bf16(aL, bH, a, 0, 0, 0);
                if (nt == 0) acc0 = a; else acc1 = a;
            }
        }
#pragma unroll
        for (int nt = 0; nt < 2; ++nt) {
            int kx = nt * 16 + col;
            f32x4 a = (nt == 0) ? acc0 : acc1;
#pragma unroll
            for (int r = 0; r < 4; ++r) {
                int n = mt * 16 + grp * 4 + r;
                float* dst = (n < 64)
                    ? (XFre + (size_t)plane * 2048 + n * 32 + kx)
                    : (XFim + (size_t)plane * 2048 + (n - 64) * 32 + kx);
                *dst = a[r];
            }
        }
    }
}

// ---- per-mode complex matmul (planar XF in, transposed-interleaved OFT out)
__global__ __launch_bounds__(128) void k_modemul(const float* __restrict__ XFre,
                                                 const float* __restrict__ XFim,
                                                 const float2* __restrict__ sw1,
                                                 const float2* __restrict__ sw2,
                                                 float* __restrict__ OFT, int l) {
    int o = blockIdx.x, j = blockIdx.y;
    int tid = threadIdx.x;
    int kx = tid & 31, b = tid >> 5;
    int jj = (j < 32) ? j : (j - 32);
    const float2* Wb = ((j < 32) ? sw1 : sw2) + (l * 4194304 + o * 1024 + jj * 32 + kx);
    const float* Xr = XFre + (size_t)(b * 64) * 2048 + j * 32 + kx;
    const float* Xi = XFim + (size_t)(b * 64) * 2048 + j * 32 + kx;
    float ar = 0.f, ai = 0.f;
    for (int i = 0; i < 64; ++i) {
        float xr = Xr[i * 2048], xi = Xi[i * 2048];
        float2 wv = Wb[i * 65536];
        ar += xr * wv.x - xi * wv.y;
        ai += xr * wv.y + xi * wv.x;
    }
    float* dst = OFT + (size_t)(b * 64 + o) * 4096 + kx * 128 + 2 * j;
    dst[0] = ar;
    dst[1] = ai;
}

// ---- MFMA inverse DFT over H (split-bf16): Zc[h][kx] = sum_k AI[c][h][k]*OFT[plane][kx][k]
__global__ __launch_bounds__(256) void k_inv_h(const float* __restrict__ OFT,
                                               float* __restrict__ Zre,
                                               float* __restrict__ Zim,
                                               const unsigned short* __restrict__ AIH,
                                               const unsigned short* __restrict__ AIL) {
    __shared__ __align__(16) unsigned short smH[32 * 128];   // [kx][k] swizzled, 8 KB
    __shared__ __align__(16) unsigned short smL[32 * 128];
    int t = threadIdx.x;
    int plane = blockIdx.x;
    const float* op = OFT + (size_t)plane * 4096;
#pragma unroll
    for (int pass = 0; pass < 4; ++pass) {
        int idx = pass * 256 + t;
        int kx = idx >> 5, seg = idx & 31;
        float4 v = *(const float4*)(op + kx * 128 + seg * 4);
        unsigned h0 = f2bf(v.x), h1 = f2bf(v.y), h2 = f2bf(v.z), h3 = f2bf(v.w);
        unsigned l0 = f2bf(v.x - __uint_as_float(h0 << 16));
        unsigned l1 = f2bf(v.y - __uint_as_float(h1 << 16));
        unsigned l2 = f2bf(v.z - __uint_as_float(h2 << 16));
        unsigned l3 = f2bf(v.w - __uint_as_float(h3 << 16));
        int k0 = seg * 4;
        int oct = k0 >> 3, e = k0 & 7;   // e in {0,4}
        int blk = oct ^ (kx & 7);
        uint2 ph = {h0 | (h1 << 16), h2 | (h3 << 16)};
        uint2 pl = {l0 | (l1 << 16), l2 | (l3 << 16)};
        *(uint2*)&smH[kx * 128 + blk * 8 + e] = ph;
        *(uint2*)&smL[kx * 128 + blk * 8 + e] = pl;
    }
    __syncthreads();
    int lane = t & 63, wv = t >> 6;
    int col = lane & 15, grp = lane >> 4;
#pragma unroll
    for (int mi = 0; mi < 4; ++mi) {
        int mt = wv * 4 + mi;                    // 16 M-tiles; h = mt*16 + grp*4 + r
#pragma unroll
        for (int cc = 0; cc < 2; ++cc) {
            const unsigned short* Ah = AIH + cc * 32768 + (mt * 16 + col) * 128;
            const unsigned short* Al = AIL + cc * 32768 + (mt * 16 + col) * 128;
            f32x4 acc0 = {0.f, 0.f, 0.f, 0.f}, acc1 = {0.f, 0.f, 0.f, 0.f};
#pragma unroll
            for (int kb = 0; kb < 4; ++kb) {
                short8b aH = *(const short8b*)&Ah[kb * 32 + grp * 8];
                short8b aL = *(const short8b*)&Al[kb * 32 + grp * 8];
#pragma unroll
                for (int nt = 0; nt < 2; ++nt) {
                    int kx = nt * 16 + col;
                    int blk = (kb * 4 + grp) ^ (kx & 7);
                    short8b bH = *(const short8b*)&smH[kx * 128 + blk * 8];
                    short8b bL = *(const short8b*)&smL[kx * 128 + blk * 8];
                    f32x4 a = (nt == 0) ? acc0 : acc1;
                    a = __builtin_amdgcn_mfma_f32_16x16x32_bf16(aH, bH, a, 0, 0, 0);
                    a = __builtin_amdgcn_mfma_f32_16x16x32_bf16(aH, bL, a, 0, 0, 0);
                    a = __builtin_amdgcn_mfma_f32_16x16x32_bf16(aL, bH, a, 0, 0, 0);
                    if (nt == 0) acc0 = a; else acc1 = a;
                }
            }
            float* Zc = (cc == 0) ? Zre : Zim;
#pragma unroll
            for (int nt = 0; nt < 2; ++nt) {
                int kx = nt * 16 + col;
                f32x4 a = (nt == 0) ? acc0 : acc1;
#pragma unroll
                for (int r = 0; r < 4; ++r) {
                    int h = mt * 16 + grp * 4 + r;
                    Zc[(size_t)plane * 8192 + h * 32 + kx] = a[r];
                }
            }
        }
    }
}

// ---- MFMA fused inverse-W DFT + channel skip + bias + GELU -> bf16 XA
__global__ __launch_bounds__(256) void k_invw_skip(const float* __restrict__ Zre,
                                                   const float* __restrict__ Zim,
                                                   const float* __restrict__ xin,
                                                   const unsigned short* __restrict__ tbf,
                                                   const unsigned short* __restrict__ wsk,
                                                   const float* __restrict__ skip_b,
                                                   unsigned short* __restrict__ xout, int l) {
    __shared__ __align__(16) unsigned short smZ[64 * 64];    // [o][k=2kx+c] swizzled, 8 KB
    __shared__ __align__(16) unsigned short smX[256 * 64];   // [w][i] swizzled, 32 KB
    int t = threadIdx.x;
    int hh = blockIdx.x, b = blockIdx.y;

    // stage Z (planar -> interleaved bf16)
    {
        int o = t >> 2, seg = t & 3;
        const float* zr = Zre + (size_t)(b * 64 + o) * 8192 + hh * 32 + seg * 8;
        const float* zi = Zim + (size_t)(b * 64 + o) * 8192 + hh * 32 + seg * 8;
        float4 r0 = *(const float4*)(zr);
        float4 r1 = *(const float4*)(zr + 4);
        float4 i0 = *(const float4*)(zi);
        float4 i1 = *(const float4*)(zi + 4);
        uint4 pk0, pk1;
        pk0.x = f2bf(r0.x) | (f2bf(i0.x) << 16);
        pk0.y = f2bf(r0.y) | (f2bf(i0.y) << 16);
        pk0.z = f2bf(r0.z) | (f2bf(i0.z) << 16);
        pk0.w = f2bf(r0.w) | (f2bf(i0.w) << 16);
        pk1.x = f2bf(r1.x) | (f2bf(i1.x) << 16);
        pk1.y = f2bf(r1.y) | (f2bf(i1.y) << 16);
        pk1.z = f2bf(r1.z) | (f2bf(i1.z) << 16);
        pk1.w = f2bf(r1.w) | (f2bf(i1.w) << 16);
        int blk0 = (seg * 2) ^ (o & 7);
        int blk1 = (seg * 2 + 1) ^ (o & 7);
        *(uint4*)&smZ[o * 64 + blk0 * 8] = pk0;
        *(uint4*)&smZ[o * 64 + blk1 * 8] = pk1;
    }
    // stage X: thread owns w = t, converts all 64 channels
    {
        const float* xb = xin + (size_t)(b * 64) * 65536 + hh * 256 + t;
#pragma unroll
        for (int i0 = 0; i0 < 64; i0 += 8) {
            float v[8];
#pragma unroll
            for (int i = 0; i < 8; ++i) v[i] = xb[(size_t)(i0 + i) * 65536];
            uint4 pk;
            pk.x = f2bf(v[0]) | (f2bf(v[1]) << 16);
            pk.y = f2bf(v[2]) | (f2bf(v[3]) << 16);
            pk.z = f2bf(v[4]) | (f2bf(v[5]) << 16);
            pk.w = f2bf(v[6]) | (f2bf(v[7]) << 16);
            int blk = (i0 >> 3) ^ (t & 7);
            *(uint4*)&smX[t * 64 + blk * 8] = pk;
        }
    }
    __syncthreads();

    int lane = t & 63, wv = t >> 6;
    int col = lane & 15, grp = lane >> 4;
    int w0 = wv * 64;

    short8b tf[4][2], bxf[4][2];
#pragma unroll
    for (int wt = 0; wt < 4; ++wt) {
        int w = w0 + wt * 16 + col;
#pragma unroll
        for (int kb = 0; kb < 2; ++kb) {
            tf[wt][kb] = *(const short8b*)&tbf[w * 64 + kb * 32 + grp * 8];
            int blk = (kb * 4 + grp) ^ (w & 7);
            bxf[wt][kb] = *(const short8b*)&smX[w * 64 + blk * 8];
        }
    }

    const unsigned short* WSp = wsk + l * 4096;
#pragma unroll
    for (int ot = 0; ot < 4; ++ot) {
        int o = ot * 16 + col;
        short8b az[2], ask[2];
#pragma unroll
        for (int kb = 0; kb < 2; ++kb) {
            int blk = (kb * 4 + grp) ^ (o & 7);
            az[kb] = *(const short8b*)&smZ[o * 64 + blk * 8];
            ask[kb] = *(const short8b*)&WSp[o * 64 + kb * 32 + grp * 8];
        }
        f32x4 bias = *(const f32x4*)&skip_b[l * 64 + ot * 16 + grp * 4];
#pragma unroll
        for (int wt = 0; wt < 4; ++wt) {
            f32x4 acc = bias;
            acc = __builtin_amdgcn_mfma_f32_16x16x32_bf16(az[0], tf[wt][0], acc, 0, 0, 0);
            acc = __builtin_amdgcn_mfma_f32_16x16x32_bf16(az[1], tf[wt][1], acc, 0, 0, 0);
            acc = __builtin_amdgcn_mfma_f32_16x16x32_bf16(ask[0], bxf[wt][0], acc, 0, 0, 0);
            acc = __builtin_amdgcn_mfma_f32_16x16x32_bf16(ask[1], bxf[wt][1], acc, 0, 0, 0);
            unsigned short* op = xout + (size_t)(b * 64 + ot * 16 + grp * 4) * 65536
                               + hh * 256 + w0 + wt * 16 + col;
            op[0]          = (unsigned short)f2bf(gelu_f(acc[0]));
            op[65536]      = (unsigned short)f2bf(gelu_f(acc[1]));
            op[2 * 65536]  = (unsigned short)f2bf(gelu_f(acc[2]));
            op[3 * 65536]  = (unsigned short)f2bf(gelu_f(acc[3]));
        }
    }
}

// ---- MFMA channel MLP: x2 = gelu(W2@gelu(W1@x+b1)+b2 + Wsk@x+bsk); input bf16 XA
__global__ __launch_bounds__(256) void k_mlp(const unsigned short* __restrict__ xin,
                                             const unsigned short* __restrict__ wb,
                                             const float* __restrict__ b1,
                                             const float* __restrict__ b2,
                                             const float* __restrict__ bsk,
                                             float* __restrict__ xout, int l) {
    __shared__ __align__(16) unsigned short smemX[128 * 64];
    __shared__ __align__(16) unsigned short smemH[128 * 128];
    int t = threadIdx.x;
    int b = blockIdx.y;
    int p0 = blockIdx.x * 128;

    {
        int pxs = t & 127;
        int cb = (t >> 7) * 8;
        const unsigned short* xb = xin + (size_t)(b * 64) * 65536 + p0 + pxs;
#pragma unroll
        for (int pass = 0; pass < 4; ++pass) {
            int ch0 = pass * 16 + cb;
            unsigned u[8];
#pragma unroll
            for (int i = 0; i < 8; ++i) u[i] = xb[(size_t)(ch0 + i) * 65536];
            uint4 pk;
            pk.x = u[0] | (u[1] << 16);
            pk.y = u[2] | (u[3] << 16);
            pk.z = u[4] | (u[5] << 16);
            pk.w = u[6] | (u[7] << 16);
            int blk = (ch0 >> 3) ^ (pxs & 7);
            *(uint4*)&smemX[pxs * 64 + blk * 8] = pk;
        }
    }
    __syncthreads();

    int lane = t & 63, wv = t >> 6;
    int col = lane & 15, grp = lane >> 4;

    short8b bx[2][2];
#pragma unroll
    for (int pxt = 0; pxt < 2; ++pxt)
#pragma unroll
        for (int kb = 0; kb < 2; ++kb) {
            int px = wv * 32 + pxt * 16 + col;
            int blk = (kb * 4 + grp) ^ (px & 7);
            bx[pxt][kb] = *(const short8b*)&smemX[px * 64 + blk * 8];
        }

    const unsigned short* W1p = wb + l * 8192;
#pragma unroll
    for (int ot = 0; ot < 8; ++ot) {
        short8b a0 = *(const short8b*)&W1p[(ot * 16 + col) * 64 + grp * 8];
        short8b a1 = *(const short8b*)&W1p[(ot * 16 + col) * 64 + 32 + grp * 8];
        int hm0 = ot * 16 + grp * 4;
        f32x4 bb = *(const f32x4*)&b1[l * 128 + hm0];
#pragma unroll
        for (int pxt = 0; pxt < 2; ++pxt) {
            f32x4 acc = bb;
            acc = __builtin_amdgcn_mfma_f32_16x16x32_bf16(a0, bx[pxt][0], acc, 0, 0, 0);
            acc = __builtin_amdgcn_mfma_f32_16x16x32_bf16(a1, bx[pxt][1], acc, 0, 0, 0);
            ushort4 hp;
            hp.x = (unsigned short)f2bf(gelu_f(acc[0]));
            hp.y = (unsigned short)f2bf(gelu_f(acc[1]));
            hp.z = (unsigned short)f2bf(gelu_f(acc[2]));
            hp.w = (unsigned short)f2bf(gelu_f(acc[3]));
            int px = wv * 32 + pxt * 16 + col;
            int blk = (hm0 >> 3) ^ (px & 7);
            *(ushort4*)&smemH[px * 128 + blk * 8 + (hm0 & 7)] = hp;
        }
    }

    short8b bh[2][4];
#pragma unroll
    for (int pxt = 0; pxt < 2; ++pxt)
#pragma unroll
        for (int kb = 0; kb < 4; ++kb) {
            int px = wv * 32 + pxt * 16 + col;
            int blk = (kb * 4 + grp) ^ (px & 7);
            bh[pxt][kb] = *(const short8b*)&smemH[px * 128 + blk * 8];
        }

    const unsigned short* W2p = wb + 16384 + l * 8192;
    const unsigned short* WSp = wb + 32768 + l * 4096;
#pragma unroll
    for (int ot = 0; ot < 4; ++ot) {
        int o0 = ot * 16 + grp * 4;
        f32x4 b2v = *(const f32x4*)&b2[l * 64 + o0];
        f32x4 bsv = *(const f32x4*)&bsk[l * 64 + o0];
        short8b a2[4], as[2];
#pragma unroll
        for (int kb = 0; kb < 4; ++kb)
            a2[kb] = *(const short8b*)&W2p[(ot * 16 + col) * 128 + kb * 32 + grp * 8];
#pragma unroll
        for (int kb = 0; kb < 2; ++kb)
            as[kb] = *(const short8b*)&WSp[(ot * 16 + col) * 64 + kb * 32 + grp * 8];
#pragma unroll
        for (int pxt = 0; pxt < 2; ++pxt) {
            f32x4 acc = b2v + bsv;
#pragma unroll
            for (int kb = 0; kb < 4; ++kb)
                acc = __builtin_amdgcn_mfma_f32_16x16x32_bf16(a2[kb], bh[pxt][kb], acc, 0, 0, 0);
#pragma unroll
            for (int kb = 0; kb < 2; ++kb)
                acc = __builtin_amdgcn_mfma_f32_16x16x32_bf16(as[kb], bx[pxt][kb], acc, 0, 0, 0);
            int px = wv * 32 + pxt * 16 + col;
            float* op = xout + (size_t)(b * 64 + o0) * 65536 + p0 + px;
            op[0]          = gelu_f(acc[0]);
            op[65536]      = gelu_f(acc[1]);
            op[2 * 65536]  = gelu_f(acc[2]);
            op[3 * 65536]  = gelu_f(acc[3]);
        }
    }
}

// ---- MFMA projection: out = PW2 @ gelu(PW1@x + pb1) + pb2  (O=1)
__global__ __launch_bounds__(256) void k_proj(const float* __restrict__ xin,
                                              const unsigned short* __restrict__ wb,
                                              const float* __restrict__ pb1,
                                              const float* __restrict__ pw2,
                                              const float* __restrict__ pb2,
                                              float* __restrict__ out) {
    __shared__ __align__(16) unsigned short smemX[128 * 64];
    int t = threadIdx.x;
    int b = blockIdx.y;
    int p0 = blockIdx.x * 128;
    {
        int pxs = t & 127;
        int cb = (t >> 7) * 8;
        const float* xb = xin + (size_t)(b * 64) * 65536 + p0 + pxs;
#pragma unroll
        for (int pass = 0; pass < 4; ++pass) {
            int ch0 = pass * 16 + cb;
            float v[8];
#pragma unroll
            for (int i = 0; i < 8; ++i) v[i] = xb[(size_t)(ch0 + i) * 65536];
            uint4 pk;
            pk.x = f2bf(v[0]) | (f2bf(v[1]) << 16);
            pk.y = f2bf(v[2]) | (f2bf(v[3]) << 16);
            pk.z = f2bf(v[4]) | (f2bf(v[5]) << 16);
            pk.w = f2bf(v[6]) | (f2bf(v[7]) << 16);
            int blk = (ch0 >> 3) ^ (pxs & 7);
            *(uint4*)&smemX[pxs * 64 + blk * 8] = pk;
        }
    }
    __syncthreads();

    int lane = t & 63, wv = t >> 6;
    int col = lane & 15, grp = lane >> 4;

    short8b bx[2][2];
#pragma unroll
    for (int pxt = 0; pxt < 2; ++pxt)
#pragma unroll
        for (int kb = 0; kb < 2; ++kb) {
            int px = wv * 32 + pxt * 16 + col;
            int blk = (kb * 4 + grp) ^ (px & 7);
            bx[pxt][kb] = *(const short8b*)&smemX[px * 64 + blk * 8];
        }

    const unsigned short* P1p = wb + 40960;
    float psum0 = 0.f, psum1 = 0.f;
#pragma unroll
    for (int ot = 0; ot < 16; ++ot) {
        short8b a0 = *(const short8b*)&P1p[(ot * 16 + col) * 64 + grp * 8];
        short8b a1 = *(const short8b*)&P1p[(ot * 16 + col) * 64 + 32 + grp * 8];
        int o0 = ot * 16 + grp * 4;
        f32x4 b1v = *(const f32x4*)&pb1[o0];
        f32x4 w2v = *(const f32x4*)&pw2[o0];
        {
            f32x4 acc = b1v;
            acc = __builtin_amdgcn_mfma_f32_16x16x32_bf16(a0, bx[0][0], acc, 0, 0, 0);
            acc = __builtin_amdgcn_mfma_f32_16x16x32_bf16(a1, bx[0][1], acc, 0, 0, 0);
            psum0 += w2v[0] * gelu_f(acc[0]) + w2v[1] * gelu_f(acc[1])
                   + w2v[2] * gelu_f(acc[2]) + w2v[3] * gelu_f(acc[3]);
        }
        {
            f32x4 acc = b1v;
            acc = __builtin_amdgcn_mfma_f32_16x16x32_bf16(a0, bx[1][0], acc, 0, 0, 0);
            acc = __builtin_amdgcn_mfma_f32_16x16x32_bf16(a1, bx[1][1], acc, 0, 0, 0);
            psum1 += w2v[0] * gelu_f(acc[0]) + w2v[1] * gelu_f(acc[1])
                   + w2v[2] * gelu_f(acc[2]) + w2v[3] * gelu_f(acc[3]);
        }
    }
    psum0 += __shfl_xor(psum0, 16);
    psum0 += __shfl_xor(psum0, 32);
    psum1 += __shfl_xor(psum1, 16);
    psum1 += __shfl_xor(psum1, 32);
    if (grp == 0) {
        float bias = pb2[0];
        out[(size_t)b * 65536 + p0 + wv * 32 + col] = psum0 + bias;
        out[(size_t)b * 65536 + p0 + wv * 32 + 16 + col] = psum1 + bias;
    }
}

extern "C" void kernel_launch(void* const* d_in, const int* in_sizes, int n_in,
                              void* d_out, int out_size, void* d_ws, size_t ws_size,
                              hipStream_t stream) {
    const float* x          = (const float*)d_in[0];
    const float2* sw1       = (const float2*)d_in[1];
    const float2* sw2       = (const float2*)d_in[2];
    const float* skip_w     = (const float*)d_in[3];
    const float* skip_b     = (const float*)d_in[4];
    const float* mlp_w1     = (const float*)d_in[5];
    const float* mlp_b1     = (const float*)d_in[6];
    const float* mlp_w2     = (const float*)d_in[7];
    const float* mlp_b2     = (const float*)d_in[8];
    const float* mlp_skip_w = (const float*)d_in[9];
    const float* mlp_skip_b = (const float*)d_in[10];
    const float* proj_w1    = (const float*)d_in[11];
    const float* proj_b1    = (const float*)d_in[12];
    const float* proj_w2    = (const float*)d_in[13];
    const float* proj_b2    = (const float*)d_in[14];

    float* ws = (float*)d_ws;
    unsigned short* XAb = (unsigned short*)(ws + OFF_XA);
    float* XB  = ws + OFF_XB;
    float* X1f = ws + OFF_Z1;                    // fwd_w output (aliases Zre/Zim)
    float* Zre = ws + OFF_Z1;
    float* Zim = ws + OFF_Z1 + 2097152;
    float* XFre = ws + OFF_XF;
    float* XFim = ws + OFF_XF + 524288;
    float* OFT = ws + OFF_OF;
    const unsigned short* TBF = (const unsigned short*)(ws + OFF_TBF);
    const unsigned short* EH  = (const unsigned short*)(ws + OFF_EH);
    const unsigned short* EL  = (const unsigned short*)(ws + OFF_EL);
    const unsigned short* AFH = (const unsigned short*)(ws + OFF_AFH);
    const unsigned short* AFL = (const unsigned short*)(ws + OFF_AFL);
    const unsigned short* AIH = (const unsigned short*)(ws + OFF_AIH);
    const unsigned short* AIL = (const unsigned short*)(ws + OFF_AIL);
    unsigned short* WB = (unsigned short*)(ws + OFF_WBF);

    init_tw<<<640, 256, 0, stream>>>(ws);
    k_cvt<<<256, 256, 0, stream>>>(mlp_w1, mlp_w2, mlp_skip_w, proj_w1, skip_w, WB);

    const float* cur = x;
    for (int l = 0; l < 2; ++l) {
        k_fwd_w<<<1024, 256, 0, stream>>>(cur, X1f, EH, EL);
        k_fwd_h<<<256, 256, 0, stream>>>(X1f, XFre, XFim, AFH, AFL);
        k_modemul<<<dim3(64, 64), 128, 0, stream>>>(XFre, XFim, sw1, sw2, OFT, l);
        k_inv_h<<<256, 256, 0, stream>>>(OFT, Zre, Zim, AIH, AIL);
        k_invw_skip<<<dim3(256, 4), 256, 0, stream>>>(Zre, Zim, cur, TBF,
                                                      WB + 57344, skip_b, XAb, l);
        k_mlp<<<dim3(512, 4), 256, 0, stream>>>(XAb, WB, mlp_b1, mlp_b2, mlp_skip_b, XB, l);
        cur = XB;
    }
    k_proj<<<dim3(512, 4), 256, 0, stream>>>(XB, WB, proj_b1, proj_w2, proj_b2, (float*)d_out);
}

// Round 7
// 423.072 us; speedup vs baseline: 5.7030x; 1.0158x over previous
//
#include <hip/hip_runtime.h>
#include <math.h>

// Problem constants: B=4, C=64, H=256, W=256, L=2, M1=M2=32, HM=128, P=256, O=1

// workspace layout (in floats)
#define OFF_XA   0                      // bf16 XA: ushort[16777216]
#define OFF_XB   16777216               // bf16 XBb[16777216] + XBb2[16777216] (ushorts)
#define OFF_Z1   33554432               // 4194304 floats: X1 (4M) OR Zre(2M)+Zim(2M)
#define OFF_XF   37748736               // XFre 524288 + XFim 524288
#define OFF_OF   38797312               // OFT 1048576  [plane][kx][2j+d]
#define OFF_TBF  39845888               // ushort[16384] invW twiddle Tt[w][k]
#define OFF_EH   39854080               // ushort[16384] fwdW E_hi[n][w]
#define OFF_EL   39862272               // ushort[16384] fwdW E_lo[n][w]
#define OFF_AFH  39870464               // ushort[65536] fwdH A_hi[n=128][k=512]
#define OFF_AFL  39903232               // ushort[65536] fwdH A_lo
#define OFF_AIH  39936000               // ushort[65536] invH A_hi[c=2][h=256][k=128]
#define OFF_AIL  39968768               // ushort[65536] invH A_lo
#define OFF_WBF  40001536               // ushort[65536] bf16 weights
// total = 40034304 floats ≈ 152.7 MiB

// WB (ushort) layout: [0:16384) mlp_w1 | [16384:32768) mlp_w2 | [32768:40960) mlp_skip_w
//                     [40960:57344) proj_w1 | [57344:65536) spectral skip_w (2x64x64)

typedef __attribute__((ext_vector_type(8))) short short8b;   // 8 bf16 (4 VGPRs)
typedef __attribute__((ext_vector_type(4))) float f32x4;     // MFMA acc

__device__ __forceinline__ float gelu_f(float v) {
    float u = v * fmaf(v * v, 0.0713548162f, 1.5957691216f);
    return v * __builtin_amdgcn_rcpf(1.0f + __expf(-u));
}

__device__ __forceinline__ unsigned f2bf(float f) {
    unsigned int u = __float_as_uint(f);
    u += 0x7FFFu + ((u >> 16) & 1u);   // RNE
    return u >> 16;
}

__global__ __launch_bounds__(256) void init_tw(float* ws) {
    int idx = blockIdx.x * 256 + threadIdx.x;
    unsigned short* tbf = (unsigned short*)(ws + OFF_TBF);
    unsigned short* eh  = (unsigned short*)(ws + OFF_EH);
    unsigned short* el  = (unsigned short*)(ws + OFF_EL);
    unsigned short* afh = (unsigned short*)(ws + OFF_AFH);
    unsigned short* afl = (unsigned short*)(ws + OFF_AFL);
    unsigned short* aih = (unsigned short*)(ws + OFF_AIH);
    unsigned short* ail = (unsigned short*)(ws + OFF_AIL);
    const double PI128 = 3.14159265358979323846 / 128.0;
    if (idx < 16384) {
        int w = idx >> 6, k = idx & 63;
        int kx = k >> 1;
        int m = (kx * w) & 255;
        double a = (double)m * PI128;
        float sc = (kx == 0) ? (1.0f / 65536.0f) : (2.0f / 65536.0f);
        float v = (k & 1) ? (float)(-sin(a)) * sc : (float)cos(a) * sc;
        tbf[idx] = (unsigned short)f2bf(v);
    }
    int i2 = idx - 16384;
    if (i2 >= 0 && i2 < 16384) {
        int n = i2 >> 8, w = i2 & 255;
        int kx = n >> 1;
        int m = (kx * w) & 255;
        double a = (double)m * PI128;
        float v = (n & 1) ? (float)(-sin(a)) : (float)cos(a);
        unsigned h = f2bf(v);
        eh[i2] = (unsigned short)h;
        el[i2] = (unsigned short)f2bf(v - __uint_as_float(h << 16));
    }
    int i3 = idx - 32768;
    if (i3 >= 0 && i3 < 65536) {
        int n = i3 >> 9, k = i3 & 511;
        int j = n & 63, c = n >> 6;
        int h = k >> 1, d = k & 1;
        int ky = (j < 32) ? j : (192 + j);
        int m = (ky * h) & 255;
        double a = (double)m * PI128;
        float cv = (float)cos(a), sv = (float)sin(a);
        float v = (c == 0) ? (d ? sv : cv) : (d ? cv : -sv);
        unsigned hh = f2bf(v);
        afh[i3] = (unsigned short)hh;
        afl[i3] = (unsigned short)f2bf(v - __uint_as_float(hh << 16));
    }
    int i4 = idx - 98304;
    if (i4 >= 0 && i4 < 65536) {
        int c = i4 >> 15, rem = i4 & 32767;
        int h = rem >> 7, k = rem & 127;
        int j = k >> 1, d = k & 1;
        int ky = (j < 32) ? j : (192 + j);
        int m = (ky * h) & 255;
        double a = (double)m * PI128;
        float cv = (float)cos(a), sv = (float)sin(a);
        float v = (c == 0) ? (d ? -sv : cv) : (d ? cv : sv);
        unsigned hh = f2bf(v);
        aih[i4] = (unsigned short)hh;
        ail[i4] = (unsigned short)f2bf(v - __uint_as_float(hh << 16));
    }
}

__global__ __launch_bounds__(256) void k_cvt(const float* __restrict__ w1,
                                             const float* __restrict__ w2,
                                             const float* __restrict__ wsk,
                                             const float* __restrict__ pw1,
                                             const float* __restrict__ ssk,
                                             unsigned short* __restrict__ wb) {
    int idx = blockIdx.x * 256 + threadIdx.x;
    if (idx < 16384)       wb[idx] = (unsigned short)f2bf(w1[idx]);
    else if (idx < 32768)  wb[idx] = (unsigned short)f2bf(w2[idx - 16384]);
    else if (idx < 40960)  wb[idx] = (unsigned short)f2bf(wsk[idx - 32768]);
    else if (idx < 57344)  wb[idx] = (unsigned short)f2bf(pw1[idx - 40960]);
    else if (idx < 65536)  wb[idx] = (unsigned short)f2bf(ssk[idx - 57344]);
}

// ---- MFMA fwd-W DFT, fp32 input (layer 0), split-bf16 3-pass, coalesced staging.
// 32 rows/block, 2048 blocks, 32 KB LDS.
__global__ __launch_bounds__(256) void k_fwd_w_f32(const float* __restrict__ x,
                                                   float* __restrict__ X1f,
                                                   const unsigned short* __restrict__ EH,
                                                   const unsigned short* __restrict__ EL) {
    __shared__ __align__(16) unsigned short smH[32 * 256];   // 16 KB [row][w] swizzled
    __shared__ __align__(16) unsigned short smL[32 * 256];   // 16 KB
    int t = threadIdx.x;
    size_t row0 = (size_t)blockIdx.x * 32;
    const float* xg = x + row0 * 256;
#pragma unroll
    for (int pass = 0; pass < 8; ++pass) {
        int idx = pass * 256 + t;          // float4 index; wave = one full row
        int row = idx >> 6;
        int w0 = (idx & 63) * 4;
        float4 v = *(const float4*)(xg + (size_t)idx * 4);
        unsigned h0 = f2bf(v.x), h1 = f2bf(v.y), h2 = f2bf(v.z), h3 = f2bf(v.w);
        unsigned l0 = f2bf(v.x - __uint_as_float(h0 << 16));
        unsigned l1 = f2bf(v.y - __uint_as_float(h1 << 16));
        unsigned l2 = f2bf(v.z - __uint_as_float(h2 << 16));
        unsigned l3 = f2bf(v.w - __uint_as_float(h3 << 16));
        int oct = w0 >> 3, e = w0 & 7;
        int blk = oct ^ (row & 7);
        uint2 ph = {h0 | (h1 << 16), h2 | (h3 << 16)};
        uint2 pl = {l0 | (l1 << 16), l2 | (l3 << 16)};
        *(uint2*)&smH[row * 256 + blk * 8 + e] = ph;
        *(uint2*)&smL[row * 256 + blk * 8 + e] = pl;
    }
    __syncthreads();
    int lane = t & 63, wv = t >> 6;
    int col = lane & 15, grp = lane >> 4;
    int mt = wv >> 1, nh = wv & 1;        // wave = (row-tile, n-half)
    int row = mt * 16 + col;

    short8b bH[8], bL[8];
#pragma unroll
    for (int kb = 0; kb < 8; ++kb) {
        int blk = (kb * 4 + grp) ^ (row & 7);
        bH[kb] = *(const short8b*)&smH[row * 256 + blk * 8];
        bL[kb] = *(const short8b*)&smL[row * 256 + blk * 8];
    }
#pragma unroll
    for (int oi = 0; oi < 2; ++oi) {
        int ot = nh * 2 + oi;
        f32x4 acc = {0.f, 0.f, 0.f, 0.f};
#pragma unroll
        for (int kb = 0; kb < 8; ++kb) {
            const short8b aH = *(const short8b*)&EH[(ot * 16 + col) * 256 + kb * 32 + grp * 8];
            const short8b aL = *(const short8b*)&EL[(ot * 16 + col) * 256 + kb * 32 + grp * 8];
            acc = __builtin_amdgcn_mfma_f32_16x16x32_bf16(aH, bH[kb], acc, 0, 0, 0);
            acc = __builtin_amdgcn_mfma_f32_16x16x32_bf16(aH, bL[kb], acc, 0, 0, 0);
            acc = __builtin_amdgcn_mfma_f32_16x16x32_bf16(aL, bH[kb], acc, 0, 0, 0);
        }
        *(float4*)&X1f[(row0 + row) * 64 + ot * 16 + grp * 4] = *(float4*)&acc;
    }
}

// ---- MFMA fwd-W DFT, bf16 input (layer 1): x_lo == 0 exactly, so 2-pass
// (E_hi + E_lo) is exact for the bf16 input. 64 rows/block, 1024 blocks, 32 KB LDS.
__global__ __launch_bounds__(256) void k_fwd_w_bf16(const unsigned short* __restrict__ xb,
                                                    float* __restrict__ X1f,
                                                    const unsigned short* __restrict__ EH,
                                                    const unsigned short* __restrict__ EL) {
    __shared__ __align__(16) unsigned short smH[64 * 256];   // 32 KB
    int t = threadIdx.x;
    size_t row0 = (size_t)blockIdx.x * 64;
    const unsigned short* xg = xb + row0 * 256;
#pragma unroll
    for (int pass = 0; pass < 8; ++pass) {
        int idx = pass * 256 + t;          // 16B granule index
        int row = idx >> 5;
        int oct = idx & 31;
        uint4 v = *(const uint4*)(xg + (size_t)idx * 8);
        int blk = oct ^ (row & 7);
        *(uint4*)&smH[row * 256 + blk * 8] = v;
    }
    __syncthreads();
    int lane = t & 63, wv = t >> 6;
    int col = lane & 15, grp = lane >> 4;
    int row = wv * 16 + col;

    short8b bH[8];
#pragma unroll
    for (int kb = 0; kb < 8; ++kb) {
        int blk = (kb * 4 + grp) ^ (row & 7);
        bH[kb] = *(const short8b*)&smH[row * 256 + blk * 8];
    }
#pragma unroll
    for (int ot = 0; ot < 4; ++ot) {
        f32x4 acc = {0.f, 0.f, 0.f, 0.f};
#pragma unroll
        for (int kb = 0; kb < 8; ++kb) {
            const short8b aH = *(const short8b*)&EH[(ot * 16 + col) * 256 + kb * 32 + grp * 8];
            const short8b aL = *(const short8b*)&EL[(ot * 16 + col) * 256 + kb * 32 + grp * 8];
            acc = __builtin_amdgcn_mfma_f32_16x16x32_bf16(aH, bH[kb], acc, 0, 0, 0);
            acc = __builtin_amdgcn_mfma_f32_16x16x32_bf16(aL, bH[kb], acc, 0, 0, 0);
        }
        *(float4*)&X1f[(row0 + row) * 64 + ot * 16 + grp * 4] = *(float4*)&acc;
    }
}

// ---- MFMA forward DFT over H (split-bf16): XF[n][kx] = sum_k AF[n][k]*X1[plane][kx][k]
__global__ __launch_bounds__(256) void k_fwd_h(const float* __restrict__ X1f,
                                               float* __restrict__ XFre,
                                               float* __restrict__ XFim,
                                               const unsigned short* __restrict__ AFH,
                                               const unsigned short* __restrict__ AFL) {
    __shared__ __align__(16) unsigned short smH[32 * 512];   // [kx][k] swizzled, 32 KB
    __shared__ __align__(16) unsigned short smL[32 * 512];
    int t = threadIdx.x;
    int plane = blockIdx.x;
    const float* xp = X1f + (size_t)plane * 16384;
#pragma unroll
    for (int pass = 0; pass < 16; ++pass) {
        int idx = pass * 256 + t;
        int h = idx >> 4, seg = idx & 15;
        float4 v = *(const float4*)(xp + h * 64 + seg * 4);
        int kx0 = seg * 2, kx1 = seg * 2 + 1;
        int k0 = 2 * h;
        unsigned hx = f2bf(v.x), hy = f2bf(v.y), hz = f2bf(v.z), hw = f2bf(v.w);
        unsigned lx = f2bf(v.x - __uint_as_float(hx << 16));
        unsigned ly = f2bf(v.y - __uint_as_float(hy << 16));
        unsigned lz = f2bf(v.z - __uint_as_float(hz << 16));
        unsigned lw = f2bf(v.w - __uint_as_float(hw << 16));
        int oct = k0 >> 3, e = k0 & 7;
        int b0 = oct ^ (kx0 & 7), b1 = oct ^ (kx1 & 7);
        *(unsigned*)&smH[kx0 * 512 + b0 * 8 + e] = hx | (hy << 16);
        *(unsigned*)&smH[kx1 * 512 + b1 * 8 + e] = hz | (hw << 16);
        *(unsigned*)&smL[kx0 * 512 + b0 * 8 + e] = lx | (ly << 16);
        *(unsigned*)&smL[kx1 * 512 + b1 * 8 + e] = lz | (lw << 16);
    }
    __syncthreads();
    int lane = t & 63, wv = t >> 6;
    int col = lane & 15, grp = lane >> 4;
#pragma unroll
    for (int mi = 0; mi < 2; ++mi) {
        int mt = wv * 2 + mi;
        const unsigned short* Ah = AFH + (mt * 16 + col) * 512;
        const unsigned short* Al = AFL + (mt * 16 + col) * 512;
        f32x4 acc0 = {0.f, 0.f, 0.f, 0.f}, acc1 = {0.f, 0.f, 0.f, 0.f};
#pragma unroll
        for (int kb = 0; kb < 16; ++kb) {
            short8b aH = *(const short8b*)&Ah[kb * 32 + grp * 8];
            short8b aL = *(const short8b*)&Al[kb * 32 + grp * 8];
#pragma unroll
            for (int nt = 0; nt < 2; ++nt) {
                int kx = nt * 16 + col;
                int blk = (kb * 4 + grp) ^ (kx & 7);
                short8b bH = *(const short8b*)&smH[kx * 512 + blk * 8];
                short8b bL = *(const short8b*)&smL[kx * 512 + blk * 8];
                f32x4 a = (nt == 0) ? acc0 : acc1;
                a = __builtin_amdgcn_mfma_f32_16x16x32_bf16(aH, bH, a, 0, 0, 0);
                a = __builtin_amdgcn_mfma_f32_16x16x32_bf16(aH, bL, a, 0, 0, 0);
                a = __builtin_amdgcn_mfma_f32_16x16x32_bf16(aL, bH, a, 0, 0, 0);
                if (nt == 0) acc0 = a; else acc1 = a;
            }
        }
#pragma unroll
        for (int nt = 0; nt < 2; ++nt) {
            int kx = nt * 16 + col;
            f32x4 a = (nt == 0) ? acc0 : acc1;
#pragma unroll
            for (int r = 0; r < 4; ++r) {
                int n = mt * 16 + grp * 4 + r;
                float* dst = (n < 64)
                    ? (XFre + (size_t)plane * 2048 + n * 32 + kx)
                    : (XFim + (size_t)plane * 2048 + (n - 64) * 32 + kx);
                *dst = a[r];
            }
        }
    }
}

// ---- per-mode complex matmul (planar XF in, transposed-interleaved OFT out)
__global__ __launch_bounds__(128) void k_modemul(const float* __restrict__ XFre,
                                                 const float* __restrict__ XFim,
                                                 const float2* __restrict__ sw1,
                                                 const float2* __restrict__ sw2,
                                                 float* __restrict__ OFT, int l) {
    int o = blockIdx.x, j = blockIdx.y;
    int tid = threadIdx.x;
    int kx = tid & 31, b = tid >> 5;
    int jj = (j < 32) ? j : (j - 32);
    const float2* Wb = ((j < 32) ? sw1 : sw2) + (l * 4194304 + o * 1024 + jj * 32 + kx);
    const float* Xr = XFre + (size_t)(b * 64) * 2048 + j * 32 + kx;
    const float* Xi = XFim + (size_t)(b * 64) * 2048 + j * 32 + kx;
    float ar = 0.f, ai = 0.f;
    for (int i = 0; i < 64; ++i) {
        float xr = Xr[i * 2048], xi = Xi[i * 2048];
        float2 wv = Wb[i * 65536];
        ar += xr * wv.x - xi * wv.y;
        ai += xr * wv.y + xi * wv.x;
    }
    float* dst = OFT + (size_t)(b * 64 + o) * 4096 + kx * 128 + 2 * j;
    dst[0] = ar;
    dst[1] = ai;
}

// ---- MFMA inverse DFT over H (split-bf16)
__global__ __launch_bounds__(256) void k_inv_h(const float* __restrict__ OFT,
                                               float* __restrict__ Zre,
                                               float* __restrict__ Zim,
                                               const unsigned short* __restrict__ AIH,
                                               const unsigned short* __restrict__ AIL) {
    __shared__ __align__(16) unsigned short smH[32 * 128];
    __shared__ __align__(16) unsigned short smL[32 * 128];
    int t = threadIdx.x;
    int plane = blockIdx.x;
    const float* op = OFT + (size_t)plane * 4096;
#pragma unroll
    for (int pass = 0; pass < 4; ++pass) {
        int idx = pass * 256 + t;
        int kx = idx >> 5, seg = idx & 31;
        float4 v = *(const float4*)(op + kx * 128 + seg * 4);
        unsigned h0 = f2bf(v.x), h1 = f2bf(v.y), h2 = f2bf(v.z), h3 = f2bf(v.w);
        unsigned l0 = f2bf(v.x - __uint_as_float(h0 << 16));
        unsigned l1 = f2bf(v.y - __uint_as_float(h1 << 16));
        unsigned l2 = f2bf(v.z - __uint_as_float(h2 << 16));
        unsigned l3 = f2bf(v.w - __uint_as_float(h3 << 16));
        int k0 = seg * 4;
        int oct = k0 >> 3, e = k0 & 7;
        int blk = oct ^ (kx & 7);
        uint2 ph = {h0 | (h1 << 16), h2 | (h3 << 16)};
        uint2 pl = {l0 | (l1 << 16), l2 | (l3 << 16)};
        *(uint2*)&smH[kx * 128 + blk * 8 + e] = ph;
        *(uint2*)&smL[kx * 128 + blk * 8 + e] = pl;
    }
    __syncthreads();
    int lane = t & 63, wv = t >> 6;
    int col = lane & 15, grp = lane >> 4;
#pragma unroll
    for (int mi = 0; mi < 4; ++mi) {
        int mt = wv * 4 + mi;
#pragma unroll
        for (int cc = 0; cc < 2; ++cc) {
            const unsigned short* Ah = AIH + cc * 32768 + (mt * 16 + col) * 128;
            const unsigned short* Al = AIL + cc * 32768 + (mt * 16 + col) * 128;
            f32x4 acc0 = {0.f, 0.f, 0.f, 0.f}, acc1 = {0.f, 0.f, 0.f, 0.f};
#pragma unroll
            for (int kb = 0; kb < 4; ++kb) {
                short8b aH = *(const short8b*)&Ah[kb * 32 + grp * 8];
                short8b aL = *(const short8b*)&Al[kb * 32 + grp * 8];
#pragma unroll
                for (int nt = 0; nt < 2; ++nt) {
                    int kx = nt * 16 + col;
                    int blk = (kb * 4 + grp) ^ (kx & 7);
                    short8b bH = *(const short8b*)&smH[kx * 128 + blk * 8];
                    short8b bL = *(const short8b*)&smL[kx * 128 + blk * 8];
                    f32x4 a = (nt == 0) ? acc0 : acc1;
                    a = __builtin_amdgcn_mfma_f32_16x16x32_bf16(aH, bH, a, 0, 0, 0);
                    a = __builtin_amdgcn_mfma_f32_16x16x32_bf16(aH, bL, a, 0, 0, 0);
                    a = __builtin_amdgcn_mfma_f32_16x16x32_bf16(aL, bH, a, 0, 0, 0);
                    if (nt == 0) acc0 = a; else acc1 = a;
                }
            }
            float* Zc = (cc == 0) ? Zre : Zim;
#pragma unroll
            for (int nt = 0; nt < 2; ++nt) {
                int kx = nt * 16 + col;
                f32x4 a = (nt == 0) ? acc0 : acc1;
#pragma unroll
                for (int r = 0; r < 4; ++r) {
                    int h = mt * 16 + grp * 4 + r;
                    Zc[(size_t)plane * 8192 + h * 32 + kx] = a[r];
                }
            }
        }
    }
}

// ---- MFMA fused inverse-W DFT + channel skip + bias + GELU -> bf16 XA
// BF16IN=0: skip-x from fp32 xinf; BF16IN=1: from bf16 xinb.
template<int BF16IN>
__global__ __launch_bounds__(256) void k_invw_skip(const float* __restrict__ Zre,
                                                   const float* __restrict__ Zim,
                                                   const float* __restrict__ xinf,
                                                   const unsigned short* __restrict__ xinb,
                                                   const unsigned short* __restrict__ tbf,
                                                   const unsigned short* __restrict__ wsk,
                                                   const float* __restrict__ skip_b,
                                                   unsigned short* __restrict__ xout, int l) {
    __shared__ __align__(16) unsigned short smZ[64 * 64];
    __shared__ __align__(16) unsigned short smX[256 * 64];
    int t = threadIdx.x;
    int hh = blockIdx.x, b = blockIdx.y;

    {
        int o = t >> 2, seg = t & 3;
        const float* zr = Zre + (size_t)(b * 64 + o) * 8192 + hh * 32 + seg * 8;
        const float* zi = Zim + (size_t)(b * 64 + o) * 8192 + hh * 32 + seg * 8;
        float4 r0 = *(const float4*)(zr);
        float4 r1 = *(const float4*)(zr + 4);
        float4 i0 = *(const float4*)(zi);
        float4 i1 = *(const float4*)(zi + 4);
        uint4 pk0, pk1;
        pk0.x = f2bf(r0.x) | (f2bf(i0.x) << 16);
        pk0.y = f2bf(r0.y) | (f2bf(i0.y) << 16);
        pk0.z = f2bf(r0.z) | (f2bf(i0.z) << 16);
        pk0.w = f2bf(r0.w) | (f2bf(i0.w) << 16);
        pk1.x = f2bf(r1.x) | (f2bf(i1.x) << 16);
        pk1.y = f2bf(r1.y) | (f2bf(i1.y) << 16);
        pk1.z = f2bf(r1.z) | (f2bf(i1.z) << 16);
        pk1.w = f2bf(r1.w) | (f2bf(i1.w) << 16);
        int blk0 = (seg * 2) ^ (o & 7);
        int blk1 = (seg * 2 + 1) ^ (o & 7);
        *(uint4*)&smZ[o * 64 + blk0 * 8] = pk0;
        *(uint4*)&smZ[o * 64 + blk1 * 8] = pk1;
    }
    if (BF16IN) {
        const unsigned short* xb = xinb + (size_t)(b * 64) * 65536 + hh * 256 + t;
#pragma unroll
        for (int i0 = 0; i0 < 64; i0 += 8) {
            unsigned u[8];
#pragma unroll
            for (int i = 0; i < 8; ++i) u[i] = xb[(size_t)(i0 + i) * 65536];
            uint4 pk;
            pk.x = u[0] | (u[1] << 16);
            pk.y = u[2] | (u[3] << 16);
            pk.z = u[4] | (u[5] << 16);
            pk.w = u[6] | (u[7] << 16);
            int blk = (i0 >> 3) ^ (t & 7);
            *(uint4*)&smX[t * 64 + blk * 8] = pk;
        }
    } else {
        const float* xb = xinf + (size_t)(b * 64) * 65536 + hh * 256 + t;
#pragma unroll
        for (int i0 = 0; i0 < 64; i0 += 8) {
            float v[8];
#pragma unroll
            for (int i = 0; i < 8; ++i) v[i] = xb[(size_t)(i0 + i) * 65536];
            uint4 pk;
            pk.x = f2bf(v[0]) | (f2bf(v[1]) << 16);
            pk.y = f2bf(v[2]) | (f2bf(v[3]) << 16);
            pk.z = f2bf(v[4]) | (f2bf(v[5]) << 16);
            pk.w = f2bf(v[6]) | (f2bf(v[7]) << 16);
            int blk = (i0 >> 3) ^ (t & 7);
            *(uint4*)&smX[t * 64 + blk * 8] = pk;
        }
    }
    __syncthreads();

    int lane = t & 63, wv = t >> 6;
    int col = lane & 15, grp = lane >> 4;
    int w0 = wv * 64;

    short8b tf[4][2], bxf[4][2];
#pragma unroll
    for (int wt = 0; wt < 4; ++wt) {
        int w = w0 + wt * 16 + col;
#pragma unroll
        for (int kb = 0; kb < 2; ++kb) {
            tf[wt][kb] = *(const short8b*)&tbf[w * 64 + kb * 32 + grp * 8];
            int blk = (kb * 4 + grp) ^ (w & 7);
            bxf[wt][kb] = *(const short8b*)&smX[w * 64 + blk * 8];
        }
    }

    const unsigned short* WSp = wsk + l * 4096;
#pragma unroll
    for (int ot = 0; ot < 4; ++ot) {
        int o = ot * 16 + col;
        short8b az[2], ask[2];
#pragma unroll
        for (int kb = 0; kb < 2; ++kb) {
            int blk = (kb * 4 + grp) ^ (o & 7);
            az[kb] = *(const short8b*)&smZ[o * 64 + blk * 8];
            ask[kb] = *(const short8b*)&WSp[o * 64 + kb * 32 + grp * 8];
        }
        f32x4 bias = *(const f32x4*)&skip_b[l * 64 + ot * 16 + grp * 4];
#pragma unroll
        for (int wt = 0; wt < 4; ++wt) {
            f32x4 acc = bias;
            acc = __builtin_amdgcn_mfma_f32_16x16x32_bf16(az[0], tf[wt][0], acc, 0, 0, 0);
            acc = __builtin_amdgcn_mfma_f32_16x16x32_bf16(az[1], tf[wt][1], acc, 0, 0, 0);
            acc = __builtin_amdgcn_mfma_f32_16x16x32_bf16(ask[0], bxf[wt][0], acc, 0, 0, 0);
            acc = __builtin_amdgcn_mfma_f32_16x16x32_bf16(ask[1], bxf[wt][1], acc, 0, 0, 0);
            unsigned short* op = xout + (size_t)(b * 64 + ot * 16 + grp * 4) * 65536
                               + hh * 256 + w0 + wt * 16 + col;
            op[0]          = (unsigned short)f2bf(gelu_f(acc[0]));
            op[65536]      = (unsigned short)f2bf(gelu_f(acc[1]));
            op[2 * 65536]  = (unsigned short)f2bf(gelu_f(acc[2]));
            op[3 * 65536]  = (unsigned short)f2bf(gelu_f(acc[3]));
        }
    }
}

// ---- MFMA channel MLP -> bf16 out
__global__ __launch_bounds__(256) void k_mlp(const unsigned short* __restrict__ xin,
                                             const unsigned short* __restrict__ wb,
                                             const float* __restrict__ b1,
                                             const float* __restrict__ b2,
                                             const float* __restrict__ bsk,
                                             unsigned short* __restrict__ xout, int l) {
    __shared__ __align__(16) unsigned short smemX[128 * 64];
    __shared__ __align__(16) unsigned short smemH[128 * 128];
    int t = threadIdx.x;
    int b = blockIdx.y;
    int p0 = blockIdx.x * 128;

    {
        int pxs = t & 127;
        int cb = (t >> 7) * 8;
        const unsigned short* xb = xin + (size_t)(b * 64) * 65536 + p0 + pxs;
#pragma unroll
        for (int pass = 0; pass < 4; ++pass) {
            int ch0 = pass * 16 + cb;
            unsigned u[8];
#pragma unroll
            for (int i = 0; i < 8; ++i) u[i] = xb[(size_t)(ch0 + i) * 65536];
            uint4 pk;
            pk.x = u[0] | (u[1] << 16);
            pk.y = u[2] | (u[3] << 16);
            pk.z = u[4] | (u[5] << 16);
            pk.w = u[6] | (u[7] << 16);
            int blk = (ch0 >> 3) ^ (pxs & 7);
            *(uint4*)&smemX[pxs * 64 + blk * 8] = pk;
        }
    }
    __syncthreads();

    int lane = t & 63, wv = t >> 6;
    int col = lane & 15, grp = lane >> 4;

    short8b bx[2][2];
#pragma unroll
    for (int pxt = 0; pxt < 2; ++pxt)
#pragma unroll
        for (int kb = 0; kb < 2; ++kb) {
            int px = wv * 32 + pxt * 16 + col;
            int blk = (kb * 4 + grp) ^ (px & 7);
            bx[pxt][kb] = *(const short8b*)&smemX[px * 64 + blk * 8];
        }

    const unsigned short* W1p = wb + l * 8192;
#pragma unroll
    for (int ot = 0; ot < 8; ++ot) {
        short8b a0 = *(const short8b*)&W1p[(ot * 16 + col) * 64 + grp * 8];
        short8b a1 = *(const short8b*)&W1p[(ot * 16 + col) * 64 + 32 + grp * 8];
        int hm0 = ot * 16 + grp * 4;
        f32x4 bb = *(const f32x4*)&b1[l * 128 + hm0];
#pragma unroll
        for (int pxt = 0; pxt < 2; ++pxt) {
            f32x4 acc = bb;
            acc = __builtin_amdgcn_mfma_f32_16x16x32_bf16(a0, bx[pxt][0], acc, 0, 0, 0);
            acc = __builtin_amdgcn_mfma_f32_16x16x32_bf16(a1, bx[pxt][1], acc, 0, 0, 0);
            ushort4 hp;
            hp.x = (unsigned short)f2bf(gelu_f(acc[0]));
            hp.y = (unsigned short)f2bf(gelu_f(acc[1]));
            hp.z = (unsigned short)f2bf(gelu_f(acc[2]));
            hp.w = (unsigned short)f2bf(gelu_f(acc[3]));
            int px = wv * 32 + pxt * 16 + col;
            int blk = (hm0 >> 3) ^ (px & 7);
            *(ushort4*)&smemH[px * 128 + blk * 8 + (hm0 & 7)] = hp;
        }
    }

    short8b bh[2][4];
#pragma unroll
    for (int pxt = 0; pxt < 2; ++pxt)
#pragma unroll
        for (int kb = 0; kb < 4; ++kb) {
            int px = wv * 32 + pxt * 16 + col;
            int blk = (kb * 4 + grp) ^ (px & 7);
            bh[pxt][kb] = *(const short8b*)&smemH[px * 128 + blk * 8];
        }

    const unsigned short* W2p = wb + 16384 + l * 8192;
    const unsigned short* WSp = wb + 32768 + l * 4096;
#pragma unroll
    for (int ot = 0; ot < 4; ++ot) {
        int o0 = ot * 16 + grp * 4;
        f32x4 b2v = *(const f32x4*)&b2[l * 64 + o0];
        f32x4 bsv = *(const f32x4*)&bsk[l * 64 + o0];
        short8b a2[4], as[2];
#pragma unroll
        for (int kb = 0; kb < 4; ++kb)
            a2[kb] = *(const short8b*)&W2p[(ot * 16 + col) * 128 + kb * 32 + grp * 8];
#pragma unroll
        for (int kb = 0; kb < 2; ++kb)
            as[kb] = *(const short8b*)&WSp[(ot * 16 + col) * 64 + kb * 32 + grp * 8];
#pragma unroll
        for (int pxt = 0; pxt < 2; ++pxt) {
            f32x4 acc = b2v + bsv;
#pragma unroll
            for (int kb = 0; kb < 4; ++kb)
                acc = __builtin_amdgcn_mfma_f32_16x16x32_bf16(a2[kb], bh[pxt][kb], acc, 0, 0, 0);
#pragma unroll
            for (int kb = 0; kb < 2; ++kb)
                acc = __builtin_amdgcn_mfma_f32_16x16x32_bf16(as[kb], bx[pxt][kb], acc, 0, 0, 0);
            int px = wv * 32 + pxt * 16 + col;
            unsigned short* op = xout + (size_t)(b * 64 + o0) * 65536 + p0 + px;
            op[0]          = (unsigned short)f2bf(gelu_f(acc[0]));
            op[65536]      = (unsigned short)f2bf(gelu_f(acc[1]));
            op[2 * 65536]  = (unsigned short)f2bf(gelu_f(acc[2]));
            op[3 * 65536]  = (unsigned short)f2bf(gelu_f(acc[3]));
        }
    }
}

// ---- MFMA projection (bf16 input): out = PW2 @ gelu(PW1@x + pb1) + pb2
__global__ __launch_bounds__(256) void k_proj(const unsigned short* __restrict__ xin,
                                              const unsigned short* __restrict__ wb,
                                              const float* __restrict__ pb1,
                                              const float* __restrict__ pw2,
                                              const float* __restrict__ pb2,
                                              float* __restrict__ out) {
    __shared__ __align__(16) unsigned short smemX[128 * 64];
    int t = threadIdx.x;
    int b = blockIdx.y;
    int p0 = blockIdx.x * 128;
    {
        int pxs = t & 127;
        int cb = (t >> 7) * 8;
        const unsigned short* xb = xin + (size_t)(b * 64) * 65536 + p0 + pxs;
#pragma unroll
        for (int pass = 0; pass < 4; ++pass) {
            int ch0 = pass * 16 + cb;
            unsigned u[8];
#pragma unroll
            for (int i = 0; i < 8; ++i) u[i] = xb[(size_t)(ch0 + i) * 65536];
            uint4 pk;
            pk.x = u[0] | (u[1] << 16);
            pk.y = u[2] | (u[3] << 16);
            pk.z = u[4] | (u[5] << 16);
            pk.w = u[6] | (u[7] << 16);
            int blk = (ch0 >> 3) ^ (pxs & 7);
            *(uint4*)&smemX[pxs * 64 + blk * 8] = pk;
        }
    }
    __syncthreads();

    int lane = t & 63, wv = t >> 6;
    int col = lane & 15, grp = lane >> 4;

    short8b bx[2][2];
#pragma unroll
    for (int pxt = 0; pxt < 2; ++pxt)
#pragma unroll
        for (int kb = 0; kb < 2; ++kb) {
            int px = wv * 32 + pxt * 16 + col;
            int blk = (kb * 4 + grp) ^ (px & 7);
            bx[pxt][kb] = *(const short8b*)&smemX[px * 64 + blk * 8];
        }

    const unsigned short* P1p = wb + 40960;
    float psum0 = 0.f, psum1 = 0.f;
#pragma unroll
    for (int ot = 0; ot < 16; ++ot) {
        short8b a0 = *(const short8b*)&P1p[(ot * 16 + col) * 64 + grp * 8];
        short8b a1 = *(const short8b*)&P1p[(ot * 16 + col) * 64 + 32 + grp * 8];
        int o0 = ot * 16 + grp * 4;
        f32x4 b1v = *(const f32x4*)&pb1[o0];
        f32x4 w2v = *(const f32x4*)&pw2[o0];
        {
            f32x4 acc = b1v;
            acc = __builtin_amdgcn_mfma_f32_16x16x32_bf16(a0, bx[0][0], acc, 0, 0, 0);
            acc = __builtin_amdgcn_mfma_f32_16x16x32_bf16(a1, bx[0][1], acc, 0, 0, 0);
            psum0 += w2v[0] * gelu_f(acc[0]) + w2v[1] * gelu_f(acc[1])
                   + w2v[2] * gelu_f(acc[2]) + w2v[3] * gelu_f(acc[3]);
        }
        {
            f32x4 acc = b1v;
            acc = __builtin_amdgcn_mfma_f32_16x16x32_bf16(a0, bx[1][0], acc, 0, 0, 0);
            acc = __builtin_amdgcn_mfma_f32_16x16x32_bf16(a1, bx[1][1], acc, 0, 0, 0);
            psum1 += w2v[0] * gelu_f(acc[0]) + w2v[1] * gelu_f(acc[1])
                   + w2v[2] * gelu_f(acc[2]) + w2v[3] * gelu_f(acc[3]);
        }
    }
    psum0 += __shfl_xor(psum0, 16);
    psum0 += __shfl_xor(psum0, 32);
    psum1 += __shfl_xor(psum1, 16);
    psum1 += __shfl_xor(psum1, 32);
    if (grp == 0) {
        float bias = pb2[0];
        out[(size_t)b * 65536 + p0 + wv * 32 + col] = psum0 + bias;
        out[(size_t)b * 65536 + p0 + wv * 32 + 16 + col] = psum1 + bias;
    }
}

extern "C" void kernel_launch(void* const* d_in, const int* in_sizes, int n_in,
                              void* d_out, int out_size, void* d_ws, size_t ws_size,
                              hipStream_t stream) {
    const float* x          = (const float*)d_in[0];
    const float2* sw1       = (const float2*)d_in[1];
    const float2* sw2       = (const float2*)d_in[2];
    const float* skip_w     = (const float*)d_in[3];
    const float* skip_b     = (const float*)d_in[4];
    const float* mlp_w1     = (const float*)d_in[5];
    const float* mlp_b1     = (const float*)d_in[6];
    const float* mlp_w2     = (const float*)d_in[7];
    const float* mlp_b2     = (const float*)d_in[8];
    const float* mlp_skip_w = (const float*)d_in[9];
    const float* mlp_skip_b = (const float*)d_in[10];
    const float* proj_w1    = (const float*)d_in[11];
    const float* proj_b1    = (const float*)d_in[12];
    const float* proj_w2    = (const float*)d_in[13];
    const float* proj_b2    = (const float*)d_in[14];

    float* ws = (float*)d_ws;
    unsigned short* XAb  = (unsigned short*)(ws + OFF_XA);
    unsigned short* XBb  = (unsigned short*)(ws + OFF_XB);          // layer-0 output (bf16)
    unsigned short* XBb2 = (unsigned short*)(ws + OFF_XB) + 16777216; // layer-1 output (bf16)
    float* X1f = ws + OFF_Z1;
    float* Zre = ws + OFF_Z1;
    float* Zim = ws + OFF_Z1 + 2097152;
    float* XFre = ws + OFF_XF;
    float* XFim = ws + OFF_XF + 524288;
    float* OFT = ws + OFF_OF;
    const unsigned short* TBF = (const unsigned short*)(ws + OFF_TBF);
    const unsigned short* EH  = (const unsigned short*)(ws + OFF_EH);
    const unsigned short* EL  = (const unsigned short*)(ws + OFF_EL);
    const unsigned short* AFH = (const unsigned short*)(ws + OFF_AFH);
    const unsigned short* AFL = (const unsigned short*)(ws + OFF_AFL);
    const unsigned short* AIH = (const unsigned short*)(ws + OFF_AIH);
    const unsigned short* AIL = (const unsigned short*)(ws + OFF_AIL);
    unsigned short* WB = (unsigned short*)(ws + OFF_WBF);

    init_tw<<<640, 256, 0, stream>>>(ws);
    k_cvt<<<256, 256, 0, stream>>>(mlp_w1, mlp_w2, mlp_skip_w, proj_w1, skip_w, WB);

    // ---- layer 0 (fp32 input x) ----
    k_fwd_w_f32<<<2048, 256, 0, stream>>>(x, X1f, EH, EL);
    k_fwd_h<<<256, 256, 0, stream>>>(X1f, XFre, XFim, AFH, AFL);
    k_modemul<<<dim3(64, 64), 128, 0, stream>>>(XFre, XFim, sw1, sw2, OFT, 0);
    k_inv_h<<<256, 256, 0, stream>>>(OFT, Zre, Zim, AIH, AIL);
    k_invw_skip<0><<<dim3(256, 4), 256, 0, stream>>>(Zre, Zim, x, nullptr, TBF,
                                                     WB + 57344, skip_b, XAb, 0);
    k_mlp<<<dim3(512, 4), 256, 0, stream>>>(XAb, WB, mlp_b1, mlp_b2, mlp_skip_b, XBb, 0);

    // ---- layer 1 (bf16 input XBb) ----
    k_fwd_w_bf16<<<1024, 256, 0, stream>>>(XBb, X1f, EH, EL);
    k_fwd_h<<<256, 256, 0, stream>>>(X1f, XFre, XFim, AFH, AFL);
    k_modemul<<<dim3(64, 64), 128, 0, stream>>>(XFre, XFim, sw1, sw2, OFT, 1);
    k_inv_h<<<256, 256, 0, stream>>>(OFT, Zre, Zim, AIH, AIL);
    k_invw_skip<1><<<dim3(256, 4), 256, 0, stream>>>(Zre, Zim, nullptr, XBb, TBF,
                                                     WB + 57344, skip_b, XAb, 1);
    k_mlp<<<dim3(512, 4), 256, 0, stream>>>(XAb, WB, mlp_b1, mlp_b2, mlp_skip_b, XBb2, 1);

    // ---- projection ----
    k_proj<<<dim3(512, 4), 256, 0, stream>>>(XBb2, WB, proj_b1, proj_w2, proj_b2,
                                             (float*)d_out);
}